// Round 1
// baseline (6165.271 us; speedup 1.0000x reference)
//
#include <hip/hip_runtime.h>
#include <stdint.h>

#define B_ 4
#define N_ 8192
#define K_ 16
#define FEAT_ 512
#define GRID_ 45
#define M_ (GRID_*GRID_)

// ---------- helpers ----------

// monotone float <-> uint map for atomicMax on floats
__device__ __forceinline__ unsigned int fmap(float f){
  unsigned int u = __float_as_uint(f);
  return (u & 0x80000000u) ? ~u : (u | 0x80000000u);
}
__device__ __forceinline__ float funmap(unsigned int u){
  return (u & 0x80000000u) ? __uint_as_float(u ^ 0x80000000u) : __uint_as_float(~u);
}

// sorted top-16 insert (ascending d, ties keep earlier index first)
__device__ __forceinline__ void topk_insert(float (&d)[16], int (&id)[16], float v, int j){
  if (v < d[15]){
    bool c[16];
#pragma unroll
    for (int s = 0; s < 16; ++s) c[s] = v < d[s];
#pragma unroll
    for (int s = 15; s >= 1; --s){
      d[s]  = c[s-1] ? d[s-1] : (c[s] ? v : d[s]);
      id[s] = c[s-1] ? id[s-1] : (c[s] ? j : id[s]);
    }
    if (c[0]){ d[0] = v; id[0] = j; }
  }
}

// ---------- init ----------
__global__ void k_init(unsigned int* glob){
  int i = blockIdx.x*256 + threadIdx.x;
  if (i < B_*1024) glob[i] = 0x007FFFFFu;   // fmap(-inf)
}

// ---------- KNN #1: nearest other point (candidate-split via u64 atomicMin) ----------
__global__ __launch_bounds__(256) void k_nn1(const float* __restrict__ pts,
                                             unsigned long long* __restrict__ nn64){
  __shared__ float sp[2048*3];
  int b = blockIdx.z, s = blockIdx.y;
  int c0 = s*2048;
  const float* P = pts + (size_t)b*N_*3;
  for (int i = threadIdx.x; i < 2048*3; i += 256) sp[i] = P[c0*3 + i];
  __syncthreads();
  int n = blockIdx.x*256 + threadIdx.x;
  float qx = P[n*3], qy = P[n*3+1], qz = P[n*3+2];
  float best = 1e30f; int bi = 0;
  for (int j = 0; j < 2048; ++j){
    float dx = qx - sp[j*3], dy = qy - sp[j*3+1], dz = qz - sp[j*3+2];
    float d2 = fmaf(dx,dx, fmaf(dy,dy, dz*dz));
    int cj = c0 + j;
    if (d2 < best && cj != n){ best = d2; bi = cj; }
  }
  unsigned long long key = ((unsigned long long)__float_as_uint(best) << 32) | (unsigned int)bi;
  atomicMin(&nn64[(size_t)b*N_ + n], key);
}

// ---------- local_cov + 3 convs (12->64->64->64, relu each) ----------
__global__ __launch_bounds__(256) void k_cov_mlp(const float* __restrict__ pts,
    const unsigned long long* __restrict__ nn64,
    const float* __restrict__ w1, const float* __restrict__ b1,
    const float* __restrict__ w2, const float* __restrict__ b2,
    const float* __restrict__ w3, const float* __restrict__ b3,
    float* __restrict__ xout){
  __shared__ __align__(16) float W1t[12*64];
  __shared__ __align__(16) float W2t[64*64];
  __shared__ __align__(16) float W3t[64*64];
  __shared__ float B1[64], B2[64], B3[64];
  __shared__ __align__(16) float x0[64][12];
  __shared__ __align__(16) float h1[64][64];
  __shared__ __align__(16) float h2[64][64];
  int b = blockIdx.y; int n0 = blockIdx.x*64; int tid = threadIdx.x;
  for (int i = tid; i < 12*64; i += 256){ int o = i % 64, ci = i / 64; W1t[i] = w1[o*12 + ci]; }
  for (int i = tid; i < 64*64; i += 256){ int o = i % 64, ci = i / 64; W2t[i] = w2[o*64 + ci]; W3t[i] = w3[o*64 + ci]; }
  if (tid < 64){ B1[tid]=b1[tid]; B2[tid]=b2[tid]; B3[tid]=b3[tid]; }
  {
    int p = tid % 64, cg = tid / 64;
    int n = n0 + p;
    const float* P = pts + ((size_t)b*N_ + n)*3;
    int nb = (int)(nn64[(size_t)b*N_ + n] & 0xFFFFFFFFull);
    const float* Q = pts + ((size_t)b*N_ + nb)*3;
    if (cg == 0){ x0[p][0]=P[0]; x0[p][1]=P[1]; x0[p][2]=P[2]; }
    else { int i = cg-1; float pi = P[i];
      x0[p][3+i*3+0]=pi*Q[0]; x0[p][3+i*3+1]=pi*Q[1]; x0[p][3+i*3+2]=pi*Q[2]; }
  }
  __syncthreads();
  { int o = tid % 64, pg = tid / 64;
    for (int p = pg; p < 64; p += 4){
      float acc = B1[o];
#pragma unroll
      for (int ci = 0; ci < 12; ++ci) acc = fmaf(W1t[ci*64+o], x0[p][ci], acc);
      h1[p][o] = fmaxf(acc, 0.f);
    } }
  __syncthreads();
  { int o = tid % 64, pg = tid / 64;
    for (int p = pg; p < 64; p += 4){
      float acc = B2[o];
#pragma unroll
      for (int ci = 0; ci < 64; ++ci) acc = fmaf(W2t[ci*64+o], h1[p][ci], acc);
      h2[p][o] = fmaxf(acc, 0.f);
    } }
  __syncthreads();
  { int o = tid % 64, pg = tid / 64;
    for (int p = pg; p < 64; p += 4){
      float acc = B3[o];
#pragma unroll
      for (int ci = 0; ci < 64; ++ci) acc = fmaf(W3t[ci*64+o], h2[p][ci], acc);
      xout[((size_t)b*N_ + n0 + p)*64 + o] = fmaxf(acc, 0.f);
    } }
}

// ---------- per-point squared norm (fma chain MUST match knn's chain) ----------
template<int C>
__global__ void k_cc(const float* __restrict__ f, float* __restrict__ cc){
  int i = blockIdx.x*256 + threadIdx.x;
  if (i >= B_*N_) return;
  const float4* row = (const float4*)(f + (size_t)i*C);
  float acc = 0.f;
#pragma unroll
  for (int c4 = 0; c4 < C/4; ++c4){
    float4 v = row[c4];
    acc = fmaf(v.x,v.x,acc); acc = fmaf(v.y,v.y,acc);
    acc = fmaf(v.z,v.z,acc); acc = fmaf(v.w,v.w,acc);
  }
  cc[i] = acc;
}

// ---------- general KNN partial (candidate range split S ways) ----------
template<int C, int TILE, int S>
__global__ __launch_bounds__(256) void k_knn_part(const float* __restrict__ f,
    const float* __restrict__ cc, float* __restrict__ pd, int* __restrict__ pid){
  __shared__ __align__(16) float sc[TILE*C];
  __shared__ float scc[TILE];
  int b = blockIdx.z, s = blockIdx.y;
  const float* F = f + (size_t)b*N_*C;
  int n = blockIdx.x*256 + threadIdx.x;
  float q[C];
  const float4* qrow = (const float4*)(F + (size_t)n*C);
#pragma unroll
  for (int c4 = 0; c4 < C/4; ++c4){ float4 v = qrow[c4];
    q[4*c4]=v.x; q[4*c4+1]=v.y; q[4*c4+2]=v.z; q[4*c4+3]=v.w; }
  float qq = 0.f;
#pragma unroll
  for (int c = 0; c < C; ++c) qq = fmaf(q[c], q[c], qq);
  float d[16]; int id[16];
#pragma unroll
  for (int t = 0; t < 16; ++t){ d[t] = 1e30f; id[t] = 0; }
  const int span = N_ / S;
  int j0 = s*span;
  for (int t0 = j0; t0 < j0 + span; t0 += TILE){
    __syncthreads();
    const float4* src = (const float4*)(F + (size_t)t0*C);
    float4* dst = (float4*)sc;
    for (int i = threadIdx.x; i < TILE*C/4; i += 256) dst[i] = src[i];
    for (int i = threadIdx.x; i < TILE; i += 256) scc[i] = cc[(size_t)b*N_ + t0 + i];
    __syncthreads();
    for (int j = 0; j < TILE; j += 2){
      float a0 = 0.f, a1 = 0.f;
      const float4* r0 = (const float4*)(sc + j*C);
      const float4* r1 = (const float4*)(sc + (j+1)*C);
#pragma unroll
      for (int c4 = 0; c4 < C/4; ++c4){
        float4 u0 = r0[c4], u1 = r1[c4];
        a0 = fmaf(q[4*c4  ], u0.x, a0); a0 = fmaf(q[4*c4+1], u0.y, a0);
        a0 = fmaf(q[4*c4+2], u0.z, a0); a0 = fmaf(q[4*c4+3], u0.w, a0);
        a1 = fmaf(q[4*c4  ], u1.x, a1); a1 = fmaf(q[4*c4+1], u1.y, a1);
        a1 = fmaf(q[4*c4+2], u1.z, a1); a1 = fmaf(q[4*c4+3], u1.w, a1);
      }
      float v0 = fmaf(-2.f, a0, qq + scc[j]);
      float v1 = fmaf(-2.f, a1, qq + scc[j+1]);
      topk_insert(d, id, v0, t0 + j);
      topk_insert(d, id, v1, t0 + j + 1);
    }
  }
  size_t base = ((size_t)(b*N_ + n)*S + s)*16;
#pragma unroll
  for (int t = 0; t < 16; ++t){ pd[base+t] = d[t]; pid[base+t] = id[t]; }
}

template<int S>
__global__ void k_knn_merge(const float* __restrict__ pd, const int* __restrict__ pid,
                            int* __restrict__ idxout){
  int i = blockIdx.x*256 + threadIdx.x;
  if (i >= B_*N_) return;
  float d[16]; int id[16];
#pragma unroll
  for (int t = 0; t < 16; ++t){ d[t] = 1e30f; id[t] = 0; }
  size_t base = (size_t)i*S*16;
  for (int t = 0; t < S*16; ++t) topk_insert(d, id, pd[base+t], pid[base+t]);
  for (int t = 0; t < 16; ++t) idxout[(size_t)i*16 + t] = id[t];
}

// ---------- maxpool(x) + conv 64->64 relu + conv 64->128 ----------
__global__ __launch_bounds__(256) void k_gpool_mlp(const float* __restrict__ x,
    const int* __restrict__ idx,
    const float* __restrict__ g1a, const float* __restrict__ g1ab,
    const float* __restrict__ g1b, const float* __restrict__ g1bb,
    float* __restrict__ gout){
  __shared__ __align__(16) float Wt1[64*64];
  __shared__ __align__(16) float Wt2[64*128];
  __shared__ float Ba[64], Bb[128];
  __shared__ __align__(16) float m[64][64];
  __shared__ __align__(16) float r[64][64];
  int b = blockIdx.y; int n0 = blockIdx.x*64; int tid = threadIdx.x;
  for (int i = tid; i < 64*64; i += 256){ int o = i%64, ci = i/64; Wt1[i] = g1a[o*64+ci]; }
  for (int i = tid; i < 64*128; i += 256){ int o = i%128, ci = i/128; Wt2[i] = g1b[o*64+ci]; }
  if (tid < 64) Ba[tid] = g1ab[tid];
  if (tid < 128) Bb[tid] = g1bb[tid];
  { int p = tid/4, cg = tid%4; int n = n0 + p;
    const int* ip = idx + ((size_t)b*N_ + n)*16;
    float mm[16];
#pragma unroll
    for (int u = 0; u < 16; ++u) mm[u] = -1e30f;
    for (int k = 0; k < 16; ++k){
      int nb = ip[k];
      const float4* src = (const float4*)(x + ((size_t)b*N_ + nb)*64 + cg*16);
#pragma unroll
      for (int u = 0; u < 4; ++u){
        float4 v = src[u];
        mm[4*u  ] = fmaxf(mm[4*u  ], v.x); mm[4*u+1] = fmaxf(mm[4*u+1], v.y);
        mm[4*u+2] = fmaxf(mm[4*u+2], v.z); mm[4*u+3] = fmaxf(mm[4*u+3], v.w);
      }
    }
#pragma unroll
    for (int u = 0; u < 16; ++u) m[p][cg*16+u] = mm[u];
  }
  __syncthreads();
  { int o = tid%64, pg = tid/64;
    float acc[16];
#pragma unroll
    for (int u = 0; u < 16; ++u) acc[u] = Ba[o];
    for (int ci = 0; ci < 64; ci += 4){
      float w0 = Wt1[ci*64+o], w1_ = Wt1[(ci+1)*64+o], w2_ = Wt1[(ci+2)*64+o], w3_ = Wt1[(ci+3)*64+o];
#pragma unroll
      for (int u = 0; u < 16; ++u){
        float4 mv = *(const float4*)&m[pg*16+u][ci];
        acc[u] = fmaf(w0, mv.x, acc[u]); acc[u] = fmaf(w1_, mv.y, acc[u]);
        acc[u] = fmaf(w2_, mv.z, acc[u]); acc[u] = fmaf(w3_, mv.w, acc[u]);
      }
    }
#pragma unroll
    for (int u = 0; u < 16; ++u) r[pg*16+u][o] = fmaxf(acc[u], 0.f);
  }
  __syncthreads();
  { int o = tid%128, pg = tid/128;   // no relu on this conv
    float acc[32];
#pragma unroll
    for (int u = 0; u < 32; ++u) acc[u] = Bb[o];
    for (int ci = 0; ci < 64; ci += 4){
      float w0 = Wt2[ci*128+o], w1_ = Wt2[(ci+1)*128+o], w2_ = Wt2[(ci+2)*128+o], w3_ = Wt2[(ci+3)*128+o];
#pragma unroll
      for (int u = 0; u < 32; ++u){
        float4 rv = *(const float4*)&r[pg*32+u][ci];
        acc[u] = fmaf(w0, rv.x, acc[u]); acc[u] = fmaf(w1_, rv.y, acc[u]);
        acc[u] = fmaf(w2_, rv.z, acc[u]); acc[u] = fmaf(w3_, rv.w, acc[u]);
      }
    }
#pragma unroll
    for (int u = 0; u < 32; ++u)
      gout[((size_t)b*N_ + n0 + pg*32 + u)*128 + o] = acc[u];
  }
}

// ---------- maxpool(g) + conv 128->128 relu + conv 128->1024 + global max ----------
__global__ __launch_bounds__(256) void k_hpool_max(const float* __restrict__ g,
    const int* __restrict__ idx,
    const float* __restrict__ g2a, const float* __restrict__ g2ab,
    const float* __restrict__ g2b, const float* __restrict__ g2bb,
    unsigned int* __restrict__ glob){
  __shared__ __align__(16) float m[32][128];
  __shared__ __align__(16) float t[32][128];
  int b = blockIdx.y; int n0 = blockIdx.x*32; int tid = threadIdx.x;
  { int p = tid/8, cg = tid%8; int n = n0+p;
    const int* ip = idx + ((size_t)b*N_+n)*16;
    float mm[16];
#pragma unroll
    for (int u = 0; u < 16; ++u) mm[u] = -1e30f;
    for (int k = 0; k < 16; ++k){
      int nb = ip[k];
      const float4* src = (const float4*)(g + ((size_t)b*N_+nb)*128 + cg*16);
#pragma unroll
      for (int u = 0; u < 4; ++u){
        float4 v = src[u];
        mm[4*u  ] = fmaxf(mm[4*u  ], v.x); mm[4*u+1] = fmaxf(mm[4*u+1], v.y);
        mm[4*u+2] = fmaxf(mm[4*u+2], v.z); mm[4*u+3] = fmaxf(mm[4*u+3], v.w);
      }
    }
#pragma unroll
    for (int u = 0; u < 16; ++u) m[p][cg*16+u] = mm[u];
  }
  __syncthreads();
  { int o = tid%128, pg = tid/128;
    float acc[16];
#pragma unroll
    for (int u = 0; u < 16; ++u) acc[u] = g2ab[o];
    const float4* wrow = (const float4*)(g2a + (size_t)o*128);
    for (int c4 = 0; c4 < 32; ++c4){
      float4 wv = wrow[c4];
#pragma unroll
      for (int u = 0; u < 16; ++u){
        float4 mv = *(const float4*)&m[pg*16+u][c4*4];
        acc[u] = fmaf(wv.x,mv.x,acc[u]); acc[u] = fmaf(wv.y,mv.y,acc[u]);
        acc[u] = fmaf(wv.z,mv.z,acc[u]); acc[u] = fmaf(wv.w,mv.w,acc[u]);
      }
    }
#pragma unroll
    for (int u = 0; u < 16; ++u) t[pg*16+u][o] = fmaxf(acc[u], 0.f);
  }
  __syncthreads();
  for (int oc = 0; oc < 4; ++oc){
    int o = oc*256 + tid;
    const float4* wrow = (const float4*)(g2b + (size_t)o*128);
    float acc[32];
#pragma unroll
    for (int u = 0; u < 32; ++u) acc[u] = 0.f;
    for (int c4 = 0; c4 < 32; ++c4){
      float4 wv = wrow[c4];
#pragma unroll
      for (int u = 0; u < 32; ++u){
        float4 tv = *(const float4*)&t[u][c4*4];
        acc[u] = fmaf(wv.x,tv.x,acc[u]); acc[u] = fmaf(wv.y,tv.y,acc[u]);
        acc[u] = fmaf(wv.z,tv.z,acc[u]); acc[u] = fmaf(wv.w,tv.w,acc[u]);
      }
    }
    float bias = g2bb[o];
    float mx = -1e30f;
#pragma unroll
    for (int u = 0; u < 32; ++u) mx = fmaxf(mx, acc[u] + bias);
    atomicMax(&glob[b*1024 + o], fmap(mx));
  }
}

// ---------- code MLP + decoder base precompute ----------
__global__ __launch_bounds__(512) void k_code(const unsigned int* __restrict__ glob,
    const float* __restrict__ m1, const float* __restrict__ m1b,
    const float* __restrict__ m2, const float* __restrict__ m2b,
    const float* __restrict__ f1a, const float* __restrict__ f1ab,
    const float* __restrict__ f2a, const float* __restrict__ f2ab,
    float* __restrict__ base1, float* __restrict__ base2){
  __shared__ __align__(16) float gl_s[1024];
  __shared__ __align__(16) float hid_s[512];
  __shared__ __align__(16) float code_s[512];
  int b = blockIdx.x; int tid = threadIdx.x;
  for (int i = tid; i < 1024; i += 512) gl_s[i] = funmap(glob[b*1024+i]);
  __syncthreads();
  { float acc = m1b[tid];
    const float4* wr = (const float4*)(m1 + (size_t)tid*1024);
    for (int c4 = 0; c4 < 256; ++c4){ float4 wv = wr[c4]; float4 gv = *(const float4*)&gl_s[c4*4];
      acc = fmaf(wv.x,gv.x,acc); acc = fmaf(wv.y,gv.y,acc);
      acc = fmaf(wv.z,gv.z,acc); acc = fmaf(wv.w,gv.w,acc); }
    hid_s[tid] = fmaxf(acc, 0.f);
  }
  __syncthreads();
  { float acc = m2b[tid];
    const float4* wr = (const float4*)(m2 + (size_t)tid*512);
    for (int c4 = 0; c4 < 128; ++c4){ float4 wv = wr[c4]; float4 hv = *(const float4*)&hid_s[c4*4];
      acc = fmaf(wv.x,hv.x,acc); acc = fmaf(wv.y,hv.y,acc);
      acc = fmaf(wv.z,hv.z,acc); acc = fmaf(wv.w,hv.w,acc); }
    code_s[tid] = acc;
  }
  __syncthreads();
  { float acc = f1ab[tid];
    const float* wr = f1a + (size_t)tid*514;   // stride 514: scalar loads (alignment)
    for (int c = 0; c < 512; ++c) acc = fmaf(wr[c], code_s[c], acc);
    base1[b*512 + tid] = acc;
  }
  { float acc = f2ab[tid];
    const float* wr = f2a + (size_t)tid*515;
    for (int c = 0; c < 512; ++c) acc = fmaf(wr[c], code_s[c], acc);
    base2[b*512 + tid] = acc;
  }
}

// ---------- folding decoder (layer-a collapsed to base + NIN fmas) ----------
template<int NIN>
__global__ __launch_bounds__(256) void k_fold(const float* __restrict__ base,
    const float* __restrict__ fa,
    const float* __restrict__ fb, const float* __restrict__ fbb,
    const float* __restrict__ fc, const float* __restrict__ fcb,
    const float* __restrict__ pin, float* __restrict__ pout){
  __shared__ __align__(16) float y1[32][512];
  __shared__ __align__(16) float y2[32][516];
  __shared__ float pcoord[32][NIN];
  int b = blockIdx.y; int m0 = blockIdx.x*32; int tid = threadIdx.x;
  if (tid < 32*NIN){
    int p = tid / NIN, c = tid % NIN;
    int mm = min(m0 + p, M_-1);
    float v;
    if (NIN == 2){
      const float step = 0.6f/44.f;
      int ii = (c == 0) ? (mm/GRID_) : (mm%GRID_);
      v = -0.3f + step*ii;
    } else {
      v = pin[((size_t)b*M_ + mm)*3 + c];
    }
    pcoord[p][c] = v;
  }
  __syncthreads();
  const int stride_a = 512 + NIN;
  for (int rep = 0; rep < 2; ++rep){
    int o = rep*256 + tid;
    float av[NIN];
#pragma unroll
    for (int c = 0; c < NIN; ++c) av[c] = fa[(size_t)o*stride_a + 512 + c];
    float bv = base[b*512 + o];
    for (int p = 0; p < 32; ++p){
      float acc = bv;
#pragma unroll
      for (int c = 0; c < NIN; ++c) acc = fmaf(av[c], pcoord[p][c], acc);
      y1[p][o] = fmaxf(acc, 0.f);
    }
  }
  __syncthreads();
  for (int rep = 0; rep < 2; ++rep){
    int o2 = rep*256 + tid;
    const float* wr = fb + (size_t)o2*512;
    float acc[32];
#pragma unroll
    for (int u = 0; u < 32; ++u) acc[u] = 0.f;
    for (int c4 = 0; c4 < 128; ++c4){
      float4 wv = *(const float4*)&wr[c4*4];
#pragma unroll
      for (int u = 0; u < 32; ++u){
        float4 yv = *(const float4*)&y1[u][c4*4];
        acc[u] = fmaf(wv.x,yv.x,acc[u]); acc[u] = fmaf(wv.y,yv.y,acc[u]);
        acc[u] = fmaf(wv.z,yv.z,acc[u]); acc[u] = fmaf(wv.w,yv.w,acc[u]);
      }
    }
    float bias = fbb[o2];
#pragma unroll
    for (int u = 0; u < 32; ++u) y2[u][o2] = fmaxf(acc[u] + bias, 0.f);
  }
  __syncthreads();
  if (tid < 96){
    int p = tid / 3, c = tid % 3;
    const float* wr = fc + (size_t)c*512;
    float acc = fcb[c];
    for (int o4 = 0; o4 < 128; ++o4){
      float4 wv = *(const float4*)&wr[o4*4];
      float4 yv = *(const float4*)&y2[p][o4*4];
      acc = fmaf(wv.x,yv.x,acc); acc = fmaf(wv.y,yv.y,acc);
      acc = fmaf(wv.z,yv.z,acc); acc = fmaf(wv.w,yv.w,acc);
    }
    int mm = m0 + p;
    if (mm < M_) pout[((size_t)b*M_ + mm)*3 + c] = acc;
  }
}

// ---------- launcher ----------
extern "C" void kernel_launch(void* const* d_in, const int* in_sizes, int n_in,
                              void* d_out, int out_size, void* d_ws, size_t ws_size,
                              hipStream_t stream){
  const float* pts  = (const float*)d_in[0];
  const float* w1   = (const float*)d_in[1];  const float* b1   = (const float*)d_in[2];
  const float* w2   = (const float*)d_in[3];  const float* b2   = (const float*)d_in[4];
  const float* w3   = (const float*)d_in[5];  const float* b3   = (const float*)d_in[6];
  const float* g1a  = (const float*)d_in[7];  const float* g1ab = (const float*)d_in[8];
  const float* g1b  = (const float*)d_in[9];  const float* g1bb = (const float*)d_in[10];
  const float* g2a  = (const float*)d_in[11]; const float* g2ab = (const float*)d_in[12];
  const float* g2b  = (const float*)d_in[13]; const float* g2bb = (const float*)d_in[14];
  const float* m1   = (const float*)d_in[15]; const float* m1b  = (const float*)d_in[16];
  const float* m2   = (const float*)d_in[17]; const float* m2b  = (const float*)d_in[18];
  const float* f1a  = (const float*)d_in[19]; const float* f1ab = (const float*)d_in[20];
  const float* f1b  = (const float*)d_in[21]; const float* f1bb = (const float*)d_in[22];
  const float* f1c  = (const float*)d_in[23]; const float* f1cb = (const float*)d_in[24];
  const float* f2a  = (const float*)d_in[25]; const float* f2ab = (const float*)d_in[26];
  const float* f2b  = (const float*)d_in[27]; const float* f2bb = (const float*)d_in[28];
  const float* f2c  = (const float*)d_in[29]; const float* f2cb = (const float*)d_in[30];
  float* out = (float*)d_out;

  char* w = (char*)d_ws;
  auto alloc = [&](size_t bytes){ char* p = w; w += (bytes + 255) & ~(size_t)255; return p; };
  unsigned long long* nn64 = (unsigned long long*)alloc((size_t)B_*N_*8);
  float* x    = (float*)alloc((size_t)B_*N_*64*4);
  float* g    = (float*)alloc((size_t)B_*N_*128*4);
  float* cc   = (float*)alloc((size_t)B_*N_*4);
  int*   idx  = (int*)alloc((size_t)B_*N_*16*4);
  float* pd   = (float*)alloc((size_t)B_*N_*4*16*4);
  int*   pid  = (int*)alloc((size_t)B_*N_*4*16*4);
  unsigned int* glob = (unsigned int*)alloc((size_t)B_*1024*4);
  float* base1 = (float*)alloc((size_t)B_*512*4);
  float* base2 = (float*)alloc((size_t)B_*512*4);
  float* mid   = (float*)alloc((size_t)B_*M_*3*4);
  (void)ws_size; (void)in_sizes; (void)n_in; (void)out_size;

  hipMemsetAsync(nn64, 0xFF, (size_t)B_*N_*8, stream);
  k_init<<<dim3((B_*1024+255)/256), 256, 0, stream>>>(glob);
  k_nn1<<<dim3(N_/256, 4, B_), 256, 0, stream>>>(pts, nn64);
  k_cov_mlp<<<dim3(N_/64, B_), 256, 0, stream>>>(pts, nn64, w1,b1,w2,b2,w3,b3, x);
  k_cc<64><<<dim3(B_*N_/256), 256, 0, stream>>>(x, cc);
  k_knn_part<64,128,4><<<dim3(N_/256, 4, B_), 256, 0, stream>>>(x, cc, pd, pid);
  k_knn_merge<4><<<dim3(B_*N_/256), 256, 0, stream>>>(pd, pid, idx);
  k_gpool_mlp<<<dim3(N_/64, B_), 256, 0, stream>>>(x, idx, g1a,g1ab,g1b,g1bb, g);
  k_cc<128><<<dim3(B_*N_/256), 256, 0, stream>>>(g, cc);
  k_knn_part<128,64,4><<<dim3(N_/256, 4, B_), 256, 0, stream>>>(g, cc, pd, pid);
  k_knn_merge<4><<<dim3(B_*N_/256), 256, 0, stream>>>(pd, pid, idx);
  k_hpool_max<<<dim3(N_/32, B_), 256, 0, stream>>>(g, idx, g2a,g2ab,g2b,g2bb, glob);
  k_code<<<dim3(B_), 512, 0, stream>>>(glob, m1,m1b,m2,m2b, f1a,f1ab, f2a,f2ab, base1, base2);
  k_fold<2><<<dim3((M_+31)/32, B_), 256, 0, stream>>>(base1, f1a, f1b, f1bb, f1c, f1cb, nullptr, mid);
  k_fold<3><<<dim3((M_+31)/32, B_), 256, 0, stream>>>(base2, f2a, f2b, f2bb, f2c, f2cb, mid, out);
}

// Round 2
// 5956.425 us; speedup vs baseline: 1.0351x; 1.0351x over previous
//
#include <hip/hip_runtime.h>
#include <stdint.h>

#define B_ 4
#define N_ 8192
#define K_ 16
#define FEAT_ 512
#define GRID_ 45
#define M_ (GRID_*GRID_)

// ---------- helpers ----------

__device__ __forceinline__ unsigned int fmap(float f){
  unsigned int u = __float_as_uint(f);
  return (u & 0x80000000u) ? ~u : (u | 0x80000000u);
}
__device__ __forceinline__ float funmap(unsigned int u){
  return (u & 0x80000000u) ? __uint_as_float(u ^ 0x80000000u) : __uint_as_float(~u);
}

// sorted top-16 insert, lexicographic (dist, index) -> order-independent,
// matches jax.lax.top_k tie-break (lower index first)
__device__ __forceinline__ void lex_insert(float (&d)[16], int (&id)[16], float v, int j){
  if (v < d[15] || (v == d[15] && j < id[15])){
    bool c[16];
#pragma unroll
    for (int s = 0; s < 16; ++s) c[s] = (v < d[s]) || (v == d[s] && j < id[s]);
#pragma unroll
    for (int s = 15; s >= 1; --s){
      d[s]  = c[s-1] ? d[s-1] : (c[s] ? v : d[s]);
      id[s] = c[s-1] ? id[s-1] : (c[s] ? j : id[s]);
    }
    if (c[0]){ d[0] = v; id[0] = j; }
  }
}

// LDS chunk swizzle for [rows][128 float] tiles: 16B chunk c of row r stored at
// c ^ ((c>>3)&3) ^ ((r>>3)&7)  -- involution; balances banks for
// stride-8-word reads, row-column scans, and 8-row-strided writes.
__device__ __forceinline__ int swz(int row, int col){
  int c = col >> 2;
  c ^= (c >> 3) & 3;
  c ^= (row >> 3) & 7;
  return (row << 7) + (c << 2) + (col & 3);
}

#define GLDS(l, g) __builtin_amdgcn_global_load_lds((const __attribute__((address_space(1))) void*)(g), (__attribute__((address_space(3))) void*)(l), 16, 0, 0)

// ---------- init ----------
__global__ void k_init(unsigned int* glob){
  int i = blockIdx.x*256 + threadIdx.x;
  if (i < B_*1024) glob[i] = 0x007FFFFFu;   // fmap(-inf)
}

// ---------- KNN #1: nearest other point ----------
__global__ __launch_bounds__(256) void k_nn1(const float* __restrict__ pts,
                                             unsigned long long* __restrict__ nn64){
  __shared__ float sp[2048*3];
  int b = blockIdx.z, s = blockIdx.y;
  int c0 = s*2048;
  const float* P = pts + (size_t)b*N_*3;
  for (int i = threadIdx.x; i < 2048*3; i += 256) sp[i] = P[c0*3 + i];
  __syncthreads();
  int n = blockIdx.x*256 + threadIdx.x;
  float qx = P[n*3], qy = P[n*3+1], qz = P[n*3+2];
  float best = 1e30f; int bi = 0;
  for (int j = 0; j < 2048; ++j){
    float dx = qx - sp[j*3], dy = qy - sp[j*3+1], dz = qz - sp[j*3+2];
    float d2 = fmaf(dx,dx, fmaf(dy,dy, dz*dz));
    int cj = c0 + j;
    if (d2 < best && cj != n){ best = d2; bi = cj; }
  }
  unsigned long long key = ((unsigned long long)__float_as_uint(best) << 32) | (unsigned int)bi;
  atomicMin(&nn64[(size_t)b*N_ + n], key);
}

// ---------- local_cov + 3 convs (12->64->64->64, relu each) ----------
__global__ __launch_bounds__(256) void k_cov_mlp(const float* __restrict__ pts,
    const unsigned long long* __restrict__ nn64,
    const float* __restrict__ w1, const float* __restrict__ b1,
    const float* __restrict__ w2, const float* __restrict__ b2,
    const float* __restrict__ w3, const float* __restrict__ b3,
    float* __restrict__ xout){
  __shared__ __align__(16) float W1t[12*64];
  __shared__ __align__(16) float W2t[64*64];
  __shared__ __align__(16) float W3t[64*64];
  __shared__ float B1[64], B2[64], B3[64];
  __shared__ __align__(16) float x0[64][12];
  __shared__ __align__(16) float h1[64][64];
  __shared__ __align__(16) float h2[64][64];
  int b = blockIdx.y; int n0 = blockIdx.x*64; int tid = threadIdx.x;
  for (int i = tid; i < 12*64; i += 256){ int o = i % 64, ci = i / 64; W1t[i] = w1[o*12 + ci]; }
  for (int i = tid; i < 64*64; i += 256){ int o = i % 64, ci = i / 64; W2t[i] = w2[o*64 + ci]; W3t[i] = w3[o*64 + ci]; }
  if (tid < 64){ B1[tid]=b1[tid]; B2[tid]=b2[tid]; B3[tid]=b3[tid]; }
  {
    int p = tid % 64, cg = tid / 64;
    int n = n0 + p;
    const float* P = pts + ((size_t)b*N_ + n)*3;
    int nb = (int)(nn64[(size_t)b*N_ + n] & 0xFFFFFFFFull);
    const float* Q = pts + ((size_t)b*N_ + nb)*3;
    if (cg == 0){ x0[p][0]=P[0]; x0[p][1]=P[1]; x0[p][2]=P[2]; }
    else { int i = cg-1; float pi = P[i];
      x0[p][3+i*3+0]=pi*Q[0]; x0[p][3+i*3+1]=pi*Q[1]; x0[p][3+i*3+2]=pi*Q[2]; }
  }
  __syncthreads();
  { int o = tid % 64, pg = tid / 64;
    for (int p = pg; p < 64; p += 4){
      float acc = B1[o];
#pragma unroll
      for (int ci = 0; ci < 12; ++ci) acc = fmaf(W1t[ci*64+o], x0[p][ci], acc);
      h1[p][o] = fmaxf(acc, 0.f);
    } }
  __syncthreads();
  { int o = tid % 64, pg = tid / 64;
    for (int p = pg; p < 64; p += 4){
      float acc = B2[o];
#pragma unroll
      for (int ci = 0; ci < 64; ++ci) acc = fmaf(W2t[ci*64+o], h1[p][ci], acc);
      h2[p][o] = fmaxf(acc, 0.f);
    } }
  __syncthreads();
  { int o = tid % 64, pg = tid / 64;
    for (int p = pg; p < 64; p += 4){
      float acc = B3[o];
#pragma unroll
      for (int ci = 0; ci < 64; ++ci) acc = fmaf(W3t[ci*64+o], h2[p][ci], acc);
      xout[((size_t)b*N_ + n0 + p)*64 + o] = fmaxf(acc, 0.f);
    } }
}

// ---------- transpose [B][N][C] -> [B][C][N] ----------
template<int C>
__global__ __launch_bounds__(256) void k_transpose(const float* __restrict__ src,
                                                   float* __restrict__ dst){
  __shared__ float t[64][65];
  int b = blockIdx.z, n0 = blockIdx.x*64, c0 = blockIdx.y*64;
  int tid = threadIdx.x;
#pragma unroll
  for (int u = 0; u < 4; ++u){
    int i = tid + 256*u; int p = i>>4, c4 = i&15;
    float4 v = *(const float4*)&src[((size_t)b*N_ + n0+p)*C + c0 + 4*c4];
    t[p][4*c4] = v.x; t[p][4*c4+1]=v.y; t[p][4*c4+2]=v.z; t[p][4*c4+3]=v.w;
  }
  __syncthreads();
#pragma unroll
  for (int u = 0; u < 4; ++u){
    int i = tid + 256*u; int ch = i>>4, p4 = i&15;
    float4 v = make_float4(t[4*p4][ch], t[4*p4+1][ch], t[4*p4+2][ch], t[4*p4+3][ch]);
    *(float4*)&dst[((size_t)b*C + c0+ch)*N_ + n0 + 4*p4] = v;
  }
}

// ---------- per-point squared norm ----------
template<int C>
__global__ void k_cc(const float* __restrict__ f, float* __restrict__ cc){
  int i = blockIdx.x*256 + threadIdx.x;
  if (i >= B_*N_) return;
  const float4* row = (const float4*)(f + (size_t)i*C);
  float acc = 0.f;
#pragma unroll
  for (int c4 = 0; c4 < C/4; ++c4){
    float4 v = row[c4];
    acc = fmaf(v.x,v.x,acc); acc = fmaf(v.y,v.y,acc);
    acc = fmaf(v.z,v.z,acc); acc = fmaf(v.w,v.w,acc);
  }
  cc[i] = acc;
}

// ---------- KNN as register-tiled GEMM + fused top-16 ----------
// block: 256 thr = 16tx x 16ty; tile 128 queries x 128 candidates, 8x8/thread.
// fT: channel-major features [B][C][N]; cc: squared norms.
template<int C, int S>
__global__ __launch_bounds__(256, 2) void k_knn2(const float* __restrict__ fT,
    const float* __restrict__ cc, float* __restrict__ pd, int* __restrict__ pid){
  __shared__ __align__(16) float At[16*128];
  __shared__ __align__(16) float Bt[16*128];
  __shared__ __align__(16) float Dt[128*128];
  const int tid = threadIdx.x;
  const int tx = tid & 15, ty = tid >> 4;
  const int b = blockIdx.z, s = blockIdx.y;
  const int q0 = blockIdx.x * 128;
  const int wv = tid >> 6, lane = tid & 63;
  const float* fTb = fT + (size_t)b * C * N_;
  const float* ccb = cc + (size_t)b * N_;
  const int qy = ty*8, cx = tx*8;

  float qq[8];
#pragma unroll
  for (int i = 0; i < 8; ++i) qq[i] = ccb[q0 + qy + i];

  float d[16]; int id[16];
#pragma unroll
  for (int t = 0; t < 16; ++t){ d[t] = 1e30f; id[t] = 0; }

  const int span = N_/S;
  const int jend = s*span + span;
  for (int t0 = s*span; t0 < jend; t0 += 128){
    float ccr[8];
    { float4 r0 = *(const float4*)&ccb[t0 + cx];
      float4 r1 = *(const float4*)&ccb[t0 + cx + 4];
      ccr[0]=r0.x; ccr[1]=r0.y; ccr[2]=r0.z; ccr[3]=r0.w;
      ccr[4]=r1.x; ccr[5]=r1.y; ccr[6]=r1.z; ccr[7]=r1.w; }
    float acc[8][8];
#pragma unroll
    for (int i = 0; i < 8; ++i)
#pragma unroll
      for (int j = 0; j < 8; ++j) acc[i][j] = 0.f;

    for (int ck = 0; ck < C/16; ++ck){
      __syncthreads();
      // stage A (queries) and B (candidates): linear LDS dest, inverse-swizzled
      // global source (rule: linear dest + inv-swz source + swz on read)
#pragma unroll
      for (int j = 0; j < 2; ++j){
        int p = (wv<<7) + (j<<6) + lane;           // chunk index in tile
        int r = p >> 5, csn = p & 31;
        int cn = csn ^ ((csn>>3)&3) ^ ((r>>3)&7);  // source chunk
        const float* gA = fTb + (size_t)(ck*16 + r)*N_ + q0 + (cn<<2);
        const float* gB = fTb + (size_t)(ck*16 + r)*N_ + t0 + (cn<<2);
        GLDS(&At[(((wv<<7) + (j<<6))<<2)], gA);
        GLDS(&Bt[(((wv<<7) + (j<<6))<<2)], gB);
      }
      asm volatile("s_waitcnt vmcnt(0)" ::: "memory");
      __syncthreads();
#pragma unroll
      for (int c = 0; c < 16; ++c){
        float4 a0 = *(const float4*)&At[swz(c, qy)];
        float4 a1 = *(const float4*)&At[swz(c, qy+4)];
        float4 b0 = *(const float4*)&Bt[swz(c, cx)];
        float4 b1 = *(const float4*)&Bt[swz(c, cx+4)];
        float av[8] = {a0.x,a0.y,a0.z,a0.w,a1.x,a1.y,a1.z,a1.w};
        float bv[8] = {b0.x,b0.y,b0.z,b0.w,b1.x,b1.y,b1.z,b1.w};
#pragma unroll
        for (int i = 0; i < 8; ++i)
#pragma unroll
          for (int jj = 0; jj < 8; ++jj)
            acc[i][jj] = fmaf(av[i], bv[jj], acc[i][jj]);
      }
    }
    // distances -> D tile (swizzled)
#pragma unroll
    for (int i = 0; i < 8; ++i){
      float4 w0, w1;
      w0.x = fmaf(-2.f, acc[i][0], qq[i] + ccr[0]);
      w0.y = fmaf(-2.f, acc[i][1], qq[i] + ccr[1]);
      w0.z = fmaf(-2.f, acc[i][2], qq[i] + ccr[2]);
      w0.w = fmaf(-2.f, acc[i][3], qq[i] + ccr[3]);
      w1.x = fmaf(-2.f, acc[i][4], qq[i] + ccr[4]);
      w1.y = fmaf(-2.f, acc[i][5], qq[i] + ccr[5]);
      w1.z = fmaf(-2.f, acc[i][6], qq[i] + ccr[6]);
      w1.w = fmaf(-2.f, acc[i][7], qq[i] + ccr[7]);
      *(float4*)&Dt[swz(qy+i, cx)]   = w0;
      *(float4*)&Dt[swz(qy+i, cx+4)] = w1;
    }
    __syncthreads();
    if (tid < 128){
#pragma unroll 4
      for (int c = 0; c < 32; ++c){
        float4 v = *(const float4*)&Dt[swz(tid, c<<2)];
        int cb = t0 + (c<<2);
        lex_insert(d,id,v.x,cb);   lex_insert(d,id,v.y,cb+1);
        lex_insert(d,id,v.z,cb+2); lex_insert(d,id,v.w,cb+3);
      }
    }
    // no barrier needed: next iteration's first __syncthreads() separates
  }
  if (tid < 128){
    size_t base = ((size_t)(b*N_ + q0 + tid)*S + s)*16;
#pragma unroll
    for (int t = 0; t < 16; ++t){ pd[base+t] = d[t]; pid[base+t] = id[t]; }
  }
}

template<int S>
__global__ void k_knn_merge(const float* __restrict__ pd, const int* __restrict__ pid,
                            int* __restrict__ idxout){
  int i = blockIdx.x*256 + threadIdx.x;
  if (i >= B_*N_) return;
  float d[16]; int id[16];
#pragma unroll
  for (int t = 0; t < 16; ++t){ d[t] = 1e30f; id[t] = 0; }
  size_t base = (size_t)i*S*16;
  for (int t = 0; t < S*16; ++t) lex_insert(d, id, pd[base+t], pid[base+t]);
  for (int t = 0; t < 16; ++t) idxout[(size_t)i*16 + t] = id[t];
}

// ---------- maxpool(x) + conv 64->64 relu + conv 64->128 ----------
__global__ __launch_bounds__(256) void k_gpool_mlp(const float* __restrict__ x,
    const int* __restrict__ idx,
    const float* __restrict__ g1a, const float* __restrict__ g1ab,
    const float* __restrict__ g1b, const float* __restrict__ g1bb,
    float* __restrict__ gout){
  __shared__ __align__(16) float Wt1[64*64];
  __shared__ __align__(16) float Wt2[64*128];
  __shared__ float Ba[64], Bb[128];
  __shared__ __align__(16) float m[64][64];
  __shared__ __align__(16) float r[64][64];
  int b = blockIdx.y; int n0 = blockIdx.x*64; int tid = threadIdx.x;
  for (int i = tid; i < 64*64; i += 256){ int o = i%64, ci = i/64; Wt1[i] = g1a[o*64+ci]; }
  for (int i = tid; i < 64*128; i += 256){ int o = i%128, ci = i/128; Wt2[i] = g1b[o*64+ci]; }
  if (tid < 64) Ba[tid] = g1ab[tid];
  if (tid < 128) Bb[tid] = g1bb[tid];
  { int p = tid/4, cg = tid%4; int n = n0 + p;
    const int* ip = idx + ((size_t)b*N_ + n)*16;
    float mm[16];
#pragma unroll
    for (int u = 0; u < 16; ++u) mm[u] = -1e30f;
    for (int k = 0; k < 16; ++k){
      int nb = ip[k];
      const float4* src = (const float4*)(x + ((size_t)b*N_ + nb)*64 + cg*16);
#pragma unroll
      for (int u = 0; u < 4; ++u){
        float4 v = src[u];
        mm[4*u  ] = fmaxf(mm[4*u  ], v.x); mm[4*u+1] = fmaxf(mm[4*u+1], v.y);
        mm[4*u+2] = fmaxf(mm[4*u+2], v.z); mm[4*u+3] = fmaxf(mm[4*u+3], v.w);
      }
    }
#pragma unroll
    for (int u = 0; u < 16; ++u) m[p][cg*16+u] = mm[u];
  }
  __syncthreads();
  { int o = tid%64, pg = tid/64;
    float acc[16];
#pragma unroll
    for (int u = 0; u < 16; ++u) acc[u] = Ba[o];
    for (int ci = 0; ci < 64; ci += 4){
      float w0 = Wt1[ci*64+o], w1_ = Wt1[(ci+1)*64+o], w2_ = Wt1[(ci+2)*64+o], w3_ = Wt1[(ci+3)*64+o];
#pragma unroll
      for (int u = 0; u < 16; ++u){
        float4 mv = *(const float4*)&m[pg*16+u][ci];
        acc[u] = fmaf(w0, mv.x, acc[u]); acc[u] = fmaf(w1_, mv.y, acc[u]);
        acc[u] = fmaf(w2_, mv.z, acc[u]); acc[u] = fmaf(w3_, mv.w, acc[u]);
      }
    }
#pragma unroll
    for (int u = 0; u < 16; ++u) r[pg*16+u][o] = fmaxf(acc[u], 0.f);
  }
  __syncthreads();
  { int o = tid%128, pg = tid/128;   // no relu on this conv
    float acc[32];
#pragma unroll
    for (int u = 0; u < 32; ++u) acc[u] = Bb[o];
    for (int ci = 0; ci < 64; ci += 4){
      float w0 = Wt2[ci*128+o], w1_ = Wt2[(ci+1)*128+o], w2_ = Wt2[(ci+2)*128+o], w3_ = Wt2[(ci+3)*128+o];
#pragma unroll
      for (int u = 0; u < 32; ++u){
        float4 rv = *(const float4*)&r[pg*32+u][ci];
        acc[u] = fmaf(w0, rv.x, acc[u]); acc[u] = fmaf(w1_, rv.y, acc[u]);
        acc[u] = fmaf(w2_, rv.z, acc[u]); acc[u] = fmaf(w3_, rv.w, acc[u]);
      }
    }
#pragma unroll
    for (int u = 0; u < 32; ++u)
      gout[((size_t)b*N_ + n0 + pg*32 + u)*128 + o] = acc[u];
  }
}

// ---------- maxpool(g) + conv 128->128 relu + conv 128->1024 + global max ----------
__global__ __launch_bounds__(256) void k_hpool_max(const float* __restrict__ g,
    const int* __restrict__ idx,
    const float* __restrict__ g2a, const float* __restrict__ g2ab,
    const float* __restrict__ g2b, const float* __restrict__ g2bb,
    unsigned int* __restrict__ glob){
  __shared__ __align__(16) float m[32][128];
  __shared__ __align__(16) float t[32][128];
  int b = blockIdx.y; int n0 = blockIdx.x*32; int tid = threadIdx.x;
  { int p = tid/8, cg = tid%8; int n = n0+p;
    const int* ip = idx + ((size_t)b*N_+n)*16;
    float mm[16];
#pragma unroll
    for (int u = 0; u < 16; ++u) mm[u] = -1e30f;
    for (int k = 0; k < 16; ++k){
      int nb = ip[k];
      const float4* src = (const float4*)(g + ((size_t)b*N_+nb)*128 + cg*16);
#pragma unroll
      for (int u = 0; u < 4; ++u){
        float4 v = src[u];
        mm[4*u  ] = fmaxf(mm[4*u  ], v.x); mm[4*u+1] = fmaxf(mm[4*u+1], v.y);
        mm[4*u+2] = fmaxf(mm[4*u+2], v.z); mm[4*u+3] = fmaxf(mm[4*u+3], v.w);
      }
    }
#pragma unroll
    for (int u = 0; u < 16; ++u) m[p][cg*16+u] = mm[u];
  }
  __syncthreads();
  { int o = tid%128, pg = tid/128;
    float acc[16];
#pragma unroll
    for (int u = 0; u < 16; ++u) acc[u] = g2ab[o];
    const float4* wrow = (const float4*)(g2a + (size_t)o*128);
    for (int c4 = 0; c4 < 32; ++c4){
      float4 wv = wrow[c4];
#pragma unroll
      for (int u = 0; u < 16; ++u){
        float4 mv = *(const float4*)&m[pg*16+u][c4*4];
        acc[u] = fmaf(wv.x,mv.x,acc[u]); acc[u] = fmaf(wv.y,mv.y,acc[u]);
        acc[u] = fmaf(wv.z,mv.z,acc[u]); acc[u] = fmaf(wv.w,mv.w,acc[u]);
      }
    }
#pragma unroll
    for (int u = 0; u < 16; ++u) t[pg*16+u][o] = fmaxf(acc[u], 0.f);
  }
  __syncthreads();
  for (int oc = 0; oc < 4; ++oc){
    int o = oc*256 + tid;
    const float4* wrow = (const float4*)(g2b + (size_t)o*128);
    float acc[32];
#pragma unroll
    for (int u = 0; u < 32; ++u) acc[u] = 0.f;
    for (int c4 = 0; c4 < 32; ++c4){
      float4 wv = wrow[c4];
#pragma unroll
      for (int u = 0; u < 32; ++u){
        float4 tv = *(const float4*)&t[u][c4*4];
        acc[u] = fmaf(wv.x,tv.x,acc[u]); acc[u] = fmaf(wv.y,tv.y,acc[u]);
        acc[u] = fmaf(wv.z,tv.z,acc[u]); acc[u] = fmaf(wv.w,tv.w,acc[u]);
      }
    }
    float bias = g2bb[o];
    float mx = -1e30f;
#pragma unroll
    for (int u = 0; u < 32; ++u) mx = fmaxf(mx, acc[u] + bias);
    atomicMax(&glob[b*1024 + o], fmap(mx));
  }
}

// ---------- code MLP + decoder base precompute ----------
__global__ __launch_bounds__(512) void k_code(const unsigned int* __restrict__ glob,
    const float* __restrict__ m1, const float* __restrict__ m1b,
    const float* __restrict__ m2, const float* __restrict__ m2b,
    const float* __restrict__ f1a, const float* __restrict__ f1ab,
    const float* __restrict__ f2a, const float* __restrict__ f2ab,
    float* __restrict__ base1, float* __restrict__ base2){
  __shared__ __align__(16) float gl_s[1024];
  __shared__ __align__(16) float hid_s[512];
  __shared__ __align__(16) float code_s[512];
  int b = blockIdx.x; int tid = threadIdx.x;
  for (int i = tid; i < 1024; i += 512) gl_s[i] = funmap(glob[b*1024+i]);
  __syncthreads();
  { float acc = m1b[tid];
    const float4* wr = (const float4*)(m1 + (size_t)tid*1024);
    for (int c4 = 0; c4 < 256; ++c4){ float4 wv = wr[c4]; float4 gv = *(const float4*)&gl_s[c4*4];
      acc = fmaf(wv.x,gv.x,acc); acc = fmaf(wv.y,gv.y,acc);
      acc = fmaf(wv.z,gv.z,acc); acc = fmaf(wv.w,gv.w,acc); }
    hid_s[tid] = fmaxf(acc, 0.f);
  }
  __syncthreads();
  { float acc = m2b[tid];
    const float4* wr = (const float4*)(m2 + (size_t)tid*512);
    for (int c4 = 0; c4 < 128; ++c4){ float4 wv = wr[c4]; float4 hv = *(const float4*)&hid_s[c4*4];
      acc = fmaf(wv.x,hv.x,acc); acc = fmaf(wv.y,hv.y,acc);
      acc = fmaf(wv.z,hv.z,acc); acc = fmaf(wv.w,hv.w,acc); }
    code_s[tid] = acc;
  }
  __syncthreads();
  { float acc = f1ab[tid];
    const float* wr = f1a + (size_t)tid*514;
    for (int c = 0; c < 512; ++c) acc = fmaf(wr[c], code_s[c], acc);
    base1[b*512 + tid] = acc;
  }
  { float acc = f2ab[tid];
    const float* wr = f2a + (size_t)tid*515;
    for (int c = 0; c < 512; ++c) acc = fmaf(wr[c], code_s[c], acc);
    base2[b*512 + tid] = acc;
  }
}

// ---------- folding decoder ----------
template<int NIN>
__global__ __launch_bounds__(256) void k_fold(const float* __restrict__ base,
    const float* __restrict__ fa,
    const float* __restrict__ fb, const float* __restrict__ fbb,
    const float* __restrict__ fc, const float* __restrict__ fcb,
    const float* __restrict__ pin, float* __restrict__ pout){
  __shared__ __align__(16) float y1[32][512];
  __shared__ __align__(16) float y2[32][516];
  __shared__ float pcoord[32][NIN];
  int b = blockIdx.y; int m0 = blockIdx.x*32; int tid = threadIdx.x;
  if (tid < 32*NIN){
    int p = tid / NIN, c = tid % NIN;
    int mm = min(m0 + p, M_-1);
    float v;
    if (NIN == 2){
      const float step = 0.6f/44.f;
      int ii = (c == 0) ? (mm/GRID_) : (mm%GRID_);
      v = -0.3f + step*ii;
    } else {
      v = pin[((size_t)b*M_ + mm)*3 + c];
    }
    pcoord[p][c] = v;
  }
  __syncthreads();
  const int stride_a = 512 + NIN;
  for (int rep = 0; rep < 2; ++rep){
    int o = rep*256 + tid;
    float av[NIN];
#pragma unroll
    for (int c = 0; c < NIN; ++c) av[c] = fa[(size_t)o*stride_a + 512 + c];
    float bv = base[b*512 + o];
    for (int p = 0; p < 32; ++p){
      float acc = bv;
#pragma unroll
      for (int c = 0; c < NIN; ++c) acc = fmaf(av[c], pcoord[p][c], acc);
      y1[p][o] = fmaxf(acc, 0.f);
    }
  }
  __syncthreads();
  for (int rep = 0; rep < 2; ++rep){
    int o2 = rep*256 + tid;
    const float* wr = fb + (size_t)o2*512;
    float acc[32];
#pragma unroll
    for (int u = 0; u < 32; ++u) acc[u] = 0.f;
    for (int c4 = 0; c4 < 128; ++c4){
      float4 wv = *(const float4*)&wr[c4*4];
#pragma unroll
      for (int u = 0; u < 32; ++u){
        float4 yv = *(const float4*)&y1[u][c4*4];
        acc[u] = fmaf(wv.x,yv.x,acc[u]); acc[u] = fmaf(wv.y,yv.y,acc[u]);
        acc[u] = fmaf(wv.z,yv.z,acc[u]); acc[u] = fmaf(wv.w,yv.w,acc[u]);
      }
    }
    float bias = fbb[o2];
#pragma unroll
    for (int u = 0; u < 32; ++u) y2[u][o2] = fmaxf(acc[u] + bias, 0.f);
  }
  __syncthreads();
  if (tid < 96){
    int p = tid / 3, c = tid % 3;
    const float* wr = fc + (size_t)c*512;
    float acc = fcb[c];
    for (int o4 = 0; o4 < 128; ++o4){
      float4 wv = *(const float4*)&wr[o4*4];
      float4 yv = *(const float4*)&y2[p][o4*4];
      acc = fmaf(wv.x,yv.x,acc); acc = fmaf(wv.y,yv.y,acc);
      acc = fmaf(wv.z,yv.z,acc); acc = fmaf(wv.w,yv.w,acc);
    }
    int mm = m0 + p;
    if (mm < M_) pout[((size_t)b*M_ + mm)*3 + c] = acc;
  }
}

// ---------- launcher ----------
extern "C" void kernel_launch(void* const* d_in, const int* in_sizes, int n_in,
                              void* d_out, int out_size, void* d_ws, size_t ws_size,
                              hipStream_t stream){
  const float* pts  = (const float*)d_in[0];
  const float* w1   = (const float*)d_in[1];  const float* b1   = (const float*)d_in[2];
  const float* w2   = (const float*)d_in[3];  const float* b2   = (const float*)d_in[4];
  const float* w3   = (const float*)d_in[5];  const float* b3   = (const float*)d_in[6];
  const float* g1a  = (const float*)d_in[7];  const float* g1ab = (const float*)d_in[8];
  const float* g1b  = (const float*)d_in[9];  const float* g1bb = (const float*)d_in[10];
  const float* g2a  = (const float*)d_in[11]; const float* g2ab = (const float*)d_in[12];
  const float* g2b  = (const float*)d_in[13]; const float* g2bb = (const float*)d_in[14];
  const float* m1   = (const float*)d_in[15]; const float* m1b  = (const float*)d_in[16];
  const float* m2   = (const float*)d_in[17]; const float* m2b  = (const float*)d_in[18];
  const float* f1a  = (const float*)d_in[19]; const float* f1ab = (const float*)d_in[20];
  const float* f1b  = (const float*)d_in[21]; const float* f1bb = (const float*)d_in[22];
  const float* f1c  = (const float*)d_in[23]; const float* f1cb = (const float*)d_in[24];
  const float* f2a  = (const float*)d_in[25]; const float* f2ab = (const float*)d_in[26];
  const float* f2b  = (const float*)d_in[27]; const float* f2bb = (const float*)d_in[28];
  const float* f2c  = (const float*)d_in[29]; const float* f2cb = (const float*)d_in[30];
  float* out = (float*)d_out;

  char* w = (char*)d_ws;
  auto alloc = [&](size_t bytes){ char* p = w; w += (bytes + 255) & ~(size_t)255; return p; };
  unsigned long long* nn64 = (unsigned long long*)alloc((size_t)B_*N_*8);
  float* x    = (float*)alloc((size_t)B_*N_*64*4);
  float* xT   = (float*)alloc((size_t)B_*N_*64*4);
  float* g    = (float*)alloc((size_t)B_*N_*128*4);
  float* gT   = (float*)alloc((size_t)B_*N_*128*4);
  float* cc   = (float*)alloc((size_t)B_*N_*4);
  int*   idx  = (int*)alloc((size_t)B_*N_*16*4);
  float* pd   = (float*)alloc((size_t)B_*N_*2*16*4);
  int*   pid  = (int*)alloc((size_t)B_*N_*2*16*4);
  unsigned int* glob = (unsigned int*)alloc((size_t)B_*1024*4);
  float* base1 = (float*)alloc((size_t)B_*512*4);
  float* base2 = (float*)alloc((size_t)B_*512*4);
  float* mid   = (float*)alloc((size_t)B_*M_*3*4);
  (void)ws_size; (void)in_sizes; (void)n_in; (void)out_size;

  hipMemsetAsync(nn64, 0xFF, (size_t)B_*N_*8, stream);
  k_init<<<dim3((B_*1024+255)/256), 256, 0, stream>>>(glob);
  k_nn1<<<dim3(N_/256, 4, B_), 256, 0, stream>>>(pts, nn64);
  k_cov_mlp<<<dim3(N_/64, B_), 256, 0, stream>>>(pts, nn64, w1,b1,w2,b2,w3,b3, x);
  k_transpose<64><<<dim3(N_/64, 1, B_), 256, 0, stream>>>(x, xT);
  k_cc<64><<<dim3(B_*N_/256), 256, 0, stream>>>(x, cc);
  k_knn2<64,2><<<dim3(N_/128, 2, B_), 256, 0, stream>>>(xT, cc, pd, pid);
  k_knn_merge<2><<<dim3(B_*N_/256), 256, 0, stream>>>(pd, pid, idx);
  k_gpool_mlp<<<dim3(N_/64, B_), 256, 0, stream>>>(x, idx, g1a,g1ab,g1b,g1bb, g);
  k_transpose<128><<<dim3(N_/64, 2, B_), 256, 0, stream>>>(g, gT);
  k_cc<128><<<dim3(B_*N_/256), 256, 0, stream>>>(g, cc);
  k_knn2<128,2><<<dim3(N_/128, 2, B_), 256, 0, stream>>>(gT, cc, pd, pid);
  k_knn_merge<2><<<dim3(B_*N_/256), 256, 0, stream>>>(pd, pid, idx);
  k_hpool_max<<<dim3(N_/32, B_), 256, 0, stream>>>(g, idx, g2a,g2ab,g2b,g2bb, glob);
  k_code<<<dim3(B_), 512, 0, stream>>>(glob, m1,m1b,m2,m2b, f1a,f1ab, f2a,f2ab, base1, base2);
  k_fold<2><<<dim3((M_+31)/32, B_), 256, 0, stream>>>(base1, f1a, f1b, f1bb, f1c, f1cb, nullptr, mid);
  k_fold<3><<<dim3((M_+31)/32, B_), 256, 0, stream>>>(base2, f2a, f2b, f2bb, f2c, f2cb, mid, out);
}

// Round 3
// 4509.045 us; speedup vs baseline: 1.3673x; 1.3210x over previous
//
#include <hip/hip_runtime.h>
#include <stdint.h>

#define B_ 4
#define N_ 8192
#define K_ 16
#define FEAT_ 512
#define GRID_ 45
#define M_ (GRID_*GRID_)

typedef unsigned long long ull;
typedef __bf16 bf16x8 __attribute__((ext_vector_type(8)));
typedef float f32x16 __attribute__((ext_vector_type(16)));

// ---------- helpers ----------

__device__ __forceinline__ unsigned int fmap(float f){
  unsigned int u = __float_as_uint(f);
  return (u & 0x80000000u) ? ~u : (u | 0x80000000u);
}
__device__ __forceinline__ float funmap(unsigned int u){
  return (u & 0x80000000u) ? __uint_as_float(u ^ 0x80000000u) : __uint_as_float(~u);
}

// sorted top-16 insert on packed (fmap(dist)<<32 | idx) keys: lex order ==
// jax.lax.top_k tie-break (lower index first). Order-independent.
__device__ __forceinline__ void ins16(ull (&d)[16], ull k){
  if (k < d[15]){
    bool c[16];
#pragma unroll
    for (int s = 0; s < 16; ++s) c[s] = k < d[s];
#pragma unroll
    for (int s = 15; s >= 1; --s) d[s] = c[s-1] ? d[s-1] : (c[s] ? k : d[s]);
    if (c[0]) d[0] = k;
  }
}

#define GLDS(l, g) __builtin_amdgcn_global_load_lds((const __attribute__((address_space(1))) void*)(g), (__attribute__((address_space(3))) void*)(l), 16, 0, 0)

// ---------- init ----------
__global__ void k_init(unsigned int* glob){
  int i = blockIdx.x*256 + threadIdx.x;
  if (i < B_*1024) glob[i] = 0x007FFFFFu;   // fmap(-inf)
}

// ---------- KNN #1: nearest other point (exact fp32) ----------
__global__ __launch_bounds__(256) void k_nn1(const float* __restrict__ pts,
                                             unsigned long long* __restrict__ nn64){
  __shared__ float sp[2048*3];
  int b = blockIdx.z, s = blockIdx.y;
  int c0 = s*2048;
  const float* P = pts + (size_t)b*N_*3;
  for (int i = threadIdx.x; i < 2048*3; i += 256) sp[i] = P[c0*3 + i];
  __syncthreads();
  int n = blockIdx.x*256 + threadIdx.x;
  float qx = P[n*3], qy = P[n*3+1], qz = P[n*3+2];
  float best = 1e30f; int bi = 0;
  for (int j = 0; j < 2048; ++j){
    float dx = qx - sp[j*3], dy = qy - sp[j*3+1], dz = qz - sp[j*3+2];
    float d2 = fmaf(dx,dx, fmaf(dy,dy, dz*dz));
    int cj = c0 + j;
    if (d2 < best && cj != n){ best = d2; bi = cj; }
  }
  unsigned long long key = ((unsigned long long)__float_as_uint(best) << 32) | (unsigned int)bi;
  atomicMin(&nn64[(size_t)b*N_ + n], key);
}

// ---------- local_cov + 3 convs (12->64->64->64, relu each) ----------
__global__ __launch_bounds__(256) void k_cov_mlp(const float* __restrict__ pts,
    const unsigned long long* __restrict__ nn64,
    const float* __restrict__ w1, const float* __restrict__ b1,
    const float* __restrict__ w2, const float* __restrict__ b2,
    const float* __restrict__ w3, const float* __restrict__ b3,
    float* __restrict__ xout){
  __shared__ __align__(16) float W1t[12*64];
  __shared__ __align__(16) float W2t[64*64];
  __shared__ __align__(16) float W3t[64*64];
  __shared__ float B1[64], B2[64], B3[64];
  __shared__ __align__(16) float x0[64][12];
  __shared__ __align__(16) float h1[64][64];
  __shared__ __align__(16) float h2[64][64];
  int b = blockIdx.y; int n0 = blockIdx.x*64; int tid = threadIdx.x;
  for (int i = tid; i < 12*64; i += 256){ int o = i % 64, ci = i / 64; W1t[i] = w1[o*12 + ci]; }
  for (int i = tid; i < 64*64; i += 256){ int o = i % 64, ci = i / 64; W2t[i] = w2[o*64 + ci]; W3t[i] = w3[o*64 + ci]; }
  if (tid < 64){ B1[tid]=b1[tid]; B2[tid]=b2[tid]; B3[tid]=b3[tid]; }
  {
    int p = tid % 64, cg = tid / 64;
    int n = n0 + p;
    const float* P = pts + ((size_t)b*N_ + n)*3;
    int nb = (int)(nn64[(size_t)b*N_ + n] & 0xFFFFFFFFull);
    const float* Q = pts + ((size_t)b*N_ + nb)*3;
    if (cg == 0){ x0[p][0]=P[0]; x0[p][1]=P[1]; x0[p][2]=P[2]; }
    else { int i = cg-1; float pi = P[i];
      x0[p][3+i*3+0]=pi*Q[0]; x0[p][3+i*3+1]=pi*Q[1]; x0[p][3+i*3+2]=pi*Q[2]; }
  }
  __syncthreads();
  { int o = tid % 64, pg = tid / 64;
    for (int p = pg; p < 64; p += 4){
      float acc = B1[o];
#pragma unroll
      for (int ci = 0; ci < 12; ++ci) acc = fmaf(W1t[ci*64+o], x0[p][ci], acc);
      h1[p][o] = fmaxf(acc, 0.f);
    } }
  __syncthreads();
  { int o = tid % 64, pg = tid / 64;
    for (int p = pg; p < 64; p += 4){
      float acc = B2[o];
#pragma unroll
      for (int ci = 0; ci < 64; ++ci) acc = fmaf(W2t[ci*64+o], h1[p][ci], acc);
      h2[p][o] = fmaxf(acc, 0.f);
    } }
  __syncthreads();
  { int o = tid % 64, pg = tid / 64;
    for (int p = pg; p < 64; p += 4){
      float acc = B3[o];
#pragma unroll
      for (int ci = 0; ci < 64; ++ci) acc = fmaf(W3t[ci*64+o], h2[p][ci], acc);
      xout[((size_t)b*N_ + n0 + p)*64 + o] = fmaxf(acc, 0.f);
    } }
}

// ---------- bf16 hi/lo split + squared norms ----------
template<int C>
__global__ __launch_bounds__(256) void k_prep(const float* __restrict__ f,
    unsigned short* __restrict__ fh, unsigned short* __restrict__ fl,
    float* __restrict__ cc){
  constexpr int P = C/32;
  int i = blockIdx.x*256 + threadIdx.x;
  int row = i / P, part = i % P;
  if (row >= B_*N_) return;
  const float* src = f + (size_t)row*C + part*32;
  unsigned short hs[32], ls[32];
  float ss = 0.f;
#pragma unroll
  for (int c4 = 0; c4 < 8; ++c4){
    float4 v = *(const float4*)&src[c4*4];
    float vv[4] = {v.x, v.y, v.z, v.w};
#pragma unroll
    for (int u = 0; u < 4; ++u){
      float x = vv[u];
      ss = fmaf(x, x, ss);
      __bf16 h = (__bf16)x;
      __bf16 l = (__bf16)(x - (float)h);
      hs[c4*4+u] = __builtin_bit_cast(unsigned short, h);
      ls[c4*4+u] = __builtin_bit_cast(unsigned short, l);
    }
  }
  unsigned short* dh = fh + (size_t)row*C + part*32;
  unsigned short* dl = fl + (size_t)row*C + part*32;
#pragma unroll
  for (int c = 0; c < 4; ++c){
    *(uint4*)&dh[c*8] = *(uint4*)&hs[c*8];
    *(uint4*)&dl[c*8] = *(uint4*)&ls[c*8];
  }
#pragma unroll
  for (int off = 1; off < P; off <<= 1) ss += __shfl_xor(ss, off);
  if (part == 0) cc[row] = ss;
}

// ---------- KNN via bf16-split MFMA (D^T layout, register top-16) ----------
// block 256 thr / 4 waves (2c x 2q of 64x64); tile 128 cand x 128 query.
// Q resident in LDS (swizzled); cand streamed in 64-ch chunks, dbuf GLDS.
template<int C>
__global__ __launch_bounds__(256, 1) void k_knn3(
    const unsigned short* __restrict__ fh, const unsigned short* __restrict__ fl,
    const float* __restrict__ ccg, int* __restrict__ idxout){
  extern __shared__ char smem[];
  constexpr int QBYTES = 128*C*2;
  constexpr int RC = C/8;         // 16B chunks per Q row
  constexpr int QMASK = RC-1;
  constexpr int CKS = C/64;       // 64-ch stages per cand tile
  char* qh = smem;
  char* ql = smem + QBYTES;
  char* a0 = smem + 2*QBYTES;     // 2 bufs x (Ah 16KB + Al 16KB)
  char* ccs = smem + 2*QBYTES + 65536;  // 2 x 512B

  const int tid = threadIdx.x, lane = tid & 63, wid = tid >> 6;
  const int wc = wid & 1, wq = wid >> 1;
  const int b = blockIdx.y, q0 = blockIdx.x*128;
  const unsigned short* fhb = fh + (size_t)b*N_*C;
  const unsigned short* flb = fl + (size_t)b*N_*C;
  const float* ccb = ccg + (size_t)b*N_;

  // stage resident Q (hi & lo), swizzled chunks
  for (int p = tid; p < 128*RC; p += 256){
    int q = p / RC, c = p % RC;
    int cs = c ^ (q & QMASK);
    *(float4*)(qh + q*(C*2) + cs*16) = *(const float4*)(fhb + (size_t)(q0+q)*C + c*8);
    *(float4*)(ql + q*(C*2) + cs*16) = *(const float4*)(flb + (size_t)(q0+q)*C + c*8);
  }

  // A staging: linear LDS dest, inverse-swizzled global source
  auto stageA = [&](int buf, int t0, int ck){
    char* ah = a0 + buf*32768;
#pragma unroll
    for (int jj = 0; jj < 4; ++jj){
      int p = jj*256 + (wid<<6) + lane;
      int r = p >> 3, csw = p & 7;
      int c = csw ^ (r & 7);
      const unsigned short* sh = fhb + (size_t)(t0 + r)*C + ck*64 + c*8;
      const unsigned short* sl = flb + (size_t)(t0 + r)*C + ck*64 + c*8;
      GLDS(ah + (jj*256 + (wid<<6))*16, sh);
      GLDS(ah + 16384 + (jj*256 + (wid<<6))*16, sl);
    }
  };

  f32x16 acc[2][2];
  ull dd[2][16];
#pragma unroll
  for (int j = 0; j < 2; ++j)
#pragma unroll
    for (int t = 0; t < 16; ++t) dd[j][t] = ~0ull;

  stageA(0, 0, 0);
  float4 ccreg;
  if (tid < 32) ccreg = *(const float4*)&ccb[tid*4];

  const int NSTEP = 64*CKS;
  for (int s = 0; s < NSTEP; ++s){
    const int buf = s & 1;
    const int t0 = (s/CKS)*128;
    const int ck = (CKS == 2) ? (s & 1) : 0;
    const int tb = (s/CKS) & 1;
    asm volatile("s_waitcnt vmcnt(0)" ::: "memory");
    if (ck == 0 && tid < 32) *(float4*)(ccs + tb*512 + tid*16) = ccreg;
    __syncthreads();
    if (s+1 < NSTEP){
      int nt0 = ((s+1)/CKS)*128;
      int nck = (CKS == 2) ? ((s+1) & 1) : 0;
      stageA((s+1)&1, nt0, nck);
    }
    if (ck == CKS-1 && tid < 32){
      int nt = s/CKS + 1;
      if (nt < 64) ccreg = *(const float4*)&ccb[nt*128 + tid*4];
    }
    if (ck == 0){
#pragma unroll
      for (int i = 0; i < 2; ++i)
#pragma unroll
        for (int j = 0; j < 2; ++j) acc[i][j] = (f32x16)(0.0f);
    }
    char* ah = a0 + buf*32768;
    char* al = ah + 16384;
#pragma unroll
    for (int kc = 0; kc < 4; ++kc){
      bf16x8 bhf[2], blf[2];
#pragma unroll
      for (int j = 0; j < 2; ++j){
        int q = wq*64 + j*32 + (lane & 31);
        int chunk = (ck*4 + kc)*2 + (lane >> 5);
        int cs = chunk ^ (q & QMASK);
        bhf[j] = *(bf16x8*)(qh + q*(C*2) + cs*16);
        blf[j] = *(bf16x8*)(ql + q*(C*2) + cs*16);
      }
#pragma unroll
      for (int i = 0; i < 2; ++i){
        int r = wc*64 + i*32 + (lane & 31);
        int chunk = kc*2 + (lane >> 5);
        int cs = chunk ^ (r & 7);
        bf16x8 ahf = *(bf16x8*)(ah + r*128 + cs*16);
        bf16x8 alf = *(bf16x8*)(al + r*128 + cs*16);
#pragma unroll
        for (int j = 0; j < 2; ++j){
          acc[i][j] = __builtin_amdgcn_mfma_f32_32x32x16_bf16(ahf, bhf[j], acc[i][j], 0, 0, 0);
          acc[i][j] = __builtin_amdgcn_mfma_f32_32x32x16_bf16(ahf, blf[j], acc[i][j], 0, 0, 0);
          acc[i][j] = __builtin_amdgcn_mfma_f32_32x32x16_bf16(alf, bhf[j], acc[i][j], 0, 0, 0);
        }
      }
    }
    if (ck == CKS-1){
      const float* cct = (const float*)(ccs + tb*512);
#pragma unroll
      for (int j = 0; j < 2; ++j)
#pragma unroll
        for (int i = 0; i < 2; ++i)
#pragma unroll
          for (int r = 0; r < 16; ++r){
            int rl = wc*64 + i*32 + 4*(lane>>5) + (r&3) + 8*(r>>2);
            float sv = fmaf(-2.f, acc[i][j][r], cct[rl]);
            ull key = ((ull)fmap(sv) << 32) | (unsigned)(t0 + rl);
            ins16(dd[j], key);
          }
    }
  }

  // merge 4 partial lists per query
  __syncthreads();
  ull* mbuf = (ull*)smem;      // [128 q][4 slots][16] = 64KB (overlaps Q/A areas)
  int slot = wc*2 + (lane>>5);
#pragma unroll
  for (int j = 0; j < 2; ++j){
    int q = wq*64 + j*32 + (lane & 31);
#pragma unroll
    for (int t = 0; t < 16; ++t) mbuf[(q*4 + slot)*16 + t] = dd[j][t];
  }
  __syncthreads();
  if (tid < 128){
    ull best[16];
#pragma unroll
    for (int t = 0; t < 16; ++t) best[t] = ~0ull;
    for (int t = 0; t < 64; ++t) ins16(best, mbuf[tid*64 + ((t + tid) & 63)]);
    int* op = idxout + ((size_t)b*N_ + q0 + tid)*16;
#pragma unroll
    for (int t = 0; t < 16; ++t) op[t] = (int)(best[t] & 0xffffffffu);
  }
}

// ---------- maxpool(x) + conv 64->64 relu + conv 64->128 ----------
__global__ __launch_bounds__(256) void k_gpool_mlp(const float* __restrict__ x,
    const int* __restrict__ idx,
    const float* __restrict__ g1a, const float* __restrict__ g1ab,
    const float* __restrict__ g1b, const float* __restrict__ g1bb,
    float* __restrict__ gout){
  __shared__ __align__(16) float Wt1[64*64];
  __shared__ __align__(16) float Wt2[64*128];
  __shared__ float Ba[64], Bb[128];
  __shared__ __align__(16) float m[64][64];
  __shared__ __align__(16) float r[64][64];
  int b = blockIdx.y; int n0 = blockIdx.x*64; int tid = threadIdx.x;
  for (int i = tid; i < 64*64; i += 256){ int o = i%64, ci = i/64; Wt1[i] = g1a[o*64+ci]; }
  for (int i = tid; i < 64*128; i += 256){ int o = i%128, ci = i/128; Wt2[i] = g1b[o*64+ci]; }
  if (tid < 64) Ba[tid] = g1ab[tid];
  if (tid < 128) Bb[tid] = g1bb[tid];
  { int p = tid/4, cg = tid%4; int n = n0 + p;
    const int* ip = idx + ((size_t)b*N_ + n)*16;
    float mm[16];
#pragma unroll
    for (int u = 0; u < 16; ++u) mm[u] = -1e30f;
    for (int k = 0; k < 16; ++k){
      int nb = ip[k];
      const float4* src = (const float4*)(x + ((size_t)b*N_ + nb)*64 + cg*16);
#pragma unroll
      for (int u = 0; u < 4; ++u){
        float4 v = src[u];
        mm[4*u  ] = fmaxf(mm[4*u  ], v.x); mm[4*u+1] = fmaxf(mm[4*u+1], v.y);
        mm[4*u+2] = fmaxf(mm[4*u+2], v.z); mm[4*u+3] = fmaxf(mm[4*u+3], v.w);
      }
    }
#pragma unroll
    for (int u = 0; u < 16; ++u) m[p][cg*16+u] = mm[u];
  }
  __syncthreads();
  { int o = tid%64, pg = tid/64;
    float acc[16];
#pragma unroll
    for (int u = 0; u < 16; ++u) acc[u] = Ba[o];
    for (int ci = 0; ci < 64; ci += 4){
      float w0 = Wt1[ci*64+o], w1_ = Wt1[(ci+1)*64+o], w2_ = Wt1[(ci+2)*64+o], w3_ = Wt1[(ci+3)*64+o];
#pragma unroll
      for (int u = 0; u < 16; ++u){
        float4 mv = *(const float4*)&m[pg*16+u][ci];
        acc[u] = fmaf(w0, mv.x, acc[u]); acc[u] = fmaf(w1_, mv.y, acc[u]);
        acc[u] = fmaf(w2_, mv.z, acc[u]); acc[u] = fmaf(w3_, mv.w, acc[u]);
      }
    }
#pragma unroll
    for (int u = 0; u < 16; ++u) r[pg*16+u][o] = fmaxf(acc[u], 0.f);
  }
  __syncthreads();
  { int o = tid%128, pg = tid/128;   // no relu on this conv
    float acc[32];
#pragma unroll
    for (int u = 0; u < 32; ++u) acc[u] = Bb[o];
    for (int ci = 0; ci < 64; ci += 4){
      float w0 = Wt2[ci*128+o], w1_ = Wt2[(ci+1)*128+o], w2_ = Wt2[(ci+2)*128+o], w3_ = Wt2[(ci+3)*128+o];
#pragma unroll
      for (int u = 0; u < 32; ++u){
        float4 rv = *(const float4*)&r[pg*32+u][ci];
        acc[u] = fmaf(w0, rv.x, acc[u]); acc[u] = fmaf(w1_, rv.y, acc[u]);
        acc[u] = fmaf(w2_, rv.z, acc[u]); acc[u] = fmaf(w3_, rv.w, acc[u]);
      }
    }
#pragma unroll
    for (int u = 0; u < 32; ++u)
      gout[((size_t)b*N_ + n0 + pg*32 + u)*128 + o] = acc[u];
  }
}

// ---------- maxpool(g) + conv 128->128 relu + conv 128->1024 + global max ----------
__global__ __launch_bounds__(256) void k_hpool_max(const float* __restrict__ g,
    const int* __restrict__ idx,
    const float* __restrict__ g2a, const float* __restrict__ g2ab,
    const float* __restrict__ g2b, const float* __restrict__ g2bb,
    unsigned int* __restrict__ glob){
  __shared__ __align__(16) float m[32][128];
  __shared__ __align__(16) float t[32][128];
  int b = blockIdx.y; int n0 = blockIdx.x*32; int tid = threadIdx.x;
  { int p = tid/8, cg = tid%8; int n = n0+p;
    const int* ip = idx + ((size_t)b*N_+n)*16;
    float mm[16];
#pragma unroll
    for (int u = 0; u < 16; ++u) mm[u] = -1e30f;
    for (int k = 0; k < 16; ++k){
      int nb = ip[k];
      const float4* src = (const float4*)(g + ((size_t)b*N_+nb)*128 + cg*16);
#pragma unroll
      for (int u = 0; u < 4; ++u){
        float4 v = src[u];
        mm[4*u  ] = fmaxf(mm[4*u  ], v.x); mm[4*u+1] = fmaxf(mm[4*u+1], v.y);
        mm[4*u+2] = fmaxf(mm[4*u+2], v.z); mm[4*u+3] = fmaxf(mm[4*u+3], v.w);
      }
    }
#pragma unroll
    for (int u = 0; u < 16; ++u) m[p][cg*16+u] = mm[u];
  }
  __syncthreads();
  { int o = tid%128, pg = tid/128;
    float acc[16];
#pragma unroll
    for (int u = 0; u < 16; ++u) acc[u] = g2ab[o];
    const float4* wrow = (const float4*)(g2a + (size_t)o*128);
    for (int c4 = 0; c4 < 32; ++c4){
      float4 wv = wrow[c4];
#pragma unroll
      for (int u = 0; u < 16; ++u){
        float4 mv = *(const float4*)&m[pg*16+u][c4*4];
        acc[u] = fmaf(wv.x,mv.x,acc[u]); acc[u] = fmaf(wv.y,mv.y,acc[u]);
        acc[u] = fmaf(wv.z,mv.z,acc[u]); acc[u] = fmaf(wv.w,mv.w,acc[u]);
      }
    }
#pragma unroll
    for (int u = 0; u < 16; ++u) t[pg*16+u][o] = fmaxf(acc[u], 0.f);
  }
  __syncthreads();
  for (int oc = 0; oc < 4; ++oc){
    int o = oc*256 + tid;
    const float4* wrow = (const float4*)(g2b + (size_t)o*128);
    float acc[32];
#pragma unroll
    for (int u = 0; u < 32; ++u) acc[u] = 0.f;
    for (int c4 = 0; c4 < 32; ++c4){
      float4 wv = wrow[c4];
#pragma unroll
      for (int u = 0; u < 32; ++u){
        float4 tv = *(const float4*)&t[u][c4*4];
        acc[u] = fmaf(wv.x,tv.x,acc[u]); acc[u] = fmaf(wv.y,tv.y,acc[u]);
        acc[u] = fmaf(wv.z,tv.z,acc[u]); acc[u] = fmaf(wv.w,tv.w,acc[u]);
      }
    }
    float bias = g2bb[o];
    float mx = -1e30f;
#pragma unroll
    for (int u = 0; u < 32; ++u) mx = fmaxf(mx, acc[u] + bias);
    atomicMax(&glob[b*1024 + o], fmap(mx));
  }
}

// ---------- code MLP + decoder base precompute ----------
__global__ __launch_bounds__(512) void k_code(const unsigned int* __restrict__ glob,
    const float* __restrict__ m1, const float* __restrict__ m1b,
    const float* __restrict__ m2, const float* __restrict__ m2b,
    const float* __restrict__ f1a, const float* __restrict__ f1ab,
    const float* __restrict__ f2a, const float* __restrict__ f2ab,
    float* __restrict__ base1, float* __restrict__ base2){
  __shared__ __align__(16) float gl_s[1024];
  __shared__ __align__(16) float hid_s[512];
  __shared__ __align__(16) float code_s[512];
  int b = blockIdx.x; int tid = threadIdx.x;
  for (int i = tid; i < 1024; i += 512) gl_s[i] = funmap(glob[b*1024+i]);
  __syncthreads();
  { float acc = m1b[tid];
    const float4* wr = (const float4*)(m1 + (size_t)tid*1024);
    for (int c4 = 0; c4 < 256; ++c4){ float4 wv = wr[c4]; float4 gv = *(const float4*)&gl_s[c4*4];
      acc = fmaf(wv.x,gv.x,acc); acc = fmaf(wv.y,gv.y,acc);
      acc = fmaf(wv.z,gv.z,acc); acc = fmaf(wv.w,gv.w,acc); }
    hid_s[tid] = fmaxf(acc, 0.f);
  }
  __syncthreads();
  { float acc = m2b[tid];
    const float4* wr = (const float4*)(m2 + (size_t)tid*512);
    for (int c4 = 0; c4 < 128; ++c4){ float4 wv = wr[c4]; float4 hv = *(const float4*)&hid_s[c4*4];
      acc = fmaf(wv.x,hv.x,acc); acc = fmaf(wv.y,hv.y,acc);
      acc = fmaf(wv.z,hv.z,acc); acc = fmaf(wv.w,hv.w,acc); }
    code_s[tid] = acc;
  }
  __syncthreads();
  { float acc = f1ab[tid];
    const float* wr = f1a + (size_t)tid*514;
    for (int c = 0; c < 512; ++c) acc = fmaf(wr[c], code_s[c], acc);
    base1[b*512 + tid] = acc;
  }
  { float acc = f2ab[tid];
    const float* wr = f2a + (size_t)tid*515;
    for (int c = 0; c < 512; ++c) acc = fmaf(wr[c], code_s[c], acc);
    base2[b*512 + tid] = acc;
  }
}

// ---------- folding decoder ----------
template<int NIN>
__global__ __launch_bounds__(256) void k_fold(const float* __restrict__ base,
    const float* __restrict__ fa,
    const float* __restrict__ fb, const float* __restrict__ fbb,
    const float* __restrict__ fc, const float* __restrict__ fcb,
    const float* __restrict__ pin, float* __restrict__ pout){
  __shared__ __align__(16) float y1[32][512];
  __shared__ __align__(16) float y2[32][516];
  __shared__ float pcoord[32][NIN];
  int b = blockIdx.y; int m0 = blockIdx.x*32; int tid = threadIdx.x;
  if (tid < 32*NIN){
    int p = tid / NIN, c = tid % NIN;
    int mm = min(m0 + p, M_-1);
    float v;
    if (NIN == 2){
      const float step = 0.6f/44.f;
      int ii = (c == 0) ? (mm/GRID_) : (mm%GRID_);
      v = -0.3f + step*ii;
    } else {
      v = pin[((size_t)b*M_ + mm)*3 + c];
    }
    pcoord[p][c] = v;
  }
  __syncthreads();
  const int stride_a = 512 + NIN;
  for (int rep = 0; rep < 2; ++rep){
    int o = rep*256 + tid;
    float av[NIN];
#pragma unroll
    for (int c = 0; c < NIN; ++c) av[c] = fa[(size_t)o*stride_a + 512 + c];
    float bv = base[b*512 + o];
    for (int p = 0; p < 32; ++p){
      float acc = bv;
#pragma unroll
      for (int c = 0; c < NIN; ++c) acc = fmaf(av[c], pcoord[p][c], acc);
      y1[p][o] = fmaxf(acc, 0.f);
    }
  }
  __syncthreads();
  for (int rep = 0; rep < 2; ++rep){
    int o2 = rep*256 + tid;
    const float* wr = fb + (size_t)o2*512;
    float acc[32];
#pragma unroll
    for (int u = 0; u < 32; ++u) acc[u] = 0.f;
    for (int c4 = 0; c4 < 128; ++c4){
      float4 wv = *(const float4*)&wr[c4*4];
#pragma unroll
      for (int u = 0; u < 32; ++u){
        float4 yv = *(const float4*)&y1[u][c4*4];
        acc[u] = fmaf(wv.x,yv.x,acc[u]); acc[u] = fmaf(wv.y,yv.y,acc[u]);
        acc[u] = fmaf(wv.z,yv.z,acc[u]); acc[u] = fmaf(wv.w,yv.w,acc[u]);
      }
    }
    float bias = fbb[o2];
#pragma unroll
    for (int u = 0; u < 32; ++u) y2[u][o2] = fmaxf(acc[u] + bias, 0.f);
  }
  __syncthreads();
  if (tid < 96){
    int p = tid / 3, c = tid % 3;
    const float* wr = fc + (size_t)c*512;
    float acc = fcb[c];
    for (int o4 = 0; o4 < 128; ++o4){
      float4 wv = *(const float4*)&wr[o4*4];
      float4 yv = *(const float4*)&y2[p][o4*4];
      acc = fmaf(wv.x,yv.x,acc); acc = fmaf(wv.y,yv.y,acc);
      acc = fmaf(wv.z,yv.z,acc); acc = fmaf(wv.w,yv.w,acc);
    }
    int mm = m0 + p;
    if (mm < M_) pout[((size_t)b*M_ + mm)*3 + c] = acc;
  }
}

// ---------- launcher ----------
extern "C" void kernel_launch(void* const* d_in, const int* in_sizes, int n_in,
                              void* d_out, int out_size, void* d_ws, size_t ws_size,
                              hipStream_t stream){
  const float* pts  = (const float*)d_in[0];
  const float* w1   = (const float*)d_in[1];  const float* b1   = (const float*)d_in[2];
  const float* w2   = (const float*)d_in[3];  const float* b2   = (const float*)d_in[4];
  const float* w3   = (const float*)d_in[5];  const float* b3   = (const float*)d_in[6];
  const float* g1a  = (const float*)d_in[7];  const float* g1ab = (const float*)d_in[8];
  const float* g1b  = (const float*)d_in[9];  const float* g1bb = (const float*)d_in[10];
  const float* g2a  = (const float*)d_in[11]; const float* g2ab = (const float*)d_in[12];
  const float* g2b  = (const float*)d_in[13]; const float* g2bb = (const float*)d_in[14];
  const float* m1   = (const float*)d_in[15]; const float* m1b  = (const float*)d_in[16];
  const float* m2   = (const float*)d_in[17]; const float* m2b  = (const float*)d_in[18];
  const float* f1a  = (const float*)d_in[19]; const float* f1ab = (const float*)d_in[20];
  const float* f1b  = (const float*)d_in[21]; const float* f1bb = (const float*)d_in[22];
  const float* f1c  = (const float*)d_in[23]; const float* f1cb = (const float*)d_in[24];
  const float* f2a  = (const float*)d_in[25]; const float* f2ab = (const float*)d_in[26];
  const float* f2b  = (const float*)d_in[27]; const float* f2bb = (const float*)d_in[28];
  const float* f2c  = (const float*)d_in[29]; const float* f2cb = (const float*)d_in[30];
  float* out = (float*)d_out;

  char* w = (char*)d_ws;
  auto alloc = [&](size_t bytes){ char* p = w; w += (bytes + 255) & ~(size_t)255; return p; };
  unsigned long long* nn64 = (unsigned long long*)alloc((size_t)B_*N_*8);
  float* x    = (float*)alloc((size_t)B_*N_*64*4);
  float* g    = (float*)alloc((size_t)B_*N_*128*4);
  unsigned short* xh = (unsigned short*)alloc((size_t)B_*N_*64*2);
  unsigned short* xl = (unsigned short*)alloc((size_t)B_*N_*64*2);
  unsigned short* gh = (unsigned short*)alloc((size_t)B_*N_*128*2);
  unsigned short* gl = (unsigned short*)alloc((size_t)B_*N_*128*2);
  float* ccf  = (float*)alloc((size_t)B_*N_*4);
  int*   idx  = (int*)alloc((size_t)B_*N_*16*4);
  unsigned int* glob = (unsigned int*)alloc((size_t)B_*1024*4);
  float* base1 = (float*)alloc((size_t)B_*512*4);
  float* base2 = (float*)alloc((size_t)B_*512*4);
  float* mid   = (float*)alloc((size_t)B_*M_*3*4);
  (void)ws_size; (void)in_sizes; (void)n_in; (void)out_size;

  const int SMEM64  = 2*(128*64*2)  + 65536 + 1024;   //  99,328 B
  const int SMEM128 = 2*(128*128*2) + 65536 + 1024;   // 132,096 B
  hipFuncSetAttribute((const void*)k_knn3<64>,  hipFuncAttributeMaxDynamicSharedMemorySize, SMEM64);
  hipFuncSetAttribute((const void*)k_knn3<128>, hipFuncAttributeMaxDynamicSharedMemorySize, SMEM128);

  hipMemsetAsync(nn64, 0xFF, (size_t)B_*N_*8, stream);
  k_init<<<dim3((B_*1024+255)/256), 256, 0, stream>>>(glob);
  k_nn1<<<dim3(N_/256, 4, B_), 256, 0, stream>>>(pts, nn64);
  k_cov_mlp<<<dim3(N_/64, B_), 256, 0, stream>>>(pts, nn64, w1,b1,w2,b2,w3,b3, x);
  k_prep<64><<<dim3(B_*N_*2/256), 256, 0, stream>>>(x, xh, xl, ccf);
  k_knn3<64><<<dim3(N_/128, B_), 256, SMEM64, stream>>>(xh, xl, ccf, idx);
  k_gpool_mlp<<<dim3(N_/64, B_), 256, 0, stream>>>(x, idx, g1a,g1ab,g1b,g1bb, g);
  k_prep<128><<<dim3(B_*N_*4/256), 256, 0, stream>>>(g, gh, gl, ccf);
  k_knn3<128><<<dim3(N_/128, B_), 256, SMEM128, stream>>>(gh, gl, ccf, idx);
  k_hpool_max<<<dim3(N_/32, B_), 256, 0, stream>>>(g, idx, g2a,g2ab,g2b,g2bb, glob);
  k_code<<<dim3(B_), 512, 0, stream>>>(glob, m1,m1b,m2,m2b, f1a,f1ab, f2a,f2ab, base1, base2);
  k_fold<2><<<dim3((M_+31)/32, B_), 256, 0, stream>>>(base1, f1a, f1b, f1bb, f1c, f1cb, nullptr, mid);
  k_fold<3><<<dim3((M_+31)/32, B_), 256, 0, stream>>>(base2, f2a, f2b, f2bb, f2c, f2cb, mid, out);
}

// Round 4
// 3727.712 us; speedup vs baseline: 1.6539x; 1.2096x over previous
//
#include <hip/hip_runtime.h>
#include <stdint.h>

#define B_ 4
#define N_ 8192
#define K_ 16
#define FEAT_ 512
#define GRID_ 45
#define M_ (GRID_*GRID_)

typedef unsigned long long ull;
typedef __bf16 bf16x8 __attribute__((ext_vector_type(8)));
typedef float f32x16 __attribute__((ext_vector_type(16)));

// ---------- helpers ----------

__device__ __forceinline__ unsigned int fmap(float f){
  unsigned int u = __float_as_uint(f);
  return (u & 0x80000000u) ? ~u : (u | 0x80000000u);
}
__device__ __forceinline__ float funmap(unsigned int u){
  return (u & 0x80000000u) ? __uint_as_float(u ^ 0x80000000u) : __uint_as_float(~u);
}

// sorted top-16 insert on packed (fmap(dist)<<32 | idx) keys: lex order ==
// jax.lax.top_k tie-break (lower index first). Order-independent.
__device__ __forceinline__ void ins16(ull (&d)[16], ull k){
  if (k < d[15]){
    bool c[16];
#pragma unroll
    for (int s = 0; s < 16; ++s) c[s] = k < d[s];
#pragma unroll
    for (int s = 15; s >= 1; --s) d[s] = c[s-1] ? d[s-1] : (c[s] ? k : d[s]);
    if (c[0]) d[0] = k;
  }
}

#define GLDS16(l, g) __builtin_amdgcn_global_load_lds((const __attribute__((address_space(1))) void*)(g), (__attribute__((address_space(3))) void*)(l), 16, 0, 0)
#define GLDS4(l, g)  __builtin_amdgcn_global_load_lds((const __attribute__((address_space(1))) void*)(g), (__attribute__((address_space(3))) void*)(l), 4, 0, 0)

// sentinel key = (fmap(+inf)<<32)|0xFFFFFFFF : sorts above all real keys
#define KEY_INF 0xFF800000FFFFFFFFull

// ---------- init ----------
__global__ void k_init(unsigned int* glob){
  int i = blockIdx.x*256 + threadIdx.x;
  if (i < B_*1024) glob[i] = 0x007FFFFFu;   // fmap(-inf)
}

// ---------- KNN #1: nearest other point (exact fp32) ----------
__global__ __launch_bounds__(256) void k_nn1(const float* __restrict__ pts,
                                             unsigned long long* __restrict__ nn64){
  __shared__ float sp[2048*3];
  int b = blockIdx.z, s = blockIdx.y;
  int c0 = s*2048;
  const float* P = pts + (size_t)b*N_*3;
  for (int i = threadIdx.x; i < 2048*3; i += 256) sp[i] = P[c0*3 + i];
  __syncthreads();
  int n = blockIdx.x*256 + threadIdx.x;
  float qx = P[n*3], qy = P[n*3+1], qz = P[n*3+2];
  float best = 1e30f; int bi = 0;
  for (int j = 0; j < 2048; ++j){
    float dx = qx - sp[j*3], dy = qy - sp[j*3+1], dz = qz - sp[j*3+2];
    float d2 = fmaf(dx,dx, fmaf(dy,dy, dz*dz));
    int cj = c0 + j;
    if (d2 < best && cj != n){ best = d2; bi = cj; }
  }
  unsigned long long key = ((unsigned long long)__float_as_uint(best) << 32) | (unsigned int)bi;
  atomicMin(&nn64[(size_t)b*N_ + n], key);
}

// ---------- local_cov + 3 convs (12->64->64->64, relu each) ----------
__global__ __launch_bounds__(256) void k_cov_mlp(const float* __restrict__ pts,
    const unsigned long long* __restrict__ nn64,
    const float* __restrict__ w1, const float* __restrict__ b1,
    const float* __restrict__ w2, const float* __restrict__ b2,
    const float* __restrict__ w3, const float* __restrict__ b3,
    float* __restrict__ xout){
  __shared__ __align__(16) float W1t[12*64];
  __shared__ __align__(16) float W2t[64*64];
  __shared__ __align__(16) float W3t[64*64];
  __shared__ float B1[64], B2[64], B3[64];
  __shared__ __align__(16) float x0[64][12];
  __shared__ __align__(16) float h1[64][64];
  __shared__ __align__(16) float h2[64][64];
  int b = blockIdx.y; int n0 = blockIdx.x*64; int tid = threadIdx.x;
  for (int i = tid; i < 12*64; i += 256){ int o = i % 64, ci = i / 64; W1t[i] = w1[o*12 + ci]; }
  for (int i = tid; i < 64*64; i += 256){ int o = i % 64, ci = i / 64; W2t[i] = w2[o*64 + ci]; W3t[i] = w3[o*64 + ci]; }
  if (tid < 64){ B1[tid]=b1[tid]; B2[tid]=b2[tid]; B3[tid]=b3[tid]; }
  {
    int p = tid % 64, cg = tid / 64;
    int n = n0 + p;
    const float* P = pts + ((size_t)b*N_ + n)*3;
    int nb = (int)(nn64[(size_t)b*N_ + n] & 0xFFFFFFFFull);
    const float* Q = pts + ((size_t)b*N_ + nb)*3;
    if (cg == 0){ x0[p][0]=P[0]; x0[p][1]=P[1]; x0[p][2]=P[2]; }
    else { int i = cg-1; float pi = P[i];
      x0[p][3+i*3+0]=pi*Q[0]; x0[p][3+i*3+1]=pi*Q[1]; x0[p][3+i*3+2]=pi*Q[2]; }
  }
  __syncthreads();
  { int o = tid % 64, pg = tid / 64;
    for (int p = pg; p < 64; p += 4){
      float acc = B1[o];
#pragma unroll
      for (int ci = 0; ci < 12; ++ci) acc = fmaf(W1t[ci*64+o], x0[p][ci], acc);
      h1[p][o] = fmaxf(acc, 0.f);
    } }
  __syncthreads();
  { int o = tid % 64, pg = tid / 64;
    for (int p = pg; p < 64; p += 4){
      float acc = B2[o];
#pragma unroll
      for (int ci = 0; ci < 64; ++ci) acc = fmaf(W2t[ci*64+o], h1[p][ci], acc);
      h2[p][o] = fmaxf(acc, 0.f);
    } }
  __syncthreads();
  { int o = tid % 64, pg = tid / 64;
    for (int p = pg; p < 64; p += 4){
      float acc = B3[o];
#pragma unroll
      for (int ci = 0; ci < 64; ++ci) acc = fmaf(W3t[ci*64+o], h2[p][ci], acc);
      xout[((size_t)b*N_ + n0 + p)*64 + o] = fmaxf(acc, 0.f);
    } }
}

// ---------- prep: bf16 hi/lo split into K-major granule layout + norms ----------
// T layout: [b][kf][pl 2][hi8 2][n 8192][16B granule]; granule = 8 bf16 ch.
template<int KF>
__global__ __launch_bounds__(256) void k_prep4(const float* __restrict__ f,
    unsigned short* __restrict__ T, float* __restrict__ cc){
  int b = blockIdx.y; int n = blockIdx.x*256 + threadIdx.x;
  const float* src = f + ((size_t)b*N_ + n)*(KF*16);
  char* Tb = (char*)T;
  float ss = 0.f;
#pragma unroll
  for (int kf = 0; kf < KF; ++kf){
    float v[16];
#pragma unroll
    for (int c4 = 0; c4 < 4; ++c4){
      float4 t4 = *(const float4*)&src[kf*16 + c4*4];
      v[c4*4]=t4.x; v[c4*4+1]=t4.y; v[c4*4+2]=t4.z; v[c4*4+3]=t4.w;
    }
    unsigned short hs[16], ls[16];
#pragma unroll
    for (int c = 0; c < 16; ++c){
      float x = v[c];
      ss = fmaf(x, x, ss);
      __bf16 h = (__bf16)x;
      __bf16 l = (__bf16)(x - (float)h);
      hs[c] = __builtin_bit_cast(unsigned short, h);
      ls[c] = __builtin_bit_cast(unsigned short, l);
    }
    size_t base = ((((size_t)b*KF + kf)*2)*2)*(size_t)(N_*16) + (size_t)n*16;
    const size_t HS = (size_t)N_*16;           // hi8 stride
    const size_t PS = 2*HS;                    // plane stride
    *(uint4*)(Tb + base)            = *(uint4*)&hs[0];
    *(uint4*)(Tb + base + HS)       = *(uint4*)&hs[8];
    *(uint4*)(Tb + base + PS)       = *(uint4*)&ls[0];
    *(uint4*)(Tb + base + PS + HS)  = *(uint4*)&ls[8];
  }
  cc[(size_t)b*N_ + n] = ss;
}

// ---------- KNN v4: Q-in-regs MFMA + threshold-filtered collective top-16 ----------
// block 256 thr / 4 waves; each wave owns 32 queries (col = lane&31);
// candidates streamed 64/tile via GLDS from K-major layout; S=1 (full scan).
template<int KF>
__global__ __launch_bounds__(256) void k_knn4(const unsigned short* __restrict__ T,
    const float* __restrict__ ccg, int* __restrict__ idxout){
  extern __shared__ char smem[];
  constexpr int ABUF = KF*4096;          // one candidate-tile buffer
  constexpr int CAP  = 6;                // per-thread passer queue depth
  char* As = smem;                       // 2*ABUF
  char* Cs = smem + 2*ABUF;              // 2*256 (cc tiles)
  char* Ps = smem + 2*ABUF + 512;        // 256*CAP*8 passer queues

  const int tid = threadIdx.x, lane = tid & 63, wid = tid >> 6;
  const int hi = lane >> 5, l31 = lane & 31;
  const int b = blockIdx.y, q0 = blockIdx.x*128;
  const char* Tb = (const char*)T;
  const size_t HS = (size_t)N_*16, PS = 2*HS, KS = 4*HS;
  const size_t Bb = (size_t)b*KF*KS;
  const float* ccb = ccg + (size_t)b*N_;

  // resident query fragments (hi & lo planes)
  const int q = q0 + wid*32 + l31;
  bf16x8 qh[KF], ql[KF];
#pragma unroll
  for (int kf = 0; kf < KF; ++kf){
    size_t o = Bb + kf*KS + hi*HS + (size_t)q*16;
    qh[kf] = *(const bf16x8*)(Tb + o);
    ql[kf] = *(const bf16x8*)(Tb + o + PS);
  }

  ull keys[16];
#pragma unroll
  for (int t = 0; t < 16; ++t) keys[t] = KEY_INF;
  float kapf = __builtin_inff();
  int cnt = 0;

  auto refresh_kap = [&](){
    unsigned kk = (unsigned)(keys[15] >> 32);
    kapf = (kk >= 0xFF800000u) ? __builtin_inff() : funmap(kk);
  };
  auto pushk = [&](float v, int idx){
    ull k = ((ull)fmap(v) << 32) | (unsigned)idx;
    if (cnt < CAP){ *(ull*)(Ps + (tid*CAP + cnt)*8) = k; ++cnt; }
    else { ins16(keys, k); refresh_kap(); }
  };
  auto drain = [&](){
    while (__any(cnt > 0)){
      if (cnt > 0){ --cnt; ins16(keys, *(const ull*)(Ps + (tid*CAP + cnt)*8)); }
    }
    refresh_kap();
  };
  auto stage = [&](int bf, int t0){
#pragma unroll
    for (int si = 0; si < KF; ++si){
      int s = wid + 4*si;                 // slice = (kf*2+pl)*2+hi
      int kf = s >> 2, pl = (s >> 1) & 1, h = s & 1;
      GLDS16(As + (bf*KF*4 + s)*1024,
             Tb + Bb + kf*KS + pl*PS + h*HS + (size_t)t0*16);
    }
    if (wid == 0) GLDS4(Cs + bf*256, (const char*)(ccb + t0));
  };

  stage(0, 0);
  for (int t = 0; t < 128; ++t){
    const int bf = t & 1, t0 = t*64;
    asm volatile("s_waitcnt vmcnt(0)" ::: "memory");
    __syncthreads();
    if (t + 1 < 128) stage(bf ^ 1, (t+1)*64);

    const char* Ab = As + bf*ABUF + hi*1024 + l31*16;
    f32x16 acc[2];
    acc[0] = (f32x16)(0.f); acc[1] = (f32x16)(0.f);
#pragma unroll
    for (int kf = 0; kf < KF; ++kf){
      bf16x8 ah0 = *(const bf16x8*)(Ab + kf*4096);
      bf16x8 ah1 = *(const bf16x8*)(Ab + kf*4096 + 512);
      bf16x8 al0 = *(const bf16x8*)(Ab + kf*4096 + 2048);
      bf16x8 al1 = *(const bf16x8*)(Ab + kf*4096 + 2048 + 512);
      acc[0] = __builtin_amdgcn_mfma_f32_32x32x16_bf16(ah0, qh[kf], acc[0], 0, 0, 0);
      acc[0] = __builtin_amdgcn_mfma_f32_32x32x16_bf16(ah0, ql[kf], acc[0], 0, 0, 0);
      acc[0] = __builtin_amdgcn_mfma_f32_32x32x16_bf16(al0, qh[kf], acc[0], 0, 0, 0);
      acc[1] = __builtin_amdgcn_mfma_f32_32x32x16_bf16(ah1, qh[kf], acc[1], 0, 0, 0);
      acc[1] = __builtin_amdgcn_mfma_f32_32x32x16_bf16(ah1, ql[kf], acc[1], 0, 0, 0);
      acc[1] = __builtin_amdgcn_mfma_f32_32x32x16_bf16(al1, qh[kf], acc[1], 0, 0, 0);
    }
    // selection: v = cc - 2<q,c>  (qq dropped: constant per-query shift)
    const float* cct = (const float*)(Cs + bf*256);
#pragma unroll
    for (int i = 0; i < 2; ++i){
#pragma unroll
      for (int rq = 0; rq < 4; ++rq){
        float4 c4 = *(const float4*)(cct + i*32 + 4*hi + 8*rq);
        int rowb = t0 + i*32 + 4*hi + 8*rq;
        float v0 = fmaf(-2.f, acc[i][rq*4+0], c4.x);
        float v1 = fmaf(-2.f, acc[i][rq*4+1], c4.y);
        float v2 = fmaf(-2.f, acc[i][rq*4+2], c4.z);
        float v3 = fmaf(-2.f, acc[i][rq*4+3], c4.w);
        if (v0 <= kapf) pushk(v0, rowb+0);
        if (v1 <= kapf) pushk(v1, rowb+1);
        if (v2 <= kapf) pushk(v2, rowb+2);
        if (v3 <= kapf) pushk(v3, rowb+3);
      }
    }
    if (__any(cnt >= 4)) drain();
  }
  drain();
  // merge the two k-half partial lists (lane <-> lane+32), write from lanes<32
#pragma unroll
  for (int tt = 0; tt < 16; ++tt){
    int lo = __shfl((int)(unsigned)keys[tt], (lane + 32) & 63);
    int hh = __shfl((int)(unsigned)(keys[tt] >> 32), (lane + 32) & 63);
    if (lane < 32) ins16(keys, ((ull)(unsigned)hh << 32) | (unsigned)lo);
  }
  if (lane < 32){
    int* op = idxout + ((size_t)b*N_ + q)*16;
#pragma unroll
    for (int tt = 0; tt < 16; ++tt) op[tt] = (int)(keys[tt] & 0xffffffffu);
  }
}

// ---------- maxpool(x) + conv 64->64 relu + conv 64->128 ----------
__global__ __launch_bounds__(256) void k_gpool_mlp(const float* __restrict__ x,
    const int* __restrict__ idx,
    const float* __restrict__ g1a, const float* __restrict__ g1ab,
    const float* __restrict__ g1b, const float* __restrict__ g1bb,
    float* __restrict__ gout){
  __shared__ __align__(16) float Wt1[64*64];
  __shared__ __align__(16) float Wt2[64*128];
  __shared__ float Ba[64], Bb[128];
  __shared__ __align__(16) float m[64][64];
  __shared__ __align__(16) float r[64][64];
  int b = blockIdx.y; int n0 = blockIdx.x*64; int tid = threadIdx.x;
  for (int i = tid; i < 64*64; i += 256){ int o = i%64, ci = i/64; Wt1[i] = g1a[o*64+ci]; }
  for (int i = tid; i < 64*128; i += 256){ int o = i%128, ci = i/128; Wt2[i] = g1b[o*64+ci]; }
  if (tid < 64) Ba[tid] = g1ab[tid];
  if (tid < 128) Bb[tid] = g1bb[tid];
  { int p = tid/4, cg = tid%4; int n = n0 + p;
    const int* ip = idx + ((size_t)b*N_ + n)*16;
    float mm[16];
#pragma unroll
    for (int u = 0; u < 16; ++u) mm[u] = -1e30f;
    for (int k = 0; k < 16; ++k){
      int nb = ip[k];
      const float4* src = (const float4*)(x + ((size_t)b*N_ + nb)*64 + cg*16);
#pragma unroll
      for (int u = 0; u < 4; ++u){
        float4 v = src[u];
        mm[4*u  ] = fmaxf(mm[4*u  ], v.x); mm[4*u+1] = fmaxf(mm[4*u+1], v.y);
        mm[4*u+2] = fmaxf(mm[4*u+2], v.z); mm[4*u+3] = fmaxf(mm[4*u+3], v.w);
      }
    }
#pragma unroll
    for (int u = 0; u < 16; ++u) m[p][cg*16+u] = mm[u];
  }
  __syncthreads();
  { int o = tid%64, pg = tid/64;
    float acc[16];
#pragma unroll
    for (int u = 0; u < 16; ++u) acc[u] = Ba[o];
    for (int ci = 0; ci < 64; ci += 4){
      float w0 = Wt1[ci*64+o], w1_ = Wt1[(ci+1)*64+o], w2_ = Wt1[(ci+2)*64+o], w3_ = Wt1[(ci+3)*64+o];
#pragma unroll
      for (int u = 0; u < 16; ++u){
        float4 mv = *(const float4*)&m[pg*16+u][ci];
        acc[u] = fmaf(w0, mv.x, acc[u]); acc[u] = fmaf(w1_, mv.y, acc[u]);
        acc[u] = fmaf(w2_, mv.z, acc[u]); acc[u] = fmaf(w3_, mv.w, acc[u]);
      }
    }
#pragma unroll
    for (int u = 0; u < 16; ++u) r[pg*16+u][o] = fmaxf(acc[u], 0.f);
  }
  __syncthreads();
  { int o = tid%128, pg = tid/128;   // no relu on this conv
    float acc[32];
#pragma unroll
    for (int u = 0; u < 32; ++u) acc[u] = Bb[o];
    for (int ci = 0; ci < 64; ci += 4){
      float w0 = Wt2[ci*128+o], w1_ = Wt2[(ci+1)*128+o], w2_ = Wt2[(ci+2)*128+o], w3_ = Wt2[(ci+3)*128+o];
#pragma unroll
      for (int u = 0; u < 32; ++u){
        float4 rv = *(const float4*)&r[pg*32+u][ci];
        acc[u] = fmaf(w0, rv.x, acc[u]); acc[u] = fmaf(w1_, rv.y, acc[u]);
        acc[u] = fmaf(w2_, rv.z, acc[u]); acc[u] = fmaf(w3_, rv.w, acc[u]);
      }
    }
#pragma unroll
    for (int u = 0; u < 32; ++u)
      gout[((size_t)b*N_ + n0 + pg*32 + u)*128 + o] = acc[u];
  }
}

// ---------- maxpool(g) + conv 128->128 relu + conv 128->1024 + global max ----------
__global__ __launch_bounds__(256) void k_hpool_max(const float* __restrict__ g,
    const int* __restrict__ idx,
    const float* __restrict__ g2a, const float* __restrict__ g2ab,
    const float* __restrict__ g2b, const float* __restrict__ g2bb,
    unsigned int* __restrict__ glob){
  __shared__ __align__(16) float m[32][128];
  __shared__ __align__(16) float t[32][128];
  int b = blockIdx.y; int n0 = blockIdx.x*32; int tid = threadIdx.x;
  { int p = tid/8, cg = tid%8; int n = n0+p;
    const int* ip = idx + ((size_t)b*N_+n)*16;
    float mm[16];
#pragma unroll
    for (int u = 0; u < 16; ++u) mm[u] = -1e30f;
    for (int k = 0; k < 16; ++k){
      int nb = ip[k];
      const float4* src = (const float4*)(g + ((size_t)b*N_+nb)*128 + cg*16);
#pragma unroll
      for (int u = 0; u < 4; ++u){
        float4 v = src[u];
        mm[4*u  ] = fmaxf(mm[4*u  ], v.x); mm[4*u+1] = fmaxf(mm[4*u+1], v.y);
        mm[4*u+2] = fmaxf(mm[4*u+2], v.z); mm[4*u+3] = fmaxf(mm[4*u+3], v.w);
      }
    }
#pragma unroll
    for (int u = 0; u < 16; ++u) m[p][cg*16+u] = mm[u];
  }
  __syncthreads();
  { int o = tid%128, pg = tid/128;
    float acc[16];
#pragma unroll
    for (int u = 0; u < 16; ++u) acc[u] = g2ab[o];
    const float4* wrow = (const float4*)(g2a + (size_t)o*128);
    for (int c4 = 0; c4 < 32; ++c4){
      float4 wv = wrow[c4];
#pragma unroll
      for (int u = 0; u < 16; ++u){
        float4 mv = *(const float4*)&m[pg*16+u][c4*4];
        acc[u] = fmaf(wv.x,mv.x,acc[u]); acc[u] = fmaf(wv.y,mv.y,acc[u]);
        acc[u] = fmaf(wv.z,mv.z,acc[u]); acc[u] = fmaf(wv.w,mv.w,acc[u]);
      }
    }
#pragma unroll
    for (int u = 0; u < 16; ++u) t[pg*16+u][o] = fmaxf(acc[u], 0.f);
  }
  __syncthreads();
  for (int oc = 0; oc < 4; ++oc){
    int o = oc*256 + tid;
    const float4* wrow = (const float4*)(g2b + (size_t)o*128);
    float acc[32];
#pragma unroll
    for (int u = 0; u < 32; ++u) acc[u] = 0.f;
    for (int c4 = 0; c4 < 32; ++c4){
      float4 wv = wrow[c4];
#pragma unroll
      for (int u = 0; u < 32; ++u){
        float4 tv = *(const float4*)&t[u][c4*4];
        acc[u] = fmaf(wv.x,tv.x,acc[u]); acc[u] = fmaf(wv.y,tv.y,acc[u]);
        acc[u] = fmaf(wv.z,tv.z,acc[u]); acc[u] = fmaf(wv.w,tv.w,acc[u]);
      }
    }
    float bias = g2bb[o];
    float mx = -1e30f;
#pragma unroll
    for (int u = 0; u < 32; ++u) mx = fmaxf(mx, acc[u] + bias);
    atomicMax(&glob[b*1024 + o], fmap(mx));
  }
}

// ---------- code MLP + decoder base precompute ----------
__global__ __launch_bounds__(512) void k_code(const unsigned int* __restrict__ glob,
    const float* __restrict__ m1, const float* __restrict__ m1b,
    const float* __restrict__ m2, const float* __restrict__ m2b,
    const float* __restrict__ f1a, const float* __restrict__ f1ab,
    const float* __restrict__ f2a, const float* __restrict__ f2ab,
    float* __restrict__ base1, float* __restrict__ base2){
  __shared__ __align__(16) float gl_s[1024];
  __shared__ __align__(16) float hid_s[512];
  __shared__ __align__(16) float code_s[512];
  int b = blockIdx.x; int tid = threadIdx.x;
  for (int i = tid; i < 1024; i += 512) gl_s[i] = funmap(glob[b*1024+i]);
  __syncthreads();
  { float acc = m1b[tid];
    const float4* wr = (const float4*)(m1 + (size_t)tid*1024);
    for (int c4 = 0; c4 < 256; ++c4){ float4 wv = wr[c4]; float4 gv = *(const float4*)&gl_s[c4*4];
      acc = fmaf(wv.x,gv.x,acc); acc = fmaf(wv.y,gv.y,acc);
      acc = fmaf(wv.z,gv.z,acc); acc = fmaf(wv.w,gv.w,acc); }
    hid_s[tid] = fmaxf(acc, 0.f);
  }
  __syncthreads();
  { float acc = m2b[tid];
    const float4* wr = (const float4*)(m2 + (size_t)tid*512);
    for (int c4 = 0; c4 < 128; ++c4){ float4 wv = wr[c4]; float4 hv = *(const float4*)&hid_s[c4*4];
      acc = fmaf(wv.x,hv.x,acc); acc = fmaf(wv.y,hv.y,acc);
      acc = fmaf(wv.z,hv.z,acc); acc = fmaf(wv.w,hv.w,acc); }
    code_s[tid] = acc;
  }
  __syncthreads();
  { float acc = f1ab[tid];
    const float* wr = f1a + (size_t)tid*514;
    for (int c = 0; c < 512; ++c) acc = fmaf(wr[c], code_s[c], acc);
    base1[b*512 + tid] = acc;
  }
  { float acc = f2ab[tid];
    const float* wr = f2a + (size_t)tid*515;
    for (int c = 0; c < 512; ++c) acc = fmaf(wr[c], code_s[c], acc);
    base2[b*512 + tid] = acc;
  }
}

// ---------- folding decoder ----------
template<int NIN>
__global__ __launch_bounds__(256) void k_fold(const float* __restrict__ base,
    const float* __restrict__ fa,
    const float* __restrict__ fb, const float* __restrict__ fbb,
    const float* __restrict__ fc, const float* __restrict__ fcb,
    const float* __restrict__ pin, float* __restrict__ pout){
  __shared__ __align__(16) float y1[32][512];
  __shared__ __align__(16) float y2[32][516];
  __shared__ float pcoord[32][NIN];
  int b = blockIdx.y; int m0 = blockIdx.x*32; int tid = threadIdx.x;
  if (tid < 32*NIN){
    int p = tid / NIN, c = tid % NIN;
    int mm = min(m0 + p, M_-1);
    float v;
    if (NIN == 2){
      const float step = 0.6f/44.f;
      int ii = (c == 0) ? (mm/GRID_) : (mm%GRID_);
      v = -0.3f + step*ii;
    } else {
      v = pin[((size_t)b*M_ + mm)*3 + c];
    }
    pcoord[p][c] = v;
  }
  __syncthreads();
  const int stride_a = 512 + NIN;
  for (int rep = 0; rep < 2; ++rep){
    int o = rep*256 + tid;
    float av[NIN];
#pragma unroll
    for (int c = 0; c < NIN; ++c) av[c] = fa[(size_t)o*stride_a + 512 + c];
    float bv = base[b*512 + o];
    for (int p = 0; p < 32; ++p){
      float acc = bv;
#pragma unroll
      for (int c = 0; c < NIN; ++c) acc = fmaf(av[c], pcoord[p][c], acc);
      y1[p][o] = fmaxf(acc, 0.f);
    }
  }
  __syncthreads();
  for (int rep = 0; rep < 2; ++rep){
    int o2 = rep*256 + tid;
    const float* wr = fb + (size_t)o2*512;
    float acc[32];
#pragma unroll
    for (int u = 0; u < 32; ++u) acc[u] = 0.f;
    for (int c4 = 0; c4 < 128; ++c4){
      float4 wv = *(const float4*)&wr[c4*4];
#pragma unroll
      for (int u = 0; u < 32; ++u){
        float4 yv = *(const float4*)&y1[u][c4*4];
        acc[u] = fmaf(wv.x,yv.x,acc[u]); acc[u] = fmaf(wv.y,yv.y,acc[u]);
        acc[u] = fmaf(wv.z,yv.z,acc[u]); acc[u] = fmaf(wv.w,yv.w,acc[u]);
      }
    }
    float bias = fbb[o2];
#pragma unroll
    for (int u = 0; u < 32; ++u) y2[u][o2] = fmaxf(acc[u] + bias, 0.f);
  }
  __syncthreads();
  if (tid < 96){
    int p = tid / 3, c = tid % 3;
    const float* wr = fc + (size_t)c*512;
    float acc = fcb[c];
    for (int o4 = 0; o4 < 128; ++o4){
      float4 wv = *(const float4*)&wr[o4*4];
      float4 yv = *(const float4*)&y2[p][o4*4];
      acc = fmaf(wv.x,yv.x,acc); acc = fmaf(wv.y,yv.y,acc);
      acc = fmaf(wv.z,yv.z,acc); acc = fmaf(wv.w,yv.w,acc);
    }
    int mm = m0 + p;
    if (mm < M_) pout[((size_t)b*M_ + mm)*3 + c] = acc;
  }
}

// ---------- launcher ----------
extern "C" void kernel_launch(void* const* d_in, const int* in_sizes, int n_in,
                              void* d_out, int out_size, void* d_ws, size_t ws_size,
                              hipStream_t stream){
  const float* pts  = (const float*)d_in[0];
  const float* w1   = (const float*)d_in[1];  const float* b1   = (const float*)d_in[2];
  const float* w2   = (const float*)d_in[3];  const float* b2   = (const float*)d_in[4];
  const float* w3   = (const float*)d_in[5];  const float* b3   = (const float*)d_in[6];
  const float* g1a  = (const float*)d_in[7];  const float* g1ab = (const float*)d_in[8];
  const float* g1b  = (const float*)d_in[9];  const float* g1bb = (const float*)d_in[10];
  const float* g2a  = (const float*)d_in[11]; const float* g2ab = (const float*)d_in[12];
  const float* g2b  = (const float*)d_in[13]; const float* g2bb = (const float*)d_in[14];
  const float* m1   = (const float*)d_in[15]; const float* m1b  = (const float*)d_in[16];
  const float* m2   = (const float*)d_in[17]; const float* m2b  = (const float*)d_in[18];
  const float* f1a  = (const float*)d_in[19]; const float* f1ab = (const float*)d_in[20];
  const float* f1b  = (const float*)d_in[21]; const float* f1bb = (const float*)d_in[22];
  const float* f1c  = (const float*)d_in[23]; const float* f1cb = (const float*)d_in[24];
  const float* f2a  = (const float*)d_in[25]; const float* f2ab = (const float*)d_in[26];
  const float* f2b  = (const float*)d_in[27]; const float* f2bb = (const float*)d_in[28];
  const float* f2c  = (const float*)d_in[29]; const float* f2cb = (const float*)d_in[30];
  float* out = (float*)d_out;

  char* w = (char*)d_ws;
  auto alloc = [&](size_t bytes){ char* p = w; w += (bytes + 255) & ~(size_t)255; return p; };
  unsigned long long* nn64 = (unsigned long long*)alloc((size_t)B_*N_*8);
  float* x    = (float*)alloc((size_t)B_*N_*64*4);
  float* g    = (float*)alloc((size_t)B_*N_*128*4);
  unsigned short* T64  = (unsigned short*)alloc((size_t)B_*4*4*N_*16);   //  8MB
  unsigned short* T128 = (unsigned short*)alloc((size_t)B_*8*4*N_*16);   // 16MB
  float* ccf  = (float*)alloc((size_t)B_*N_*4);
  int*   idx  = (int*)alloc((size_t)B_*N_*16*4);
  unsigned int* glob = (unsigned int*)alloc((size_t)B_*1024*4);
  float* base1 = (float*)alloc((size_t)B_*512*4);
  float* base2 = (float*)alloc((size_t)B_*512*4);
  float* mid   = (float*)alloc((size_t)B_*M_*3*4);
  (void)ws_size; (void)in_sizes; (void)n_in; (void)out_size;

  const int SMEM4 = 2*(4*4096) + 512 + 256*6*8;    // 45,568 B
  const int SMEM8 = 2*(8*4096) + 512 + 256*6*8;    // 78,336 B
  hipFuncSetAttribute((const void*)k_knn4<4>, hipFuncAttributeMaxDynamicSharedMemorySize, SMEM4);
  hipFuncSetAttribute((const void*)k_knn4<8>, hipFuncAttributeMaxDynamicSharedMemorySize, SMEM8);

  hipMemsetAsync(nn64, 0xFF, (size_t)B_*N_*8, stream);
  k_init<<<dim3((B_*1024+255)/256), 256, 0, stream>>>(glob);
  k_nn1<<<dim3(N_/256, 4, B_), 256, 0, stream>>>(pts, nn64);
  k_cov_mlp<<<dim3(N_/64, B_), 256, 0, stream>>>(pts, nn64, w1,b1,w2,b2,w3,b3, x);
  k_prep4<4><<<dim3(N_/256, B_), 256, 0, stream>>>(x, T64, ccf);
  k_knn4<4><<<dim3(N_/128, B_), 256, SMEM4, stream>>>(T64, ccf, idx);
  k_gpool_mlp<<<dim3(N_/64, B_), 256, 0, stream>>>(x, idx, g1a,g1ab,g1b,g1bb, g);
  k_prep4<8><<<dim3(N_/256, B_), 256, 0, stream>>>(g, T128, ccf);
  k_knn4<8><<<dim3(N_/128, B_), 256, SMEM8, stream>>>(T128, ccf, idx);
  k_hpool_max<<<dim3(N_/32, B_), 256, 0, stream>>>(g, idx, g2a,g2ab,g2b,g2bb, glob);
  k_code<<<dim3(B_), 512, 0, stream>>>(glob, m1,m1b,m2,m2b, f1a,f1ab, f2a,f2ab, base1, base2);
  k_fold<2><<<dim3((M_+31)/32, B_), 256, 0, stream>>>(base1, f1a, f1b, f1bb, f1c, f1cb, nullptr, mid);
  k_fold<3><<<dim3((M_+31)/32, B_), 256, 0, stream>>>(base2, f2a, f2b, f2bb, f2c, f2cb, mid, out);
}

// Round 5
// 3125.330 us; speedup vs baseline: 1.9727x; 1.1927x over previous
//
#include <hip/hip_runtime.h>
#include <stdint.h>

#define B_ 4
#define N_ 8192
#define K_ 16
#define FEAT_ 512
#define GRID_ 45
#define M_ (GRID_*GRID_)

typedef unsigned long long ull;
typedef __bf16 bf16x8 __attribute__((ext_vector_type(8)));
typedef float f32x16 __attribute__((ext_vector_type(16)));

// ---------- helpers ----------

__device__ __forceinline__ unsigned int fmap(float f){
  unsigned int u = __float_as_uint(f);
  return (u & 0x80000000u) ? ~u : (u | 0x80000000u);
}
__device__ __forceinline__ float funmap(unsigned int u){
  return (u & 0x80000000u) ? __uint_as_float(u ^ 0x80000000u) : __uint_as_float(~u);
}

// sorted top-16 insert on packed (fmap(dist)<<32 | idx) keys: lex order ==
// jax.lax.top_k tie-break (lower index first). Order-independent.
__device__ __forceinline__ void ins16(ull (&d)[16], ull k){
  if (k < d[15]){
    bool c[16];
#pragma unroll
    for (int s = 0; s < 16; ++s) c[s] = k < d[s];
#pragma unroll
    for (int s = 15; s >= 1; --s) d[s] = c[s-1] ? d[s-1] : (c[s] ? k : d[s]);
    if (c[0]) d[0] = k;
  }
}

#define GLDS16(l, g) __builtin_amdgcn_global_load_lds((const __attribute__((address_space(1))) void*)(g), (__attribute__((address_space(3))) void*)(l), 16, 0, 0)
#define GLDS4(l, g)  __builtin_amdgcn_global_load_lds((const __attribute__((address_space(1))) void*)(g), (__attribute__((address_space(3))) void*)(l), 4, 0, 0)

// sentinel key = (fmap(+inf)<<32)|0xFFFFFFFF : sorts above all real keys
#define KEY_INF 0xFF800000FFFFFFFFull

// ---------- init ----------
__global__ void k_init(unsigned int* glob){
  int i = blockIdx.x*256 + threadIdx.x;
  if (i < B_*1024) glob[i] = 0x007FFFFFu;   // fmap(-inf)
}

// ---------- KNN #1: nearest other point (exact fp32) ----------
__global__ __launch_bounds__(256) void k_nn1(const float* __restrict__ pts,
                                             unsigned long long* __restrict__ nn64){
  __shared__ float sp[2048*3];
  int b = blockIdx.z, s = blockIdx.y;
  int c0 = s*2048;
  const float* P = pts + (size_t)b*N_*3;
  for (int i = threadIdx.x; i < 2048*3; i += 256) sp[i] = P[c0*3 + i];
  __syncthreads();
  int n = blockIdx.x*256 + threadIdx.x;
  float qx = P[n*3], qy = P[n*3+1], qz = P[n*3+2];
  float best = 1e30f; int bi = 0;
  for (int j = 0; j < 2048; ++j){
    float dx = qx - sp[j*3], dy = qy - sp[j*3+1], dz = qz - sp[j*3+2];
    float d2 = fmaf(dx,dx, fmaf(dy,dy, dz*dz));
    int cj = c0 + j;
    if (d2 < best && cj != n){ best = d2; bi = cj; }
  }
  unsigned long long key = ((unsigned long long)__float_as_uint(best) << 32) | (unsigned int)bi;
  atomicMin(&nn64[(size_t)b*N_ + n], key);
}

// ---------- local_cov + 3 convs (12->64->64->64, relu each) ----------
__global__ __launch_bounds__(256) void k_cov_mlp(const float* __restrict__ pts,
    const unsigned long long* __restrict__ nn64,
    const float* __restrict__ w1, const float* __restrict__ b1,
    const float* __restrict__ w2, const float* __restrict__ b2,
    const float* __restrict__ w3, const float* __restrict__ b3,
    float* __restrict__ xout){
  __shared__ __align__(16) float W1t[12*64];
  __shared__ __align__(16) float W2t[64*64];
  __shared__ __align__(16) float W3t[64*64];
  __shared__ float B1[64], B2[64], B3[64];
  __shared__ __align__(16) float x0[64][12];
  __shared__ __align__(16) float h1[64][64];
  __shared__ __align__(16) float h2[64][64];
  int b = blockIdx.y; int n0 = blockIdx.x*64; int tid = threadIdx.x;
  for (int i = tid; i < 12*64; i += 256){ int o = i % 64, ci = i / 64; W1t[i] = w1[o*12 + ci]; }
  for (int i = tid; i < 64*64; i += 256){ int o = i % 64, ci = i / 64; W2t[i] = w2[o*64 + ci]; W3t[i] = w3[o*64 + ci]; }
  if (tid < 64){ B1[tid]=b1[tid]; B2[tid]=b2[tid]; B3[tid]=b3[tid]; }
  {
    int p = tid % 64, cg = tid / 64;
    int n = n0 + p;
    const float* P = pts + ((size_t)b*N_ + n)*3;
    int nb = (int)(nn64[(size_t)b*N_ + n] & 0xFFFFFFFFull);
    const float* Q = pts + ((size_t)b*N_ + nb)*3;
    if (cg == 0){ x0[p][0]=P[0]; x0[p][1]=P[1]; x0[p][2]=P[2]; }
    else { int i = cg-1; float pi = P[i];
      x0[p][3+i*3+0]=pi*Q[0]; x0[p][3+i*3+1]=pi*Q[1]; x0[p][3+i*3+2]=pi*Q[2]; }
  }
  __syncthreads();
  { int o = tid % 64, pg = tid / 64;
    for (int p = pg; p < 64; p += 4){
      float acc = B1[o];
#pragma unroll
      for (int ci = 0; ci < 12; ++ci) acc = fmaf(W1t[ci*64+o], x0[p][ci], acc);
      h1[p][o] = fmaxf(acc, 0.f);
    } }
  __syncthreads();
  { int o = tid % 64, pg = tid / 64;
    for (int p = pg; p < 64; p += 4){
      float acc = B2[o];
#pragma unroll
      for (int ci = 0; ci < 64; ++ci) acc = fmaf(W2t[ci*64+o], h1[p][ci], acc);
      h2[p][o] = fmaxf(acc, 0.f);
    } }
  __syncthreads();
  { int o = tid % 64, pg = tid / 64;
    for (int p = pg; p < 64; p += 4){
      float acc = B3[o];
#pragma unroll
      for (int ci = 0; ci < 64; ++ci) acc = fmaf(W3t[ci*64+o], h2[p][ci], acc);
      xout[((size_t)b*N_ + n0 + p)*64 + o] = fmaxf(acc, 0.f);
    } }
}

// ---------- prep: bf16 hi/lo split into K-major granule layout + norms ----------
// T layout: [b][kf][pl 2][hi8 2][n 8192][16B granule]; granule = 8 bf16 ch.
template<int KF>
__global__ __launch_bounds__(256) void k_prep4(const float* __restrict__ f,
    unsigned short* __restrict__ T, float* __restrict__ cc){
  int b = blockIdx.y; int n = blockIdx.x*256 + threadIdx.x;
  const float* src = f + ((size_t)b*N_ + n)*(KF*16);
  char* Tb = (char*)T;
  float ss = 0.f;
#pragma unroll
  for (int kf = 0; kf < KF; ++kf){
    float v[16];
#pragma unroll
    for (int c4 = 0; c4 < 4; ++c4){
      float4 t4 = *(const float4*)&src[kf*16 + c4*4];
      v[c4*4]=t4.x; v[c4*4+1]=t4.y; v[c4*4+2]=t4.z; v[c4*4+3]=t4.w;
    }
    unsigned short hs[16], ls[16];
#pragma unroll
    for (int c = 0; c < 16; ++c){
      float x = v[c];
      ss = fmaf(x, x, ss);
      __bf16 h = (__bf16)x;
      __bf16 l = (__bf16)(x - (float)h);
      hs[c] = __builtin_bit_cast(unsigned short, h);
      ls[c] = __builtin_bit_cast(unsigned short, l);
    }
    size_t base = ((((size_t)b*KF + kf)*2)*2)*(size_t)(N_*16) + (size_t)n*16;
    const size_t HS = (size_t)N_*16;           // hi8 stride
    const size_t PS = 2*HS;                    // plane stride
    *(uint4*)(Tb + base)            = *(uint4*)&hs[0];
    *(uint4*)(Tb + base + HS)       = *(uint4*)&hs[8];
    *(uint4*)(Tb + base + PS)       = *(uint4*)&ls[0];
    *(uint4*)(Tb + base + PS + HS)  = *(uint4*)&ls[8];
  }
  cc[(size_t)b*N_ + n] = ss;
}

// ---------- KNN v5: Q-in-regs MFMA + filtered top-16, candidate-split ----------
// block 256 thr / 4 waves; each wave owns 32 queries (col = lane&31);
// candidates [sp*N/S, (sp+1)*N/S) streamed 64/tile via GLDS; partial keys out.
template<int KF, int S>
__global__ __launch_bounds__(256, 2) void k_knn5(const unsigned short* __restrict__ T,
    const float* __restrict__ ccg, ull* __restrict__ pkeys){
  extern __shared__ char smem[];
  constexpr int ABUF = KF*4096;          // one candidate-tile buffer
  constexpr int CAP  = 6;                // per-thread passer queue depth
  constexpr int NT   = (N_/S)/64;        // tiles per split
  char* As = smem;                       // 2*ABUF
  char* Cs = smem + 2*ABUF;              // 2*256 (cc tiles)
  char* Ps = smem + 2*ABUF + 512;        // 256*CAP*8 passer queues

  const int tid = threadIdx.x, lane = tid & 63, wid = tid >> 6;
  const int hi = lane >> 5, l31 = lane & 31;
  const int b = blockIdx.z, sp = blockIdx.y, q0 = blockIdx.x*128;
  const int c0 = sp*(N_/S);
  const char* Tb = (const char*)T;
  const size_t HS = (size_t)N_*16, PS = 2*HS, KS = 4*HS;
  const size_t Bb = (size_t)b*KF*KS;
  const float* ccb = ccg + (size_t)b*N_;

  // resident query fragments (hi & lo planes)
  const int q = q0 + wid*32 + l31;
  bf16x8 qh[KF], ql[KF];
#pragma unroll
  for (int kf = 0; kf < KF; ++kf){
    size_t o = Bb + kf*KS + hi*HS + (size_t)q*16;
    qh[kf] = *(const bf16x8*)(Tb + o);
    ql[kf] = *(const bf16x8*)(Tb + o + PS);
  }

  ull keys[16];
#pragma unroll
  for (int t = 0; t < 16; ++t) keys[t] = KEY_INF;
  float kapf = __builtin_inff();
  int cnt = 0;

  auto refresh_kap = [&](){
    unsigned kk = (unsigned)(keys[15] >> 32);
    kapf = (kk >= 0xFF800000u) ? __builtin_inff() : funmap(kk);
  };
  auto pushk = [&](float v, int idx){
    ull k = ((ull)fmap(v) << 32) | (unsigned)idx;
    if (cnt < CAP){ *(ull*)(Ps + (tid*CAP + cnt)*8) = k; ++cnt; }
    else { ins16(keys, k); refresh_kap(); }
  };
  auto drain = [&](){
    while (__any(cnt > 0)){
      if (cnt > 0){ --cnt; ins16(keys, *(const ull*)(Ps + (tid*CAP + cnt)*8)); }
    }
    refresh_kap();
  };
  auto stage = [&](int bf, int t0){
#pragma unroll
    for (int si = 0; si < KF; ++si){
      int s = wid + 4*si;                 // slice = (kf*2+pl)*2+hi
      int kf = s >> 2, pl = (s >> 1) & 1, h = s & 1;
      GLDS16(As + (bf*KF*4 + s)*1024,
             Tb + Bb + kf*KS + pl*PS + h*HS + (size_t)(c0 + t0)*16);
    }
    if (wid == 0) GLDS4(Cs + bf*256, (const char*)(ccb + c0 + t0));
  };

  stage(0, 0);
  for (int t = 0; t < NT; ++t){
    const int bf = t & 1, t0 = t*64;
    asm volatile("s_waitcnt vmcnt(0)" ::: "memory");
    __syncthreads();
    if (t + 1 < NT) stage(bf ^ 1, (t+1)*64);

    const char* Ab = As + bf*ABUF + hi*1024 + l31*16;
    f32x16 acc[2];
    acc[0] = (f32x16)(0.f); acc[1] = (f32x16)(0.f);
#pragma unroll
    for (int kf = 0; kf < KF; ++kf){
      bf16x8 ah0 = *(const bf16x8*)(Ab + kf*4096);
      bf16x8 ah1 = *(const bf16x8*)(Ab + kf*4096 + 512);
      bf16x8 al0 = *(const bf16x8*)(Ab + kf*4096 + 2048);
      bf16x8 al1 = *(const bf16x8*)(Ab + kf*4096 + 2048 + 512);
      acc[0] = __builtin_amdgcn_mfma_f32_32x32x16_bf16(ah0, qh[kf], acc[0], 0, 0, 0);
      acc[0] = __builtin_amdgcn_mfma_f32_32x32x16_bf16(ah0, ql[kf], acc[0], 0, 0, 0);
      acc[0] = __builtin_amdgcn_mfma_f32_32x32x16_bf16(al0, qh[kf], acc[0], 0, 0, 0);
      acc[1] = __builtin_amdgcn_mfma_f32_32x32x16_bf16(ah1, qh[kf], acc[1], 0, 0, 0);
      acc[1] = __builtin_amdgcn_mfma_f32_32x32x16_bf16(ah1, ql[kf], acc[1], 0, 0, 0);
      acc[1] = __builtin_amdgcn_mfma_f32_32x32x16_bf16(al1, qh[kf], acc[1], 0, 0, 0);
    }
    // selection: v = cc - 2<q,c>  (qq dropped: constant per-query shift)
    const float* cct = (const float*)(Cs + bf*256);
    if (t == 0){
      // seed: unconditional insert of tile 0 (tightens kappa, kills drain storm)
#pragma unroll
      for (int i = 0; i < 2; ++i){
#pragma unroll
        for (int rq = 0; rq < 4; ++rq){
          float4 c4 = *(const float4*)(cct + i*32 + 4*hi + 8*rq);
          int rowb = c0 + i*32 + 4*hi + 8*rq;
          ins16(keys, ((ull)fmap(fmaf(-2.f, acc[i][rq*4+0], c4.x)) << 32) | (unsigned)(rowb+0));
          ins16(keys, ((ull)fmap(fmaf(-2.f, acc[i][rq*4+1], c4.y)) << 32) | (unsigned)(rowb+1));
          ins16(keys, ((ull)fmap(fmaf(-2.f, acc[i][rq*4+2], c4.z)) << 32) | (unsigned)(rowb+2));
          ins16(keys, ((ull)fmap(fmaf(-2.f, acc[i][rq*4+3], c4.w)) << 32) | (unsigned)(rowb+3));
        }
      }
      refresh_kap();
    } else {
#pragma unroll
      for (int i = 0; i < 2; ++i){
#pragma unroll
        for (int rq = 0; rq < 4; ++rq){
          float4 c4 = *(const float4*)(cct + i*32 + 4*hi + 8*rq);
          int rowb = c0 + t0 + i*32 + 4*hi + 8*rq;
          float v0 = fmaf(-2.f, acc[i][rq*4+0], c4.x);
          float v1 = fmaf(-2.f, acc[i][rq*4+1], c4.y);
          float v2 = fmaf(-2.f, acc[i][rq*4+2], c4.z);
          float v3 = fmaf(-2.f, acc[i][rq*4+3], c4.w);
          if (v0 <= kapf) pushk(v0, rowb+0);
          if (v1 <= kapf) pushk(v1, rowb+1);
          if (v2 <= kapf) pushk(v2, rowb+2);
          if (v3 <= kapf) pushk(v3, rowb+3);
        }
      }
      if (__any(cnt >= 4)) drain();
    }
  }
  drain();
  // merge the two row-half partial lists (lane <-> lane+32)
#pragma unroll
  for (int tt = 0; tt < 16; ++tt){
    int lo = __shfl((int)(unsigned)keys[tt], (lane + 32) & 63);
    int hh = __shfl((int)(unsigned)(keys[tt] >> 32), (lane + 32) & 63);
    if (lane < 32) ins16(keys, ((ull)(unsigned)hh << 32) | (unsigned)lo);
  }
  if (lane < 32){
    ull* op = pkeys + (((size_t)b*N_ + q)*S + sp)*16;
#pragma unroll
    for (int tt = 0; tt < 16; ++tt) op[tt] = keys[tt];
  }
}

// ---------- merge S partial key lists -> final idx ----------
template<int S>
__global__ void k_merge5(const ull* __restrict__ pkeys, int* __restrict__ idxout){
  int i = blockIdx.x*256 + threadIdx.x;
  if (i >= B_*N_) return;
  ull best[16];
#pragma unroll
  for (int t = 0; t < 16; ++t) best[t] = KEY_INF;
  const ull* pp = pkeys + (size_t)i*S*16;
#pragma unroll
  for (int t = 0; t < S*16; ++t) ins16(best, pp[t]);
  int* op = idxout + (size_t)i*16;
#pragma unroll
  for (int t = 0; t < 16; ++t) op[t] = (int)(best[t] & 0xffffffffu);
}

// ---------- maxpool(x) + conv 64->64 relu + conv 64->128 ----------
__global__ __launch_bounds__(256) void k_gpool_mlp(const float* __restrict__ x,
    const int* __restrict__ idx,
    const float* __restrict__ g1a, const float* __restrict__ g1ab,
    const float* __restrict__ g1b, const float* __restrict__ g1bb,
    float* __restrict__ gout){
  __shared__ __align__(16) float Wt1[64*64];
  __shared__ __align__(16) float Wt2[64*128];
  __shared__ float Ba[64], Bb[128];
  __shared__ __align__(16) float m[64][64];
  __shared__ __align__(16) float r[64][64];
  int b = blockIdx.y; int n0 = blockIdx.x*64; int tid = threadIdx.x;
  for (int i = tid; i < 64*64; i += 256){ int o = i%64, ci = i/64; Wt1[i] = g1a[o*64+ci]; }
  for (int i = tid; i < 64*128; i += 256){ int o = i%128, ci = i/128; Wt2[i] = g1b[o*64+ci]; }
  if (tid < 64) Ba[tid] = g1ab[tid];
  if (tid < 128) Bb[tid] = g1bb[tid];
  { int p = tid/4, cg = tid%4; int n = n0 + p;
    const int* ip = idx + ((size_t)b*N_ + n)*16;
    float mm[16];
#pragma unroll
    for (int u = 0; u < 16; ++u) mm[u] = -1e30f;
    for (int k = 0; k < 16; ++k){
      int nb = ip[k];
      const float4* src = (const float4*)(x + ((size_t)b*N_ + nb)*64 + cg*16);
#pragma unroll
      for (int u = 0; u < 4; ++u){
        float4 v = src[u];
        mm[4*u  ] = fmaxf(mm[4*u  ], v.x); mm[4*u+1] = fmaxf(mm[4*u+1], v.y);
        mm[4*u+2] = fmaxf(mm[4*u+2], v.z); mm[4*u+3] = fmaxf(mm[4*u+3], v.w);
      }
    }
#pragma unroll
    for (int u = 0; u < 16; ++u) m[p][cg*16+u] = mm[u];
  }
  __syncthreads();
  { int o = tid%64, pg = tid/64;
    float acc[16];
#pragma unroll
    for (int u = 0; u < 16; ++u) acc[u] = Ba[o];
    for (int ci = 0; ci < 64; ci += 4){
      float w0 = Wt1[ci*64+o], w1_ = Wt1[(ci+1)*64+o], w2_ = Wt1[(ci+2)*64+o], w3_ = Wt1[(ci+3)*64+o];
#pragma unroll
      for (int u = 0; u < 16; ++u){
        float4 mv = *(const float4*)&m[pg*16+u][ci];
        acc[u] = fmaf(w0, mv.x, acc[u]); acc[u] = fmaf(w1_, mv.y, acc[u]);
        acc[u] = fmaf(w2_, mv.z, acc[u]); acc[u] = fmaf(w3_, mv.w, acc[u]);
      }
    }
#pragma unroll
    for (int u = 0; u < 16; ++u) r[pg*16+u][o] = fmaxf(acc[u], 0.f);
  }
  __syncthreads();
  { int o = tid%128, pg = tid/128;   // no relu on this conv
    float acc[32];
#pragma unroll
    for (int u = 0; u < 32; ++u) acc[u] = Bb[o];
    for (int ci = 0; ci < 64; ci += 4){
      float w0 = Wt2[ci*128+o], w1_ = Wt2[(ci+1)*128+o], w2_ = Wt2[(ci+2)*128+o], w3_ = Wt2[(ci+3)*128+o];
#pragma unroll
      for (int u = 0; u < 32; ++u){
        float4 rv = *(const float4*)&r[pg*32+u][ci];
        acc[u] = fmaf(w0, rv.x, acc[u]); acc[u] = fmaf(w1_, rv.y, acc[u]);
        acc[u] = fmaf(w2_, rv.z, acc[u]); acc[u] = fmaf(w3_, rv.w, acc[u]);
      }
    }
#pragma unroll
    for (int u = 0; u < 32; ++u)
      gout[((size_t)b*N_ + n0 + pg*32 + u)*128 + o] = acc[u];
  }
}

// ---------- maxpool(g) + conv 128->128 relu + conv 128->1024 + global max ----------
__global__ __launch_bounds__(256) void k_hpool_max(const float* __restrict__ g,
    const int* __restrict__ idx,
    const float* __restrict__ g2a, const float* __restrict__ g2ab,
    const float* __restrict__ g2b, const float* __restrict__ g2bb,
    unsigned int* __restrict__ glob){
  __shared__ __align__(16) float m[32][128];
  __shared__ __align__(16) float t[32][128];
  int b = blockIdx.y; int n0 = blockIdx.x*32; int tid = threadIdx.x;
  { int p = tid/8, cg = tid%8; int n = n0+p;
    const int* ip = idx + ((size_t)b*N_+n)*16;
    float mm[16];
#pragma unroll
    for (int u = 0; u < 16; ++u) mm[u] = -1e30f;
    for (int k = 0; k < 16; ++k){
      int nb = ip[k];
      const float4* src = (const float4*)(g + ((size_t)b*N_+nb)*128 + cg*16);
#pragma unroll
      for (int u = 0; u < 4; ++u){
        float4 v = src[u];
        mm[4*u  ] = fmaxf(mm[4*u  ], v.x); mm[4*u+1] = fmaxf(mm[4*u+1], v.y);
        mm[4*u+2] = fmaxf(mm[4*u+2], v.z); mm[4*u+3] = fmaxf(mm[4*u+3], v.w);
      }
    }
#pragma unroll
    for (int u = 0; u < 16; ++u) m[p][cg*16+u] = mm[u];
  }
  __syncthreads();
  { int o = tid%128, pg = tid/128;
    float acc[16];
#pragma unroll
    for (int u = 0; u < 16; ++u) acc[u] = g2ab[o];
    const float4* wrow = (const float4*)(g2a + (size_t)o*128);
    for (int c4 = 0; c4 < 32; ++c4){
      float4 wv = wrow[c4];
#pragma unroll
      for (int u = 0; u < 16; ++u){
        float4 mv = *(const float4*)&m[pg*16+u][c4*4];
        acc[u] = fmaf(wv.x,mv.x,acc[u]); acc[u] = fmaf(wv.y,mv.y,acc[u]);
        acc[u] = fmaf(wv.z,mv.z,acc[u]); acc[u] = fmaf(wv.w,mv.w,acc[u]);
      }
    }
#pragma unroll
    for (int u = 0; u < 16; ++u) t[pg*16+u][o] = fmaxf(acc[u], 0.f);
  }
  __syncthreads();
  for (int oc = 0; oc < 4; ++oc){
    int o = oc*256 + tid;
    const float4* wrow = (const float4*)(g2b + (size_t)o*128);
    float acc[32];
#pragma unroll
    for (int u = 0; u < 32; ++u) acc[u] = 0.f;
    for (int c4 = 0; c4 < 32; ++c4){
      float4 wv = wrow[c4];
#pragma unroll
      for (int u = 0; u < 32; ++u){
        float4 tv = *(const float4*)&t[u][c4*4];
        acc[u] = fmaf(wv.x,tv.x,acc[u]); acc[u] = fmaf(wv.y,tv.y,acc[u]);
        acc[u] = fmaf(wv.z,tv.z,acc[u]); acc[u] = fmaf(wv.w,tv.w,acc[u]);
      }
    }
    float bias = g2bb[o];
    float mx = -1e30f;
#pragma unroll
    for (int u = 0; u < 32; ++u) mx = fmaxf(mx, acc[u] + bias);
    atomicMax(&glob[b*1024 + o], fmap(mx));
  }
}

// ---------- code MLP + decoder base precompute ----------
__global__ __launch_bounds__(512) void k_code(const unsigned int* __restrict__ glob,
    const float* __restrict__ m1, const float* __restrict__ m1b,
    const float* __restrict__ m2, const float* __restrict__ m2b,
    const float* __restrict__ f1a, const float* __restrict__ f1ab,
    const float* __restrict__ f2a, const float* __restrict__ f2ab,
    float* __restrict__ base1, float* __restrict__ base2){
  __shared__ __align__(16) float gl_s[1024];
  __shared__ __align__(16) float hid_s[512];
  __shared__ __align__(16) float code_s[512];
  int b = blockIdx.x; int tid = threadIdx.x;
  for (int i = tid; i < 1024; i += 512) gl_s[i] = funmap(glob[b*1024+i]);
  __syncthreads();
  { float acc = m1b[tid];
    const float4* wr = (const float4*)(m1 + (size_t)tid*1024);
    for (int c4 = 0; c4 < 256; ++c4){ float4 wv = wr[c4]; float4 gv = *(const float4*)&gl_s[c4*4];
      acc = fmaf(wv.x,gv.x,acc); acc = fmaf(wv.y,gv.y,acc);
      acc = fmaf(wv.z,gv.z,acc); acc = fmaf(wv.w,gv.w,acc); }
    hid_s[tid] = fmaxf(acc, 0.f);
  }
  __syncthreads();
  { float acc = m2b[tid];
    const float4* wr = (const float4*)(m2 + (size_t)tid*512);
    for (int c4 = 0; c4 < 128; ++c4){ float4 wv = wr[c4]; float4 hv = *(const float4*)&hid_s[c4*4];
      acc = fmaf(wv.x,hv.x,acc); acc = fmaf(wv.y,hv.y,acc);
      acc = fmaf(wv.z,hv.z,acc); acc = fmaf(wv.w,hv.w,acc); }
    code_s[tid] = acc;
  }
  __syncthreads();
  { float acc = f1ab[tid];
    const float* wr = f1a + (size_t)tid*514;
    for (int c = 0; c < 512; ++c) acc = fmaf(wr[c], code_s[c], acc);
    base1[b*512 + tid] = acc;
  }
  { float acc = f2ab[tid];
    const float* wr = f2a + (size_t)tid*515;
    for (int c = 0; c < 512; ++c) acc = fmaf(wr[c], code_s[c], acc);
    base2[b*512 + tid] = acc;
  }
}

// ---------- folding decoder ----------
template<int NIN>
__global__ __launch_bounds__(256) void k_fold(const float* __restrict__ base,
    const float* __restrict__ fa,
    const float* __restrict__ fb, const float* __restrict__ fbb,
    const float* __restrict__ fc, const float* __restrict__ fcb,
    const float* __restrict__ pin, float* __restrict__ pout){
  __shared__ __align__(16) float y1[32][512];
  __shared__ __align__(16) float y2[32][516];
  __shared__ float pcoord[32][NIN];
  int b = blockIdx.y; int m0 = blockIdx.x*32; int tid = threadIdx.x;
  if (tid < 32*NIN){
    int p = tid / NIN, c = tid % NIN;
    int mm = min(m0 + p, M_-1);
    float v;
    if (NIN == 2){
      const float step = 0.6f/44.f;
      int ii = (c == 0) ? (mm/GRID_) : (mm%GRID_);
      v = -0.3f + step*ii;
    } else {
      v = pin[((size_t)b*M_ + mm)*3 + c];
    }
    pcoord[p][c] = v;
  }
  __syncthreads();
  const int stride_a = 512 + NIN;
  for (int rep = 0; rep < 2; ++rep){
    int o = rep*256 + tid;
    float av[NIN];
#pragma unroll
    for (int c = 0; c < NIN; ++c) av[c] = fa[(size_t)o*stride_a + 512 + c];
    float bv = base[b*512 + o];
    for (int p = 0; p < 32; ++p){
      float acc = bv;
#pragma unroll
      for (int c = 0; c < NIN; ++c) acc = fmaf(av[c], pcoord[p][c], acc);
      y1[p][o] = fmaxf(acc, 0.f);
    }
  }
  __syncthreads();
  for (int rep = 0; rep < 2; ++rep){
    int o2 = rep*256 + tid;
    const float* wr = fb + (size_t)o2*512;
    float acc[32];
#pragma unroll
    for (int u = 0; u < 32; ++u) acc[u] = 0.f;
    for (int c4 = 0; c4 < 128; ++c4){
      float4 wv = *(const float4*)&wr[c4*4];
#pragma unroll
      for (int u = 0; u < 32; ++u){
        float4 yv = *(const float4*)&y1[u][c4*4];
        acc[u] = fmaf(wv.x,yv.x,acc[u]); acc[u] = fmaf(wv.y,yv.y,acc[u]);
        acc[u] = fmaf(wv.z,yv.z,acc[u]); acc[u] = fmaf(wv.w,yv.w,acc[u]);
      }
    }
    float bias = fbb[o2];
#pragma unroll
    for (int u = 0; u < 32; ++u) y2[u][o2] = fmaxf(acc[u] + bias, 0.f);
  }
  __syncthreads();
  if (tid < 96){
    int p = tid / 3, c = tid % 3;
    const float* wr = fc + (size_t)c*512;
    float acc = fcb[c];
    for (int o4 = 0; o4 < 128; ++o4){
      float4 wv = *(const float4*)&wr[o4*4];
      float4 yv = *(const float4*)&y2[p][o4*4];
      acc = fmaf(wv.x,yv.x,acc); acc = fmaf(wv.y,yv.y,acc);
      acc = fmaf(wv.z,yv.z,acc); acc = fmaf(wv.w,yv.w,acc);
    }
    int mm = m0 + p;
    if (mm < M_) pout[((size_t)b*M_ + mm)*3 + c] = acc;
  }
}

// ---------- launcher ----------
extern "C" void kernel_launch(void* const* d_in, const int* in_sizes, int n_in,
                              void* d_out, int out_size, void* d_ws, size_t ws_size,
                              hipStream_t stream){
  const float* pts  = (const float*)d_in[0];
  const float* w1   = (const float*)d_in[1];  const float* b1   = (const float*)d_in[2];
  const float* w2   = (const float*)d_in[3];  const float* b2   = (const float*)d_in[4];
  const float* w3   = (const float*)d_in[5];  const float* b3   = (const float*)d_in[6];
  const float* g1a  = (const float*)d_in[7];  const float* g1ab = (const float*)d_in[8];
  const float* g1b  = (const float*)d_in[9];  const float* g1bb = (const float*)d_in[10];
  const float* g2a  = (const float*)d_in[11]; const float* g2ab = (const float*)d_in[12];
  const float* g2b  = (const float*)d_in[13]; const float* g2bb = (const float*)d_in[14];
  const float* m1   = (const float*)d_in[15]; const float* m1b  = (const float*)d_in[16];
  const float* m2   = (const float*)d_in[17]; const float* m2b  = (const float*)d_in[18];
  const float* f1a  = (const float*)d_in[19]; const float* f1ab = (const float*)d_in[20];
  const float* f1b  = (const float*)d_in[21]; const float* f1bb = (const float*)d_in[22];
  const float* f1c  = (const float*)d_in[23]; const float* f1cb = (const float*)d_in[24];
  const float* f2a  = (const float*)d_in[25]; const float* f2ab = (const float*)d_in[26];
  const float* f2b  = (const float*)d_in[27]; const float* f2bb = (const float*)d_in[28];
  const float* f2c  = (const float*)d_in[29]; const float* f2cb = (const float*)d_in[30];
  float* out = (float*)d_out;

  char* w = (char*)d_ws;
  auto alloc = [&](size_t bytes){ char* p = w; w += (bytes + 255) & ~(size_t)255; return p; };
  unsigned long long* nn64 = (unsigned long long*)alloc((size_t)B_*N_*8);
  float* x    = (float*)alloc((size_t)B_*N_*64*4);
  float* g    = (float*)alloc((size_t)B_*N_*128*4);
  unsigned short* T64  = (unsigned short*)alloc((size_t)B_*4*4*N_*16);   //  8MB
  unsigned short* T128 = (unsigned short*)alloc((size_t)B_*8*4*N_*16);   // 16MB
  float* ccf  = (float*)alloc((size_t)B_*N_*4);
  int*   idx  = (int*)alloc((size_t)B_*N_*16*4);
  ull*   pkeys = (ull*)alloc((size_t)B_*N_*2*16*8);                      //  8MB
  unsigned int* glob = (unsigned int*)alloc((size_t)B_*1024*4);
  float* base1 = (float*)alloc((size_t)B_*512*4);
  float* base2 = (float*)alloc((size_t)B_*512*4);
  float* mid   = (float*)alloc((size_t)B_*M_*3*4);
  (void)ws_size; (void)in_sizes; (void)n_in; (void)out_size;

  const int SMEM4 = 2*(4*4096) + 512 + 256*6*8;    // 45,568 B
  const int SMEM8 = 2*(8*4096) + 512 + 256*6*8;    // 78,336 B
  hipFuncSetAttribute((const void*)k_knn5<4,2>, hipFuncAttributeMaxDynamicSharedMemorySize, SMEM4);
  hipFuncSetAttribute((const void*)k_knn5<8,2>, hipFuncAttributeMaxDynamicSharedMemorySize, SMEM8);

  hipMemsetAsync(nn64, 0xFF, (size_t)B_*N_*8, stream);
  k_init<<<dim3((B_*1024+255)/256), 256, 0, stream>>>(glob);
  k_nn1<<<dim3(N_/256, 4, B_), 256, 0, stream>>>(pts, nn64);
  k_cov_mlp<<<dim3(N_/64, B_), 256, 0, stream>>>(pts, nn64, w1,b1,w2,b2,w3,b3, x);
  k_prep4<4><<<dim3(N_/256, B_), 256, 0, stream>>>(x, T64, ccf);
  k_knn5<4,2><<<dim3(N_/128, 2, B_), 256, SMEM4, stream>>>(T64, ccf, pkeys);
  k_merge5<2><<<dim3(B_*N_/256), 256, 0, stream>>>(pkeys, idx);
  k_gpool_mlp<<<dim3(N_/64, B_), 256, 0, stream>>>(x, idx, g1a,g1ab,g1b,g1bb, g);
  k_prep4<8><<<dim3(N_/256, B_), 256, 0, stream>>>(g, T128, ccf);
  k_knn5<8,2><<<dim3(N_/128, 2, B_), 256, SMEM8, stream>>>(T128, ccf, pkeys);
  k_merge5<2><<<dim3(B_*N_/256), 256, 0, stream>>>(pkeys, idx);
  k_hpool_max<<<dim3(N_/32, B_), 256, 0, stream>>>(g, idx, g2a,g2ab,g2b,g2bb, glob);
  k_code<<<dim3(B_), 512, 0, stream>>>(glob, m1,m1b,m2,m2b, f1a,f1ab, f2a,f2ab, base1, base2);
  k_fold<2><<<dim3((M_+31)/32, B_), 256, 0, stream>>>(base1, f1a, f1b, f1bb, f1c, f1cb, nullptr, mid);
  k_fold<3><<<dim3((M_+31)/32, B_), 256, 0, stream>>>(base2, f2a, f2b, f2bb, f2c, f2cb, mid, out);
}

// Round 6
// 3080.712 us; speedup vs baseline: 2.0012x; 1.0145x over previous
//
#include <hip/hip_runtime.h>
#include <stdint.h>

#define B_ 4
#define N_ 8192
#define K_ 16
#define FEAT_ 512
#define GRID_ 45
#define M_ (GRID_*GRID_)

typedef unsigned long long ull;
typedef __bf16 bf16x8 __attribute__((ext_vector_type(8)));
typedef float f32x16 __attribute__((ext_vector_type(16)));

// ---------- helpers ----------

__device__ __forceinline__ unsigned int fmap(float f){
  unsigned int u = __float_as_uint(f);
  return (u & 0x80000000u) ? ~u : (u | 0x80000000u);
}
__device__ __forceinline__ float funmap(unsigned int u){
  return (u & 0x80000000u) ? __uint_as_float(u ^ 0x80000000u) : __uint_as_float(~u);
}

// sorted top-16 insert on packed (fmap(dist)<<32 | idx) keys: lex order ==
// jax.lax.top_k tie-break (lower index first). Order-independent.
__device__ __forceinline__ void ins16(ull (&d)[16], ull k){
  if (k < d[15]){
    bool c[16];
#pragma unroll
    for (int s = 0; s < 16; ++s) c[s] = k < d[s];
#pragma unroll
    for (int s = 15; s >= 1; --s) d[s] = c[s-1] ? d[s-1] : (c[s] ? k : d[s]);
    if (c[0]) d[0] = k;
  }
}

// sorted 16-float ascending insert (distance-only, strict <)
__device__ __forceinline__ void insf(float (&d)[16], float v){
  if (v < d[15]){
    bool c[16];
#pragma unroll
    for (int s = 0; s < 16; ++s) c[s] = v < d[s];
#pragma unroll
    for (int s = 15; s >= 1; --s) d[s] = c[s-1] ? d[s-1] : (c[s] ? v : d[s]);
    if (c[0]) d[0] = v;
  }
}

#define GLDS16(l, g) __builtin_amdgcn_global_load_lds((const __attribute__((address_space(1))) void*)(g), (__attribute__((address_space(3))) void*)(l), 16, 0, 0)
#define GLDS4(l, g)  __builtin_amdgcn_global_load_lds((const __attribute__((address_space(1))) void*)(g), (__attribute__((address_space(3))) void*)(l), 4, 0, 0)

#define KEY_INF 0xFF800000FFFFFFFFull

// ---------- init ----------
__global__ void k_init(unsigned int* glob){
  int i = blockIdx.x*256 + threadIdx.x;
  if (i < B_*1024) glob[i] = 0x007FFFFFu;   // fmap(-inf)
}

// ---------- KNN #1: nearest other point (exact fp32) ----------
__global__ __launch_bounds__(256) void k_nn1(const float* __restrict__ pts,
                                             unsigned long long* __restrict__ nn64){
  __shared__ float sp[2048*3];
  int b = blockIdx.z, s = blockIdx.y;
  int c0 = s*2048;
  const float* P = pts + (size_t)b*N_*3;
  for (int i = threadIdx.x; i < 2048*3; i += 256) sp[i] = P[c0*3 + i];
  __syncthreads();
  int n = blockIdx.x*256 + threadIdx.x;
  float qx = P[n*3], qy = P[n*3+1], qz = P[n*3+2];
  float best = 1e30f; int bi = 0;
  for (int j = 0; j < 2048; ++j){
    float dx = qx - sp[j*3], dy = qy - sp[j*3+1], dz = qz - sp[j*3+2];
    float d2 = fmaf(dx,dx, fmaf(dy,dy, dz*dz));
    int cj = c0 + j;
    if (d2 < best && cj != n){ best = d2; bi = cj; }
  }
  unsigned long long key = ((unsigned long long)__float_as_uint(best) << 32) | (unsigned int)bi;
  atomicMin(&nn64[(size_t)b*N_ + n], key);
}

// ---------- local_cov + 3 convs (12->64->64->64, relu each) ----------
__global__ __launch_bounds__(256) void k_cov_mlp(const float* __restrict__ pts,
    const unsigned long long* __restrict__ nn64,
    const float* __restrict__ w1, const float* __restrict__ b1,
    const float* __restrict__ w2, const float* __restrict__ b2,
    const float* __restrict__ w3, const float* __restrict__ b3,
    float* __restrict__ xout){
  __shared__ __align__(16) float W1t[12*64];
  __shared__ __align__(16) float W2t[64*64];
  __shared__ __align__(16) float W3t[64*64];
  __shared__ float B1[64], B2[64], B3[64];
  __shared__ __align__(16) float x0[64][12];
  __shared__ __align__(16) float h1[64][64];
  __shared__ __align__(16) float h2[64][64];
  int b = blockIdx.y; int n0 = blockIdx.x*64; int tid = threadIdx.x;
  for (int i = tid; i < 12*64; i += 256){ int o = i % 64, ci = i / 64; W1t[i] = w1[o*12 + ci]; }
  for (int i = tid; i < 64*64; i += 256){ int o = i % 64, ci = i / 64; W2t[i] = w2[o*64 + ci]; W3t[i] = w3[o*64 + ci]; }
  if (tid < 64){ B1[tid]=b1[tid]; B2[tid]=b2[tid]; B3[tid]=b3[tid]; }
  {
    int p = tid % 64, cg = tid / 64;
    int n = n0 + p;
    const float* P = pts + ((size_t)b*N_ + n)*3;
    int nb = (int)(nn64[(size_t)b*N_ + n] & 0xFFFFFFFFull);
    const float* Q = pts + ((size_t)b*N_ + nb)*3;
    if (cg == 0){ x0[p][0]=P[0]; x0[p][1]=P[1]; x0[p][2]=P[2]; }
    else { int i = cg-1; float pi = P[i];
      x0[p][3+i*3+0]=pi*Q[0]; x0[p][3+i*3+1]=pi*Q[1]; x0[p][3+i*3+2]=pi*Q[2]; }
  }
  __syncthreads();
  { int o = tid % 64, pg = tid / 64;
    for (int p = pg; p < 64; p += 4){
      float acc = B1[o];
#pragma unroll
      for (int ci = 0; ci < 12; ++ci) acc = fmaf(W1t[ci*64+o], x0[p][ci], acc);
      h1[p][o] = fmaxf(acc, 0.f);
    } }
  __syncthreads();
  { int o = tid % 64, pg = tid / 64;
    for (int p = pg; p < 64; p += 4){
      float acc = B2[o];
#pragma unroll
      for (int ci = 0; ci < 64; ++ci) acc = fmaf(W2t[ci*64+o], h1[p][ci], acc);
      h2[p][o] = fmaxf(acc, 0.f);
    } }
  __syncthreads();
  { int o = tid % 64, pg = tid / 64;
    for (int p = pg; p < 64; p += 4){
      float acc = B3[o];
#pragma unroll
      for (int ci = 0; ci < 64; ++ci) acc = fmaf(W3t[ci*64+o], h2[p][ci], acc);
      xout[((size_t)b*N_ + n0 + p)*64 + o] = fmaxf(acc, 0.f);
    } }
}

// ---------- prep: bf16 hi/lo split into K-major granule layout + norms ----------
// T layout: [b][kf][pl 2][hi8 2][n 8192][16B granule]; granule = 8 bf16 ch.
template<int KF>
__global__ __launch_bounds__(256) void k_prep4(const float* __restrict__ f,
    unsigned short* __restrict__ T, float* __restrict__ cc){
  int b = blockIdx.y; int n = blockIdx.x*256 + threadIdx.x;
  const float* src = f + ((size_t)b*N_ + n)*(KF*16);
  char* Tb = (char*)T;
  float ss = 0.f;
#pragma unroll
  for (int kf = 0; kf < KF; ++kf){
    float v[16];
#pragma unroll
    for (int c4 = 0; c4 < 4; ++c4){
      float4 t4 = *(const float4*)&src[kf*16 + c4*4];
      v[c4*4]=t4.x; v[c4*4+1]=t4.y; v[c4*4+2]=t4.z; v[c4*4+3]=t4.w;
    }
    unsigned short hs[16], ls[16];
#pragma unroll
    for (int c = 0; c < 16; ++c){
      float x = v[c];
      ss = fmaf(x, x, ss);
      __bf16 h = (__bf16)x;
      __bf16 l = (__bf16)(x - (float)h);
      hs[c] = __builtin_bit_cast(unsigned short, h);
      ls[c] = __builtin_bit_cast(unsigned short, l);
    }
    size_t base = ((((size_t)b*KF + kf)*2)*2)*(size_t)(N_*16) + (size_t)n*16;
    const size_t HS = (size_t)N_*16;           // hi8 stride
    const size_t PS = 2*HS;                    // plane stride
    *(uint4*)(Tb + base)            = *(uint4*)&hs[0];
    *(uint4*)(Tb + base + HS)       = *(uint4*)&hs[8];
    *(uint4*)(Tb + base + PS)       = *(uint4*)&ls[0];
    *(uint4*)(Tb + base + PS + HS)  = *(uint4*)&ls[8];
  }
  cc[(size_t)b*N_ + n] = ss;
}

// ---------- KNN phase A: distance-only top-16 -> per-(query,split) threshold ----------
// block 256 thr / 4 waves; each wave owns 32 queries (col = lane&31).
template<int KF, int S>
__global__ __launch_bounds__(256, 2) void k_knnA(const unsigned short* __restrict__ T,
    const float* __restrict__ ccg, float* __restrict__ thrq){
  extern __shared__ char smem[];
  constexpr int ABUF = KF*4096;
  constexpr int NT   = (N_/S)/64;
  char* As = smem;
  char* Cs = smem + 2*ABUF;

  const int tid = threadIdx.x, lane = tid & 63, wid = tid >> 6;
  const int hi = lane >> 5, l31 = lane & 31;
  const int b = blockIdx.z, sp = blockIdx.y, q0 = blockIdx.x*128;
  const int c0 = sp*(N_/S);
  const char* Tb = (const char*)T;
  const size_t HS = (size_t)N_*16, PS = 2*HS, KS = 4*HS;
  const size_t Bb = (size_t)b*KF*KS;
  const float* ccb = ccg + (size_t)b*N_;

  const int q = q0 + wid*32 + l31;
  bf16x8 qh[KF], ql[KF];
#pragma unroll
  for (int kf = 0; kf < KF; ++kf){
    size_t o = Bb + kf*KS + hi*HS + (size_t)q*16;
    qh[kf] = *(const bf16x8*)(Tb + o);
    ql[kf] = *(const bf16x8*)(Tb + o + PS);
  }

  float d16[16];
#pragma unroll
  for (int t = 0; t < 16; ++t) d16[t] = 1e30f;

  auto stage = [&](int bf, int t0){
#pragma unroll
    for (int si = 0; si < KF; ++si){
      int s = wid + 4*si;
      int kf = s >> 2, pl = (s >> 1) & 1, h = s & 1;
      GLDS16(As + (bf*KF*4 + s)*1024,
             Tb + Bb + kf*KS + pl*PS + h*HS + (size_t)(c0 + t0)*16);
    }
    if (wid == 0) GLDS4(Cs + bf*256, (const char*)(ccb + c0 + t0));
  };

  stage(0, 0);
  for (int t = 0; t < NT; ++t){
    const int bf = t & 1, t0 = t*64;
    asm volatile("s_waitcnt vmcnt(0)" ::: "memory");
    __syncthreads();
    if (t + 1 < NT) stage(bf ^ 1, (t+1)*64);

    const char* Ab = As + bf*ABUF + hi*1024 + l31*16;
    const float* cct = (const float*)(Cs + bf*256);
#pragma unroll
    for (int i = 0; i < 2; ++i){
      f32x16 acc = (f32x16)(0.f);
#pragma unroll
      for (int kf = 0; kf < KF; ++kf){
        bf16x8 ah = *(const bf16x8*)(Ab + kf*4096 + i*512);
        bf16x8 al = *(const bf16x8*)(Ab + kf*4096 + 2048 + i*512);
        acc = __builtin_amdgcn_mfma_f32_32x32x16_bf16(ah, qh[kf], acc, 0, 0, 0);
        acc = __builtin_amdgcn_mfma_f32_32x32x16_bf16(ah, ql[kf], acc, 0, 0, 0);
        acc = __builtin_amdgcn_mfma_f32_32x32x16_bf16(al, qh[kf], acc, 0, 0, 0);
      }
#pragma unroll
      for (int rq = 0; rq < 4; ++rq){
        float4 c4 = *(const float4*)(cct + i*32 + 4*hi + 8*rq);
        insf(d16, fmaf(-2.f, acc[rq*4+0], c4.x));
        insf(d16, fmaf(-2.f, acc[rq*4+1], c4.y));
        insf(d16, fmaf(-2.f, acc[rq*4+2], c4.z));
        insf(d16, fmaf(-2.f, acc[rq*4+3], c4.w));
      }
    }
  }
  // merge partner (lane^32) half-row list: snapshot first (lockstep-safe)
  float pl16[16];
#pragma unroll
  for (int t = 0; t < 16; ++t) pl16[t] = __shfl(d16[t], lane ^ 32);
#pragma unroll
  for (int t = 0; t < 16; ++t) insf(d16, pl16[t]);
  if (lane < 32) thrq[((size_t)b*N_ + q)*S + sp] = d16[15];
}

// ---------- KNN phase B: collect all v <= min-threshold (bitwise-identical GEMM) ----------
template<int KF, int S>
__global__ __launch_bounds__(256, 2) void k_knnB(const unsigned short* __restrict__ T,
    const float* __restrict__ ccg, const float* __restrict__ thrq,
    unsigned int* __restrict__ qcnt, ull* __restrict__ qkeys){
  extern __shared__ char smem[];
  constexpr int ABUF = KF*4096;
  constexpr int NT   = (N_/S)/64;
  char* As = smem;
  char* Cs = smem + 2*ABUF;

  const int tid = threadIdx.x, lane = tid & 63, wid = tid >> 6;
  const int hi = lane >> 5, l31 = lane & 31;
  const int b = blockIdx.z, sp = blockIdx.y, q0 = blockIdx.x*128;
  const int c0 = sp*(N_/S);
  const char* Tb = (const char*)T;
  const size_t HS = (size_t)N_*16, PS = 2*HS, KS = 4*HS;
  const size_t Bb = (size_t)b*KF*KS;
  const float* ccb = ccg + (size_t)b*N_;

  const int q = q0 + wid*32 + l31;
  bf16x8 qh[KF], ql[KF];
#pragma unroll
  for (int kf = 0; kf < KF; ++kf){
    size_t o = Bb + kf*KS + hi*HS + (size_t)q*16;
    qh[kf] = *(const bf16x8*)(Tb + o);
    ql[kf] = *(const bf16x8*)(Tb + o + PS);
  }
  float thr;
  { const float* tq = thrq + ((size_t)b*N_ + q)*S;
    thr = tq[0];
#pragma unroll
    for (int s = 1; s < S; ++s) thr = fminf(thr, tq[s]); }
  unsigned int* cp = qcnt + (size_t)b*N_ + q;
  ull* kp = qkeys + ((size_t)b*N_ + q)*32;

  auto stage = [&](int bf, int t0){
#pragma unroll
    for (int si = 0; si < KF; ++si){
      int s = wid + 4*si;
      int kf = s >> 2, pl = (s >> 1) & 1, h = s & 1;
      GLDS16(As + (bf*KF*4 + s)*1024,
             Tb + Bb + kf*KS + pl*PS + h*HS + (size_t)(c0 + t0)*16);
    }
    if (wid == 0) GLDS4(Cs + bf*256, (const char*)(ccb + c0 + t0));
  };

  stage(0, 0);
  for (int t = 0; t < NT; ++t){
    const int bf = t & 1, t0 = t*64;
    asm volatile("s_waitcnt vmcnt(0)" ::: "memory");
    __syncthreads();
    if (t + 1 < NT) stage(bf ^ 1, (t+1)*64);

    const char* Ab = As + bf*ABUF + hi*1024 + l31*16;
    const float* cct = (const float*)(Cs + bf*256);
#pragma unroll
    for (int i = 0; i < 2; ++i){
      f32x16 acc = (f32x16)(0.f);
#pragma unroll
      for (int kf = 0; kf < KF; ++kf){
        bf16x8 ah = *(const bf16x8*)(Ab + kf*4096 + i*512);
        bf16x8 al = *(const bf16x8*)(Ab + kf*4096 + 2048 + i*512);
        acc = __builtin_amdgcn_mfma_f32_32x32x16_bf16(ah, qh[kf], acc, 0, 0, 0);
        acc = __builtin_amdgcn_mfma_f32_32x32x16_bf16(ah, ql[kf], acc, 0, 0, 0);
        acc = __builtin_amdgcn_mfma_f32_32x32x16_bf16(al, qh[kf], acc, 0, 0, 0);
      }
#pragma unroll
      for (int rq = 0; rq < 4; ++rq){
        float4 c4 = *(const float4*)(cct + i*32 + 4*hi + 8*rq);
        int rowb = c0 + t0 + i*32 + 4*hi + 8*rq;
        float vv[4];
        vv[0] = fmaf(-2.f, acc[rq*4+0], c4.x);
        vv[1] = fmaf(-2.f, acc[rq*4+1], c4.y);
        vv[2] = fmaf(-2.f, acc[rq*4+2], c4.z);
        vv[3] = fmaf(-2.f, acc[rq*4+3], c4.w);
#pragma unroll
        for (int u = 0; u < 4; ++u){
          if (vv[u] <= thr){
            unsigned slot = atomicAdd(cp, 1u);
            if (slot < 32) kp[slot] = ((ull)fmap(vv[u]) << 32) | (unsigned)(rowb + u);
          }
        }
      }
    }
  }
}

// ---------- final exact top-16 over collected candidates ----------
__global__ void k_sel(const unsigned int* __restrict__ qcnt,
                      const ull* __restrict__ qkeys, int* __restrict__ idxout){
  int i = blockIdx.x*256 + threadIdx.x;
  if (i >= B_*N_) return;
  int cnt = (int)min(qcnt[i], 32u);
  ull best[16];
#pragma unroll
  for (int t = 0; t < 16; ++t) best[t] = KEY_INF;
  const ull* kp = qkeys + (size_t)i*32;
  for (int t = 0; t < cnt; ++t) ins16(best, kp[t]);
  int* op = idxout + (size_t)i*16;
#pragma unroll
  for (int t = 0; t < 16; ++t) op[t] = (int)(best[t] & 0xffffffffu);
}

// ---------- maxpool(x) + conv 64->64 relu + conv 64->128 ----------
__global__ __launch_bounds__(256) void k_gpool_mlp(const float* __restrict__ x,
    const int* __restrict__ idx,
    const float* __restrict__ g1a, const float* __restrict__ g1ab,
    const float* __restrict__ g1b, const float* __restrict__ g1bb,
    float* __restrict__ gout){
  __shared__ __align__(16) float Wt1[64*64];
  __shared__ __align__(16) float Wt2[64*128];
  __shared__ float Ba[64], Bb[128];
  __shared__ __align__(16) float m[64][64];
  __shared__ __align__(16) float r[64][64];
  int b = blockIdx.y; int n0 = blockIdx.x*64; int tid = threadIdx.x;
  for (int i = tid; i < 64*64; i += 256){ int o = i%64, ci = i/64; Wt1[i] = g1a[o*64+ci]; }
  for (int i = tid; i < 64*128; i += 256){ int o = i%128, ci = i/128; Wt2[i] = g1b[o*64+ci]; }
  if (tid < 64) Ba[tid] = g1ab[tid];
  if (tid < 128) Bb[tid] = g1bb[tid];
  { int p = tid/4, cg = tid%4; int n = n0 + p;
    const int* ip = idx + ((size_t)b*N_ + n)*16;
    float mm[16];
#pragma unroll
    for (int u = 0; u < 16; ++u) mm[u] = -1e30f;
    for (int k = 0; k < 16; ++k){
      int nb = ip[k];
      const float4* src = (const float4*)(x + ((size_t)b*N_ + nb)*64 + cg*16);
#pragma unroll
      for (int u = 0; u < 4; ++u){
        float4 v = src[u];
        mm[4*u  ] = fmaxf(mm[4*u  ], v.x); mm[4*u+1] = fmaxf(mm[4*u+1], v.y);
        mm[4*u+2] = fmaxf(mm[4*u+2], v.z); mm[4*u+3] = fmaxf(mm[4*u+3], v.w);
      }
    }
#pragma unroll
    for (int u = 0; u < 16; ++u) m[p][cg*16+u] = mm[u];
  }
  __syncthreads();
  { int o = tid%64, pg = tid/64;
    float acc[16];
#pragma unroll
    for (int u = 0; u < 16; ++u) acc[u] = Ba[o];
    for (int ci = 0; ci < 64; ci += 4){
      float w0 = Wt1[ci*64+o], w1_ = Wt1[(ci+1)*64+o], w2_ = Wt1[(ci+2)*64+o], w3_ = Wt1[(ci+3)*64+o];
#pragma unroll
      for (int u = 0; u < 16; ++u){
        float4 mv = *(const float4*)&m[pg*16+u][ci];
        acc[u] = fmaf(w0, mv.x, acc[u]); acc[u] = fmaf(w1_, mv.y, acc[u]);
        acc[u] = fmaf(w2_, mv.z, acc[u]); acc[u] = fmaf(w3_, mv.w, acc[u]);
      }
    }
#pragma unroll
    for (int u = 0; u < 16; ++u) r[pg*16+u][o] = fmaxf(acc[u], 0.f);
  }
  __syncthreads();
  { int o = tid%128, pg = tid/128;   // no relu on this conv
    float acc[32];
#pragma unroll
    for (int u = 0; u < 32; ++u) acc[u] = Bb[o];
    for (int ci = 0; ci < 64; ci += 4){
      float w0 = Wt2[ci*128+o], w1_ = Wt2[(ci+1)*128+o], w2_ = Wt2[(ci+2)*128+o], w3_ = Wt2[(ci+3)*128+o];
#pragma unroll
      for (int u = 0; u < 32; ++u){
        float4 rv = *(const float4*)&r[pg*32+u][ci];
        acc[u] = fmaf(w0, rv.x, acc[u]); acc[u] = fmaf(w1_, rv.y, acc[u]);
        acc[u] = fmaf(w2_, rv.z, acc[u]); acc[u] = fmaf(w3_, rv.w, acc[u]);
      }
    }
#pragma unroll
    for (int u = 0; u < 32; ++u)
      gout[((size_t)b*N_ + n0 + pg*32 + u)*128 + o] = acc[u];
  }
}

// ---------- maxpool(g) + conv 128->128 relu + conv 128->1024 + global max ----------
__global__ __launch_bounds__(256) void k_hpool_max(const float* __restrict__ g,
    const int* __restrict__ idx,
    const float* __restrict__ g2a, const float* __restrict__ g2ab,
    const float* __restrict__ g2b, const float* __restrict__ g2bb,
    unsigned int* __restrict__ glob){
  __shared__ __align__(16) float m[32][128];
  __shared__ __align__(16) float t[32][128];
  int b = blockIdx.y; int n0 = blockIdx.x*32; int tid = threadIdx.x;
  { int p = tid/8, cg = tid%8; int n = n0+p;
    const int* ip = idx + ((size_t)b*N_+n)*16;
    float mm[16];
#pragma unroll
    for (int u = 0; u < 16; ++u) mm[u] = -1e30f;
    for (int k = 0; k < 16; ++k){
      int nb = ip[k];
      const float4* src = (const float4*)(g + ((size_t)b*N_+nb)*128 + cg*16);
#pragma unroll
      for (int u = 0; u < 4; ++u){
        float4 v = src[u];
        mm[4*u  ] = fmaxf(mm[4*u  ], v.x); mm[4*u+1] = fmaxf(mm[4*u+1], v.y);
        mm[4*u+2] = fmaxf(mm[4*u+2], v.z); mm[4*u+3] = fmaxf(mm[4*u+3], v.w);
      }
    }
#pragma unroll
    for (int u = 0; u < 16; ++u) m[p][cg*16+u] = mm[u];
  }
  __syncthreads();
  { int o = tid%128, pg = tid/128;
    float acc[16];
#pragma unroll
    for (int u = 0; u < 16; ++u) acc[u] = g2ab[o];
    const float4* wrow = (const float4*)(g2a + (size_t)o*128);
    for (int c4 = 0; c4 < 32; ++c4){
      float4 wv = wrow[c4];
#pragma unroll
      for (int u = 0; u < 16; ++u){
        float4 mv = *(const float4*)&m[pg*16+u][c4*4];
        acc[u] = fmaf(wv.x,mv.x,acc[u]); acc[u] = fmaf(wv.y,mv.y,acc[u]);
        acc[u] = fmaf(wv.z,mv.z,acc[u]); acc[u] = fmaf(wv.w,mv.w,acc[u]);
      }
    }
#pragma unroll
    for (int u = 0; u < 16; ++u) t[pg*16+u][o] = fmaxf(acc[u], 0.f);
  }
  __syncthreads();
  for (int oc = 0; oc < 4; ++oc){
    int o = oc*256 + tid;
    const float4* wrow = (const float4*)(g2b + (size_t)o*128);
    float acc[32];
#pragma unroll
    for (int u = 0; u < 32; ++u) acc[u] = 0.f;
    for (int c4 = 0; c4 < 32; ++c4){
      float4 wv = wrow[c4];
#pragma unroll
      for (int u = 0; u < 32; ++u){
        float4 tv = *(const float4*)&t[u][c4*4];
        acc[u] = fmaf(wv.x,tv.x,acc[u]); acc[u] = fmaf(wv.y,tv.y,acc[u]);
        acc[u] = fmaf(wv.z,tv.z,acc[u]); acc[u] = fmaf(wv.w,tv.w,acc[u]);
      }
    }
    float bias = g2bb[o];
    float mx = -1e30f;
#pragma unroll
    for (int u = 0; u < 32; ++u) mx = fmaxf(mx, acc[u] + bias);
    atomicMax(&glob[b*1024 + o], fmap(mx));
  }
}

// ---------- code MLP + decoder base precompute ----------
__global__ __launch_bounds__(512) void k_code(const unsigned int* __restrict__ glob,
    const float* __restrict__ m1, const float* __restrict__ m1b,
    const float* __restrict__ m2, const float* __restrict__ m2b,
    const float* __restrict__ f1a, const float* __restrict__ f1ab,
    const float* __restrict__ f2a, const float* __restrict__ f2ab,
    float* __restrict__ base1, float* __restrict__ base2){
  __shared__ __align__(16) float gl_s[1024];
  __shared__ __align__(16) float hid_s[512];
  __shared__ __align__(16) float code_s[512];
  int b = blockIdx.x; int tid = threadIdx.x;
  for (int i = tid; i < 1024; i += 512) gl_s[i] = funmap(glob[b*1024+i]);
  __syncthreads();
  { float acc = m1b[tid];
    const float4* wr = (const float4*)(m1 + (size_t)tid*1024);
    for (int c4 = 0; c4 < 256; ++c4){ float4 wv = wr[c4]; float4 gv = *(const float4*)&gl_s[c4*4];
      acc = fmaf(wv.x,gv.x,acc); acc = fmaf(wv.y,gv.y,acc);
      acc = fmaf(wv.z,gv.z,acc); acc = fmaf(wv.w,gv.w,acc); }
    hid_s[tid] = fmaxf(acc, 0.f);
  }
  __syncthreads();
  { float acc = m2b[tid];
    const float4* wr = (const float4*)(m2 + (size_t)tid*512);
    for (int c4 = 0; c4 < 128; ++c4){ float4 wv = wr[c4]; float4 hv = *(const float4*)&hid_s[c4*4];
      acc = fmaf(wv.x,hv.x,acc); acc = fmaf(wv.y,hv.y,acc);
      acc = fmaf(wv.z,hv.z,acc); acc = fmaf(wv.w,hv.w,acc); }
    code_s[tid] = acc;
  }
  __syncthreads();
  { float acc = f1ab[tid];
    const float* wr = f1a + (size_t)tid*514;
    for (int c = 0; c < 512; ++c) acc = fmaf(wr[c], code_s[c], acc);
    base1[b*512 + tid] = acc;
  }
  { float acc = f2ab[tid];
    const float* wr = f2a + (size_t)tid*515;
    for (int c = 0; c < 512; ++c) acc = fmaf(wr[c], code_s[c], acc);
    base2[b*512 + tid] = acc;
  }
}

// ---------- folding decoder ----------
template<int NIN>
__global__ __launch_bounds__(256) void k_fold(const float* __restrict__ base,
    const float* __restrict__ fa,
    const float* __restrict__ fb, const float* __restrict__ fbb,
    const float* __restrict__ fc, const float* __restrict__ fcb,
    const float* __restrict__ pin, float* __restrict__ pout){
  __shared__ __align__(16) float y1[32][512];
  __shared__ __align__(16) float y2[32][516];
  __shared__ float pcoord[32][NIN];
  int b = blockIdx.y; int m0 = blockIdx.x*32; int tid = threadIdx.x;
  if (tid < 32*NIN){
    int p = tid / NIN, c = tid % NIN;
    int mm = min(m0 + p, M_-1);
    float v;
    if (NIN == 2){
      const float step = 0.6f/44.f;
      int ii = (c == 0) ? (mm/GRID_) : (mm%GRID_);
      v = -0.3f + step*ii;
    } else {
      v = pin[((size_t)b*M_ + mm)*3 + c];
    }
    pcoord[p][c] = v;
  }
  __syncthreads();
  const int stride_a = 512 + NIN;
  for (int rep = 0; rep < 2; ++rep){
    int o = rep*256 + tid;
    float av[NIN];
#pragma unroll
    for (int c = 0; c < NIN; ++c) av[c] = fa[(size_t)o*stride_a + 512 + c];
    float bv = base[b*512 + o];
    for (int p = 0; p < 32; ++p){
      float acc = bv;
#pragma unroll
      for (int c = 0; c < NIN; ++c) acc = fmaf(av[c], pcoord[p][c], acc);
      y1[p][o] = fmaxf(acc, 0.f);
    }
  }
  __syncthreads();
  for (int rep = 0; rep < 2; ++rep){
    int o2 = rep*256 + tid;
    const float* wr = fb + (size_t)o2*512;
    float acc[32];
#pragma unroll
    for (int u = 0; u < 32; ++u) acc[u] = 0.f;
    for (int c4 = 0; c4 < 128; ++c4){
      float4 wv = *(const float4*)&wr[c4*4];
#pragma unroll
      for (int u = 0; u < 32; ++u){
        float4 yv = *(const float4*)&y1[u][c4*4];
        acc[u] = fmaf(wv.x,yv.x,acc[u]); acc[u] = fmaf(wv.y,yv.y,acc[u]);
        acc[u] = fmaf(wv.z,yv.z,acc[u]); acc[u] = fmaf(wv.w,yv.w,acc[u]);
      }
    }
    float bias = fbb[o2];
#pragma unroll
    for (int u = 0; u < 32; ++u) y2[u][o2] = fmaxf(acc[u] + bias, 0.f);
  }
  __syncthreads();
  if (tid < 96){
    int p = tid / 3, c = tid % 3;
    const float* wr = fc + (size_t)c*512;
    float acc = fcb[c];
    for (int o4 = 0; o4 < 128; ++o4){
      float4 wv = *(const float4*)&wr[o4*4];
      float4 yv = *(const float4*)&y2[p][o4*4];
      acc = fmaf(wv.x,yv.x,acc); acc = fmaf(wv.y,yv.y,acc);
      acc = fmaf(wv.z,yv.z,acc); acc = fmaf(wv.w,yv.w,acc);
    }
    int mm = m0 + p;
    if (mm < M_) pout[((size_t)b*M_ + mm)*3 + c] = acc;
  }
}

// ---------- launcher ----------
extern "C" void kernel_launch(void* const* d_in, const int* in_sizes, int n_in,
                              void* d_out, int out_size, void* d_ws, size_t ws_size,
                              hipStream_t stream){
  const float* pts  = (const float*)d_in[0];
  const float* w1   = (const float*)d_in[1];  const float* b1   = (const float*)d_in[2];
  const float* w2   = (const float*)d_in[3];  const float* b2   = (const float*)d_in[4];
  const float* w3   = (const float*)d_in[5];  const float* b3   = (const float*)d_in[6];
  const float* g1a  = (const float*)d_in[7];  const float* g1ab = (const float*)d_in[8];
  const float* g1b  = (const float*)d_in[9];  const float* g1bb = (const float*)d_in[10];
  const float* g2a  = (const float*)d_in[11]; const float* g2ab = (const float*)d_in[12];
  const float* g2b  = (const float*)d_in[13]; const float* g2bb = (const float*)d_in[14];
  const float* m1   = (const float*)d_in[15]; const float* m1b  = (const float*)d_in[16];
  const float* m2   = (const float*)d_in[17]; const float* m2b  = (const float*)d_in[18];
  const float* f1a  = (const float*)d_in[19]; const float* f1ab = (const float*)d_in[20];
  const float* f1b  = (const float*)d_in[21]; const float* f1bb = (const float*)d_in[22];
  const float* f1c  = (const float*)d_in[23]; const float* f1cb = (const float*)d_in[24];
  const float* f2a  = (const float*)d_in[25]; const float* f2ab = (const float*)d_in[26];
  const float* f2b  = (const float*)d_in[27]; const float* f2bb = (const float*)d_in[28];
  const float* f2c  = (const float*)d_in[29]; const float* f2cb = (const float*)d_in[30];
  float* out = (float*)d_out;

  char* w = (char*)d_ws;
  auto alloc = [&](size_t bytes){ char* p = w; w += (bytes + 255) & ~(size_t)255; return p; };
  unsigned long long* nn64 = (unsigned long long*)alloc((size_t)B_*N_*8);
  float* x    = (float*)alloc((size_t)B_*N_*64*4);
  float* g    = (float*)alloc((size_t)B_*N_*128*4);
  unsigned short* T64  = (unsigned short*)alloc((size_t)B_*4*4*N_*16);   //  8MB
  unsigned short* T128 = (unsigned short*)alloc((size_t)B_*8*4*N_*16);   // 16MB
  float* ccf  = (float*)alloc((size_t)B_*N_*4);
  int*   idx  = (int*)alloc((size_t)B_*N_*16*4);
  float* thrq = (float*)alloc((size_t)B_*N_*2*4);
  unsigned int* qcnt = (unsigned int*)alloc((size_t)B_*N_*4);
  ull*   qkeys = (ull*)alloc((size_t)B_*N_*32*8);                        //  8MB
  unsigned int* glob = (unsigned int*)alloc((size_t)B_*1024*4);
  float* base1 = (float*)alloc((size_t)B_*512*4);
  float* base2 = (float*)alloc((size_t)B_*512*4);
  float* mid   = (float*)alloc((size_t)B_*M_*3*4);
  (void)ws_size; (void)in_sizes; (void)n_in; (void)out_size;

  const int SMEM4 = 2*(4*4096) + 512;    // 33,280 B
  const int SMEM8 = 2*(8*4096) + 512;    // 66,048 B
  hipFuncSetAttribute((const void*)k_knnA<4,2>, hipFuncAttributeMaxDynamicSharedMemorySize, SMEM4);
  hipFuncSetAttribute((const void*)k_knnB<4,2>, hipFuncAttributeMaxDynamicSharedMemorySize, SMEM4);
  hipFuncSetAttribute((const void*)k_knnA<8,2>, hipFuncAttributeMaxDynamicSharedMemorySize, SMEM8);
  hipFuncSetAttribute((const void*)k_knnB<8,2>, hipFuncAttributeMaxDynamicSharedMemorySize, SMEM8);

  hipMemsetAsync(nn64, 0xFF, (size_t)B_*N_*8, stream);
  k_init<<<dim3((B_*1024+255)/256), 256, 0, stream>>>(glob);
  k_nn1<<<dim3(N_/256, 4, B_), 256, 0, stream>>>(pts, nn64);
  k_cov_mlp<<<dim3(N_/64, B_), 256, 0, stream>>>(pts, nn64, w1,b1,w2,b2,w3,b3, x);

  k_prep4<4><<<dim3(N_/256, B_), 256, 0, stream>>>(x, T64, ccf);
  k_knnA<4,2><<<dim3(N_/128, 2, B_), 256, SMEM4, stream>>>(T64, ccf, thrq);
  hipMemsetAsync(qcnt, 0, (size_t)B_*N_*4, stream);
  k_knnB<4,2><<<dim3(N_/128, 2, B_), 256, SMEM4, stream>>>(T64, ccf, thrq, qcnt, qkeys);
  k_sel<<<dim3(B_*N_/256), 256, 0, stream>>>(qcnt, qkeys, idx);

  k_gpool_mlp<<<dim3(N_/64, B_), 256, 0, stream>>>(x, idx, g1a,g1ab,g1b,g1bb, g);

  k_prep4<8><<<dim3(N_/256, B_), 256, 0, stream>>>(g, T128, ccf);
  k_knnA<8,2><<<dim3(N_/128, 2, B_), 256, SMEM8, stream>>>(T128, ccf, thrq);
  hipMemsetAsync(qcnt, 0, (size_t)B_*N_*4, stream);
  k_knnB<8,2><<<dim3(N_/128, 2, B_), 256, SMEM8, stream>>>(T128, ccf, thrq, qcnt, qkeys);
  k_sel<<<dim3(B_*N_/256), 256, 0, stream>>>(qcnt, qkeys, idx);

  k_hpool_max<<<dim3(N_/32, B_), 256, 0, stream>>>(g, idx, g2a,g2ab,g2b,g2bb, glob);
  k_code<<<dim3(B_), 512, 0, stream>>>(glob, m1,m1b,m2,m2b, f1a,f1ab, f2a,f2ab, base1, base2);
  k_fold<2><<<dim3((M_+31)/32, B_), 256, 0, stream>>>(base1, f1a, f1b, f1bb, f1c, f1cb, nullptr, mid);
  k_fold<3><<<dim3((M_+31)/32, B_), 256, 0, stream>>>(base2, f2a, f2b, f2bb, f2c, f2cb, mid, out);
}

// Round 7
// 1958.642 us; speedup vs baseline: 3.1477x; 1.5729x over previous
//
#include <hip/hip_runtime.h>
#include <stdint.h>

#define B_ 4
#define N_ 8192
#define K_ 16
#define FEAT_ 512
#define GRID_ 45
#define M_ (GRID_*GRID_)

typedef unsigned long long ull;
typedef __bf16 bf16x8 __attribute__((ext_vector_type(8)));
typedef float f32x16 __attribute__((ext_vector_type(16)));

// ---------- helpers ----------

__device__ __forceinline__ unsigned int fmap(float f){
  unsigned int u = __float_as_uint(f);
  return (u & 0x80000000u) ? ~u : (u | 0x80000000u);
}
__device__ __forceinline__ float funmap(unsigned int u){
  return (u & 0x80000000u) ? __uint_as_float(u ^ 0x80000000u) : __uint_as_float(~u);
}

// sorted top-16 insert on packed (fmap(dist)<<32 | idx) keys: lex order ==
// jax.lax.top_k tie-break (lower index first). Order-independent.
__device__ __forceinline__ void ins16(ull (&d)[16], ull k){
  if (k < d[15]){
    bool c[16];
#pragma unroll
    for (int s = 0; s < 16; ++s) c[s] = k < d[s];
#pragma unroll
    for (int s = 15; s >= 1; --s) d[s] = c[s-1] ? d[s-1] : (c[s] ? k : d[s]);
    if (c[0]) d[0] = k;
  }
}

// sorted 16-float ascending insert (distance-only, strict <)
__device__ __forceinline__ void insf(float (&d)[16], float v){
  if (v < d[15]){
    bool c[16];
#pragma unroll
    for (int s = 0; s < 16; ++s) c[s] = v < d[s];
#pragma unroll
    for (int s = 15; s >= 1; --s) d[s] = c[s-1] ? d[s-1] : (c[s] ? v : d[s]);
    if (c[0]) d[0] = v;
  }
}

#define GLDS16(l, g) __builtin_amdgcn_global_load_lds((const __attribute__((address_space(1))) void*)(g), (__attribute__((address_space(3))) void*)(l), 16, 0, 0)
#define GLDS4(l, g)  __builtin_amdgcn_global_load_lds((const __attribute__((address_space(1))) void*)(g), (__attribute__((address_space(3))) void*)(l), 4, 0, 0)

#define KEY_INF 0xFF800000FFFFFFFFull

// ---------- init ----------
__global__ void k_init(unsigned int* glob){
  int i = blockIdx.x*256 + threadIdx.x;
  if (i < B_*1024) glob[i] = 0x007FFFFFu;   // fmap(-inf)
}

// ---------- KNN #1: nearest other point (exact fp32) ----------
__global__ __launch_bounds__(256) void k_nn1(const float* __restrict__ pts,
                                             unsigned long long* __restrict__ nn64){
  __shared__ float sp[2048*3];
  int b = blockIdx.z, s = blockIdx.y;
  int c0 = s*2048;
  const float* P = pts + (size_t)b*N_*3;
  for (int i = threadIdx.x; i < 2048*3; i += 256) sp[i] = P[c0*3 + i];
  __syncthreads();
  int n = blockIdx.x*256 + threadIdx.x;
  float qx = P[n*3], qy = P[n*3+1], qz = P[n*3+2];
  float best = 1e30f; int bi = 0;
  for (int j = 0; j < 2048; ++j){
    float dx = qx - sp[j*3], dy = qy - sp[j*3+1], dz = qz - sp[j*3+2];
    float d2 = fmaf(dx,dx, fmaf(dy,dy, dz*dz));
    int cj = c0 + j;
    if (d2 < best && cj != n){ best = d2; bi = cj; }
  }
  unsigned long long key = ((unsigned long long)__float_as_uint(best) << 32) | (unsigned int)bi;
  atomicMin(&nn64[(size_t)b*N_ + n], key);
}

// ---------- local_cov + 3 convs (12->64->64->64, relu each) ----------
__global__ __launch_bounds__(256) void k_cov_mlp(const float* __restrict__ pts,
    const unsigned long long* __restrict__ nn64,
    const float* __restrict__ w1, const float* __restrict__ b1,
    const float* __restrict__ w2, const float* __restrict__ b2,
    const float* __restrict__ w3, const float* __restrict__ b3,
    float* __restrict__ xout){
  __shared__ __align__(16) float W1t[12*64];
  __shared__ __align__(16) float W2t[64*64];
  __shared__ __align__(16) float W3t[64*64];
  __shared__ float B1[64], B2[64], B3[64];
  __shared__ __align__(16) float x0[64][12];
  __shared__ __align__(16) float h1[64][64];
  __shared__ __align__(16) float h2[64][64];
  int b = blockIdx.y; int n0 = blockIdx.x*64; int tid = threadIdx.x;
  for (int i = tid; i < 12*64; i += 256){ int o = i % 64, ci = i / 64; W1t[i] = w1[o*12 + ci]; }
  for (int i = tid; i < 64*64; i += 256){ int o = i % 64, ci = i / 64; W2t[i] = w2[o*64 + ci]; W3t[i] = w3[o*64 + ci]; }
  if (tid < 64){ B1[tid]=b1[tid]; B2[tid]=b2[tid]; B3[tid]=b3[tid]; }
  {
    int p = tid % 64, cg = tid / 64;
    int n = n0 + p;
    const float* P = pts + ((size_t)b*N_ + n)*3;
    int nb = (int)(nn64[(size_t)b*N_ + n] & 0xFFFFFFFFull);
    const float* Q = pts + ((size_t)b*N_ + nb)*3;
    if (cg == 0){ x0[p][0]=P[0]; x0[p][1]=P[1]; x0[p][2]=P[2]; }
    else { int i = cg-1; float pi = P[i];
      x0[p][3+i*3+0]=pi*Q[0]; x0[p][3+i*3+1]=pi*Q[1]; x0[p][3+i*3+2]=pi*Q[2]; }
  }
  __syncthreads();
  { int o = tid % 64, pg = tid / 64;
    for (int p = pg; p < 64; p += 4){
      float acc = B1[o];
#pragma unroll
      for (int ci = 0; ci < 12; ++ci) acc = fmaf(W1t[ci*64+o], x0[p][ci], acc);
      h1[p][o] = fmaxf(acc, 0.f);
    } }
  __syncthreads();
  { int o = tid % 64, pg = tid / 64;
    for (int p = pg; p < 64; p += 4){
      float acc = B2[o];
#pragma unroll
      for (int ci = 0; ci < 64; ++ci) acc = fmaf(W2t[ci*64+o], h1[p][ci], acc);
      h2[p][o] = fmaxf(acc, 0.f);
    } }
  __syncthreads();
  { int o = tid % 64, pg = tid / 64;
    for (int p = pg; p < 64; p += 4){
      float acc = B3[o];
#pragma unroll
      for (int ci = 0; ci < 64; ++ci) acc = fmaf(W3t[ci*64+o], h2[p][ci], acc);
      xout[((size_t)b*N_ + n0 + p)*64 + o] = fmaxf(acc, 0.f);
    } }
}

// ---------- prep: bf16 hi/lo split into K-major granule layout + norms ----------
// T layout: [b][kf][pl 2][hi8 2][n 8192][16B granule]; granule = 8 bf16 ch.
template<int KF>
__global__ __launch_bounds__(256) void k_prep4(const float* __restrict__ f,
    unsigned short* __restrict__ T, float* __restrict__ cc){
  int b = blockIdx.y; int n = blockIdx.x*256 + threadIdx.x;
  const float* src = f + ((size_t)b*N_ + n)*(KF*16);
  char* Tb = (char*)T;
  float ss = 0.f;
#pragma unroll
  for (int kf = 0; kf < KF; ++kf){
    float v[16];
#pragma unroll
    for (int c4 = 0; c4 < 4; ++c4){
      float4 t4 = *(const float4*)&src[kf*16 + c4*4];
      v[c4*4]=t4.x; v[c4*4+1]=t4.y; v[c4*4+2]=t4.z; v[c4*4+3]=t4.w;
    }
    unsigned short hs[16], ls[16];
#pragma unroll
    for (int c = 0; c < 16; ++c){
      float x = v[c];
      ss = fmaf(x, x, ss);
      __bf16 h = (__bf16)x;
      __bf16 l = (__bf16)(x - (float)h);
      hs[c] = __builtin_bit_cast(unsigned short, h);
      ls[c] = __builtin_bit_cast(unsigned short, l);
    }
    size_t base = ((((size_t)b*KF + kf)*2)*2)*(size_t)(N_*16) + (size_t)n*16;
    const size_t HS = (size_t)N_*16;           // hi8 stride
    const size_t PS = 2*HS;                    // plane stride
    *(uint4*)(Tb + base)            = *(uint4*)&hs[0];
    *(uint4*)(Tb + base + HS)       = *(uint4*)&hs[8];
    *(uint4*)(Tb + base + PS)       = *(uint4*)&ls[0];
    *(uint4*)(Tb + base + PS + HS)  = *(uint4*)&ls[8];
  }
  cc[(size_t)b*N_ + n] = ss;
}

// ---------- KNN phase A: distance-only top-16 -> per-(query,split) threshold ----------
template<int KF, int S>
__global__ __launch_bounds__(256, 2) void k_knnA(const unsigned short* __restrict__ T,
    const float* __restrict__ ccg, float* __restrict__ thrq){
  extern __shared__ char smem[];
  constexpr int ABUF = KF*4096;
  constexpr int NT   = (N_/S)/64;
  char* As = smem;
  char* Cs = smem + 2*ABUF;

  const int tid = threadIdx.x, lane = tid & 63, wid = tid >> 6;
  const int hi = lane >> 5, l31 = lane & 31;
  const int b = blockIdx.z, sp = blockIdx.y, q0 = blockIdx.x*128;
  const int c0 = sp*(N_/S);
  const char* Tb = (const char*)T;
  const size_t HS = (size_t)N_*16, PS = 2*HS, KS = 4*HS;
  const size_t Bb = (size_t)b*KF*KS;
  const float* ccb = ccg + (size_t)b*N_;

  const int q = q0 + wid*32 + l31;
  bf16x8 qh[KF], ql[KF];
#pragma unroll
  for (int kf = 0; kf < KF; ++kf){
    size_t o = Bb + kf*KS + hi*HS + (size_t)q*16;
    qh[kf] = *(const bf16x8*)(Tb + o);
    ql[kf] = *(const bf16x8*)(Tb + o + PS);
  }

  float d16[16];
#pragma unroll
  for (int t = 0; t < 16; ++t) d16[t] = 1e30f;

  auto stage = [&](int bf, int t0){
#pragma unroll
    for (int si = 0; si < KF; ++si){
      int s = wid + 4*si;
      int kf = s >> 2, pl = (s >> 1) & 1, h = s & 1;
      GLDS16(As + (bf*KF*4 + s)*1024,
             Tb + Bb + kf*KS + pl*PS + h*HS + (size_t)(c0 + t0)*16);
    }
    if (wid == 0) GLDS4(Cs + bf*256, (const char*)(ccb + c0 + t0));
  };

  stage(0, 0);
  for (int t = 0; t < NT; ++t){
    const int bf = t & 1, t0 = t*64;
    asm volatile("s_waitcnt vmcnt(0)" ::: "memory");
    __syncthreads();
    if (t + 1 < NT) stage(bf ^ 1, (t+1)*64);

    const char* Ab = As + bf*ABUF + hi*1024 + l31*16;
    const float* cct = (const float*)(Cs + bf*256);
#pragma unroll
    for (int i = 0; i < 2; ++i){
      f32x16 acc = (f32x16)(0.f);
#pragma unroll
      for (int kf = 0; kf < KF; ++kf){
        bf16x8 ah = *(const bf16x8*)(Ab + kf*4096 + i*512);
        bf16x8 al = *(const bf16x8*)(Ab + kf*4096 + 2048 + i*512);
        acc = __builtin_amdgcn_mfma_f32_32x32x16_bf16(ah, qh[kf], acc, 0, 0, 0);
        acc = __builtin_amdgcn_mfma_f32_32x32x16_bf16(ah, ql[kf], acc, 0, 0, 0);
        acc = __builtin_amdgcn_mfma_f32_32x32x16_bf16(al, qh[kf], acc, 0, 0, 0);
      }
#pragma unroll
      for (int rq = 0; rq < 4; ++rq){
        float4 c4 = *(const float4*)(cct + i*32 + 4*hi + 8*rq);
        insf(d16, fmaf(-2.f, acc[rq*4+0], c4.x));
        insf(d16, fmaf(-2.f, acc[rq*4+1], c4.y));
        insf(d16, fmaf(-2.f, acc[rq*4+2], c4.z));
        insf(d16, fmaf(-2.f, acc[rq*4+3], c4.w));
      }
    }
  }
  // merge partner (lane^32) half-row list: snapshot first (lockstep-safe)
  float pl16[16];
#pragma unroll
  for (int t = 0; t < 16; ++t) pl16[t] = __shfl(d16[t], lane ^ 32);
#pragma unroll
  for (int t = 0; t < 16; ++t) insf(d16, pl16[t]);
  if (lane < 32) thrq[((size_t)b*N_ + q)*S + sp] = d16[15];
}

// ---------- KNN phase B: collect v <= thr_sp into lane-private regions ----------
// region r = (q, sp, hi): exactly one owning lane; 16 slots; register counter;
// fire-and-forget stores (no atomics, no return dependency).
template<int KF, int S>
__global__ __launch_bounds__(256, 2) void k_knnB(const unsigned short* __restrict__ T,
    const float* __restrict__ ccg, const float* __restrict__ thrq,
    unsigned int* __restrict__ qcnt, ull* __restrict__ qkeys){
  extern __shared__ char smem[];
  constexpr int ABUF = KF*4096;
  constexpr int NT   = (N_/S)/64;
  char* As = smem;
  char* Cs = smem + 2*ABUF;

  const int tid = threadIdx.x, lane = tid & 63, wid = tid >> 6;
  const int hi = lane >> 5, l31 = lane & 31;
  const int b = blockIdx.z, sp = blockIdx.y, q0 = blockIdx.x*128;
  const int c0 = sp*(N_/S);
  const char* Tb = (const char*)T;
  const size_t HS = (size_t)N_*16, PS = 2*HS, KS = 4*HS;
  const size_t Bb = (size_t)b*KF*KS;
  const float* ccb = ccg + (size_t)b*N_;

  const int q = q0 + wid*32 + l31;
  bf16x8 qh[KF], ql[KF];
#pragma unroll
  for (int kf = 0; kf < KF; ++kf){
    size_t o = Bb + kf*KS + hi*HS + (size_t)q*16;
    qh[kf] = *(const bf16x8*)(Tb + o);
    ql[kf] = *(const bf16x8*)(Tb + o + PS);
  }
  const float thr = thrq[((size_t)b*N_ + q)*S + sp];
  const int reg = (int)(sp*2 + hi);
  ull* kp = qkeys + (((size_t)b*N_ + q)*4 + reg)*16;
  int cnt = 0;

  auto stage = [&](int bf, int t0){
#pragma unroll
    for (int si = 0; si < KF; ++si){
      int s = wid + 4*si;
      int kf = s >> 2, pl = (s >> 1) & 1, h = s & 1;
      GLDS16(As + (bf*KF*4 + s)*1024,
             Tb + Bb + kf*KS + pl*PS + h*HS + (size_t)(c0 + t0)*16);
    }
    if (wid == 0) GLDS4(Cs + bf*256, (const char*)(ccb + c0 + t0));
  };

  stage(0, 0);
  for (int t = 0; t < NT; ++t){
    const int bf = t & 1, t0 = t*64;
    asm volatile("s_waitcnt vmcnt(0)" ::: "memory");
    __syncthreads();
    if (t + 1 < NT) stage(bf ^ 1, (t+1)*64);

    const char* Ab = As + bf*ABUF + hi*1024 + l31*16;
    const float* cct = (const float*)(Cs + bf*256);
#pragma unroll
    for (int i = 0; i < 2; ++i){
      f32x16 acc = (f32x16)(0.f);
#pragma unroll
      for (int kf = 0; kf < KF; ++kf){
        bf16x8 ah = *(const bf16x8*)(Ab + kf*4096 + i*512);
        bf16x8 al = *(const bf16x8*)(Ab + kf*4096 + 2048 + i*512);
        acc = __builtin_amdgcn_mfma_f32_32x32x16_bf16(ah, qh[kf], acc, 0, 0, 0);
        acc = __builtin_amdgcn_mfma_f32_32x32x16_bf16(ah, ql[kf], acc, 0, 0, 0);
        acc = __builtin_amdgcn_mfma_f32_32x32x16_bf16(al, qh[kf], acc, 0, 0, 0);
      }
#pragma unroll
      for (int rq = 0; rq < 4; ++rq){
        float4 c4 = *(const float4*)(cct + i*32 + 4*hi + 8*rq);
        int rowb = c0 + t0 + i*32 + 4*hi + 8*rq;
        float vv[4];
        vv[0] = fmaf(-2.f, acc[rq*4+0], c4.x);
        vv[1] = fmaf(-2.f, acc[rq*4+1], c4.y);
        vv[2] = fmaf(-2.f, acc[rq*4+2], c4.z);
        vv[3] = fmaf(-2.f, acc[rq*4+3], c4.w);
#pragma unroll
        for (int u = 0; u < 4; ++u){
          if (vv[u] <= thr && cnt < 16){
            kp[cnt] = ((ull)fmap(vv[u]) << 32) | (unsigned)(rowb + u);
            ++cnt;
          }
        }
      }
    }
  }
  qcnt[((size_t)b*N_ + q)*4 + reg] = (unsigned)cnt;
}

// ---------- final exact top-16 over collected candidates ----------
__global__ void k_sel(const unsigned int* __restrict__ qcnt,
                      const ull* __restrict__ qkeys, int* __restrict__ idxout){
  int i = blockIdx.x*256 + threadIdx.x;
  if (i >= B_*N_) return;
  uint4 qc = *(const uint4*)(qcnt + (size_t)i*4);
  unsigned cs[4] = {qc.x, qc.y, qc.z, qc.w};
  ull best[16];
#pragma unroll
  for (int t = 0; t < 16; ++t) best[t] = KEY_INF;
  const ull* kp = qkeys + (size_t)i*64;
#pragma unroll
  for (int r = 0; r < 4; ++r){
    int cnt = (int)min(cs[r], 16u);
    for (int t = 0; t < cnt; ++t) ins16(best, kp[r*16 + t]);
  }
  int* op = idxout + (size_t)i*16;
#pragma unroll
  for (int t = 0; t < 16; ++t) op[t] = (int)(best[t] & 0xffffffffu);
}

// ---------- maxpool(x) + conv 64->64 relu + conv 64->128 ----------
__global__ __launch_bounds__(256) void k_gpool_mlp(const float* __restrict__ x,
    const int* __restrict__ idx,
    const float* __restrict__ g1a, const float* __restrict__ g1ab,
    const float* __restrict__ g1b, const float* __restrict__ g1bb,
    float* __restrict__ gout){
  __shared__ __align__(16) float Wt1[64*64];
  __shared__ __align__(16) float Wt2[64*128];
  __shared__ float Ba[64], Bb[128];
  __shared__ __align__(16) float m[64][64];
  __shared__ __align__(16) float r[64][64];
  int b = blockIdx.y; int n0 = blockIdx.x*64; int tid = threadIdx.x;
  for (int i = tid; i < 64*64; i += 256){ int o = i%64, ci = i/64; Wt1[i] = g1a[o*64+ci]; }
  for (int i = tid; i < 64*128; i += 256){ int o = i%128, ci = i/128; Wt2[i] = g1b[o*64+ci]; }
  if (tid < 64) Ba[tid] = g1ab[tid];
  if (tid < 128) Bb[tid] = g1bb[tid];
  { int p = tid/4, cg = tid%4; int n = n0 + p;
    const int* ip = idx + ((size_t)b*N_ + n)*16;
    float mm[16];
#pragma unroll
    for (int u = 0; u < 16; ++u) mm[u] = -1e30f;
    for (int k = 0; k < 16; ++k){
      int nb = ip[k];
      const float4* src = (const float4*)(x + ((size_t)b*N_ + nb)*64 + cg*16);
#pragma unroll
      for (int u = 0; u < 4; ++u){
        float4 v = src[u];
        mm[4*u  ] = fmaxf(mm[4*u  ], v.x); mm[4*u+1] = fmaxf(mm[4*u+1], v.y);
        mm[4*u+2] = fmaxf(mm[4*u+2], v.z); mm[4*u+3] = fmaxf(mm[4*u+3], v.w);
      }
    }
#pragma unroll
    for (int u = 0; u < 16; ++u) m[p][cg*16+u] = mm[u];
  }
  __syncthreads();
  { int o = tid%64, pg = tid/64;
    float acc[16];
#pragma unroll
    for (int u = 0; u < 16; ++u) acc[u] = Ba[o];
    for (int ci = 0; ci < 64; ci += 4){
      float w0 = Wt1[ci*64+o], w1_ = Wt1[(ci+1)*64+o], w2_ = Wt1[(ci+2)*64+o], w3_ = Wt1[(ci+3)*64+o];
#pragma unroll
      for (int u = 0; u < 16; ++u){
        float4 mv = *(const float4*)&m[pg*16+u][ci];
        acc[u] = fmaf(w0, mv.x, acc[u]); acc[u] = fmaf(w1_, mv.y, acc[u]);
        acc[u] = fmaf(w2_, mv.z, acc[u]); acc[u] = fmaf(w3_, mv.w, acc[u]);
      }
    }
#pragma unroll
    for (int u = 0; u < 16; ++u) r[pg*16+u][o] = fmaxf(acc[u], 0.f);
  }
  __syncthreads();
  { int o = tid%128, pg = tid/128;   // no relu on this conv
    float acc[32];
#pragma unroll
    for (int u = 0; u < 32; ++u) acc[u] = Bb[o];
    for (int ci = 0; ci < 64; ci += 4){
      float w0 = Wt2[ci*128+o], w1_ = Wt2[(ci+1)*128+o], w2_ = Wt2[(ci+2)*128+o], w3_ = Wt2[(ci+3)*128+o];
#pragma unroll
      for (int u = 0; u < 32; ++u){
        float4 rv = *(const float4*)&r[pg*32+u][ci];
        acc[u] = fmaf(w0, rv.x, acc[u]); acc[u] = fmaf(w1_, rv.y, acc[u]);
        acc[u] = fmaf(w2_, rv.z, acc[u]); acc[u] = fmaf(w3_, rv.w, acc[u]);
      }
    }
#pragma unroll
    for (int u = 0; u < 32; ++u)
      gout[((size_t)b*N_ + n0 + pg*32 + u)*128 + o] = acc[u];
  }
}

// ---------- maxpool(g) + conv 128->128 relu + conv 128->1024 + global max ----------
__global__ __launch_bounds__(256) void k_hpool_max(const float* __restrict__ g,
    const int* __restrict__ idx,
    const float* __restrict__ g2a, const float* __restrict__ g2ab,
    const float* __restrict__ g2b, const float* __restrict__ g2bb,
    unsigned int* __restrict__ glob){
  __shared__ __align__(16) float m[32][128];
  __shared__ __align__(16) float t[32][128];
  int b = blockIdx.y; int n0 = blockIdx.x*32; int tid = threadIdx.x;
  { int p = tid/8, cg = tid%8; int n = n0+p;
    const int* ip = idx + ((size_t)b*N_+n)*16;
    float mm[16];
#pragma unroll
    for (int u = 0; u < 16; ++u) mm[u] = -1e30f;
    for (int k = 0; k < 16; ++k){
      int nb = ip[k];
      const float4* src = (const float4*)(g + ((size_t)b*N_+nb)*128 + cg*16);
#pragma unroll
      for (int u = 0; u < 4; ++u){
        float4 v = src[u];
        mm[4*u  ] = fmaxf(mm[4*u  ], v.x); mm[4*u+1] = fmaxf(mm[4*u+1], v.y);
        mm[4*u+2] = fmaxf(mm[4*u+2], v.z); mm[4*u+3] = fmaxf(mm[4*u+3], v.w);
      }
    }
#pragma unroll
    for (int u = 0; u < 16; ++u) m[p][cg*16+u] = mm[u];
  }
  __syncthreads();
  { int o = tid%128, pg = tid/128;
    float acc[16];
#pragma unroll
    for (int u = 0; u < 16; ++u) acc[u] = g2ab[o];
    const float4* wrow = (const float4*)(g2a + (size_t)o*128);
    for (int c4 = 0; c4 < 32; ++c4){
      float4 wv = wrow[c4];
#pragma unroll
      for (int u = 0; u < 16; ++u){
        float4 mv = *(const float4*)&m[pg*16+u][c4*4];
        acc[u] = fmaf(wv.x,mv.x,acc[u]); acc[u] = fmaf(wv.y,mv.y,acc[u]);
        acc[u] = fmaf(wv.z,mv.z,acc[u]); acc[u] = fmaf(wv.w,mv.w,acc[u]);
      }
    }
#pragma unroll
    for (int u = 0; u < 16; ++u) t[pg*16+u][o] = fmaxf(acc[u], 0.f);
  }
  __syncthreads();
  for (int oc = 0; oc < 4; ++oc){
    int o = oc*256 + tid;
    const float4* wrow = (const float4*)(g2b + (size_t)o*128);
    float acc[32];
#pragma unroll
    for (int u = 0; u < 32; ++u) acc[u] = 0.f;
    for (int c4 = 0; c4 < 32; ++c4){
      float4 wv = wrow[c4];
#pragma unroll
      for (int u = 0; u < 32; ++u){
        float4 tv = *(const float4*)&t[u][c4*4];
        acc[u] = fmaf(wv.x,tv.x,acc[u]); acc[u] = fmaf(wv.y,tv.y,acc[u]);
        acc[u] = fmaf(wv.z,tv.z,acc[u]); acc[u] = fmaf(wv.w,tv.w,acc[u]);
      }
    }
    float bias = g2bb[o];
    float mx = -1e30f;
#pragma unroll
    for (int u = 0; u < 32; ++u) mx = fmaxf(mx, acc[u] + bias);
    atomicMax(&glob[b*1024 + o], fmap(mx));
  }
}

// ---------- code MLP + decoder base precompute ----------
__global__ __launch_bounds__(512) void k_code(const unsigned int* __restrict__ glob,
    const float* __restrict__ m1, const float* __restrict__ m1b,
    const float* __restrict__ m2, const float* __restrict__ m2b,
    const float* __restrict__ f1a, const float* __restrict__ f1ab,
    const float* __restrict__ f2a, const float* __restrict__ f2ab,
    float* __restrict__ base1, float* __restrict__ base2){
  __shared__ __align__(16) float gl_s[1024];
  __shared__ __align__(16) float hid_s[512];
  __shared__ __align__(16) float code_s[512];
  int b = blockIdx.x; int tid = threadIdx.x;
  for (int i = tid; i < 1024; i += 512) gl_s[i] = funmap(glob[b*1024+i]);
  __syncthreads();
  { float acc = m1b[tid];
    const float4* wr = (const float4*)(m1 + (size_t)tid*1024);
    for (int c4 = 0; c4 < 256; ++c4){ float4 wv = wr[c4]; float4 gv = *(const float4*)&gl_s[c4*4];
      acc = fmaf(wv.x,gv.x,acc); acc = fmaf(wv.y,gv.y,acc);
      acc = fmaf(wv.z,gv.z,acc); acc = fmaf(wv.w,gv.w,acc); }
    hid_s[tid] = fmaxf(acc, 0.f);
  }
  __syncthreads();
  { float acc = m2b[tid];
    const float4* wr = (const float4*)(m2 + (size_t)tid*512);
    for (int c4 = 0; c4 < 128; ++c4){ float4 wv = wr[c4]; float4 hv = *(const float4*)&hid_s[c4*4];
      acc = fmaf(wv.x,hv.x,acc); acc = fmaf(wv.y,hv.y,acc);
      acc = fmaf(wv.z,hv.z,acc); acc = fmaf(wv.w,hv.w,acc); }
    code_s[tid] = acc;
  }
  __syncthreads();
  { float acc = f1ab[tid];
    const float* wr = f1a + (size_t)tid*514;
    for (int c = 0; c < 512; ++c) acc = fmaf(wr[c], code_s[c], acc);
    base1[b*512 + tid] = acc;
  }
  { float acc = f2ab[tid];
    const float* wr = f2a + (size_t)tid*515;
    for (int c = 0; c < 512; ++c) acc = fmaf(wr[c], code_s[c], acc);
    base2[b*512 + tid] = acc;
  }
}

// ---------- folding decoder ----------
template<int NIN>
__global__ __launch_bounds__(256) void k_fold(const float* __restrict__ base,
    const float* __restrict__ fa,
    const float* __restrict__ fb, const float* __restrict__ fbb,
    const float* __restrict__ fc, const float* __restrict__ fcb,
    const float* __restrict__ pin, float* __restrict__ pout){
  __shared__ __align__(16) float y1[32][512];
  __shared__ __align__(16) float y2[32][516];
  __shared__ float pcoord[32][NIN];
  int b = blockIdx.y; int m0 = blockIdx.x*32; int tid = threadIdx.x;
  if (tid < 32*NIN){
    int p = tid / NIN, c = tid % NIN;
    int mm = min(m0 + p, M_-1);
    float v;
    if (NIN == 2){
      const float step = 0.6f/44.f;
      int ii = (c == 0) ? (mm/GRID_) : (mm%GRID_);
      v = -0.3f + step*ii;
    } else {
      v = pin[((size_t)b*M_ + mm)*3 + c];
    }
    pcoord[p][c] = v;
  }
  __syncthreads();
  const int stride_a = 512 + NIN;
  for (int rep = 0; rep < 2; ++rep){
    int o = rep*256 + tid;
    float av[NIN];
#pragma unroll
    for (int c = 0; c < NIN; ++c) av[c] = fa[(size_t)o*stride_a + 512 + c];
    float bv = base[b*512 + o];
    for (int p = 0; p < 32; ++p){
      float acc = bv;
#pragma unroll
      for (int c = 0; c < NIN; ++c) acc = fmaf(av[c], pcoord[p][c], acc);
      y1[p][o] = fmaxf(acc, 0.f);
    }
  }
  __syncthreads();
  for (int rep = 0; rep < 2; ++rep){
    int o2 = rep*256 + tid;
    const float* wr = fb + (size_t)o2*512;
    float acc[32];
#pragma unroll
    for (int u = 0; u < 32; ++u) acc[u] = 0.f;
    for (int c4 = 0; c4 < 128; ++c4){
      float4 wv = *(const float4*)&wr[c4*4];
#pragma unroll
      for (int u = 0; u < 32; ++u){
        float4 yv = *(const float4*)&y1[u][c4*4];
        acc[u] = fmaf(wv.x,yv.x,acc[u]); acc[u] = fmaf(wv.y,yv.y,acc[u]);
        acc[u] = fmaf(wv.z,yv.z,acc[u]); acc[u] = fmaf(wv.w,yv.w,acc[u]);
      }
    }
    float bias = fbb[o2];
#pragma unroll
    for (int u = 0; u < 32; ++u) y2[u][o2] = fmaxf(acc[u] + bias, 0.f);
  }
  __syncthreads();
  if (tid < 96){
    int p = tid / 3, c = tid % 3;
    const float* wr = fc + (size_t)c*512;
    float acc = fcb[c];
    for (int o4 = 0; o4 < 128; ++o4){
      float4 wv = *(const float4*)&wr[o4*4];
      float4 yv = *(const float4*)&y2[p][o4*4];
      acc = fmaf(wv.x,yv.x,acc); acc = fmaf(wv.y,yv.y,acc);
      acc = fmaf(wv.z,yv.z,acc); acc = fmaf(wv.w,yv.w,acc);
    }
    int mm = m0 + p;
    if (mm < M_) pout[((size_t)b*M_ + mm)*3 + c] = acc;
  }
}

// ---------- launcher ----------
extern "C" void kernel_launch(void* const* d_in, const int* in_sizes, int n_in,
                              void* d_out, int out_size, void* d_ws, size_t ws_size,
                              hipStream_t stream){
  const float* pts  = (const float*)d_in[0];
  const float* w1   = (const float*)d_in[1];  const float* b1   = (const float*)d_in[2];
  const float* w2   = (const float*)d_in[3];  const float* b2   = (const float*)d_in[4];
  const float* w3   = (const float*)d_in[5];  const float* b3   = (const float*)d_in[6];
  const float* g1a  = (const float*)d_in[7];  const float* g1ab = (const float*)d_in[8];
  const float* g1b  = (const float*)d_in[9];  const float* g1bb = (const float*)d_in[10];
  const float* g2a  = (const float*)d_in[11]; const float* g2ab = (const float*)d_in[12];
  const float* g2b  = (const float*)d_in[13]; const float* g2bb = (const float*)d_in[14];
  const float* m1   = (const float*)d_in[15]; const float* m1b  = (const float*)d_in[16];
  const float* m2   = (const float*)d_in[17]; const float* m2b  = (const float*)d_in[18];
  const float* f1a  = (const float*)d_in[19]; const float* f1ab = (const float*)d_in[20];
  const float* f1b  = (const float*)d_in[21]; const float* f1bb = (const float*)d_in[22];
  const float* f1c  = (const float*)d_in[23]; const float* f1cb = (const float*)d_in[24];
  const float* f2a  = (const float*)d_in[25]; const float* f2ab = (const float*)d_in[26];
  const float* f2b  = (const float*)d_in[27]; const float* f2bb = (const float*)d_in[28];
  const float* f2c  = (const float*)d_in[29]; const float* f2cb = (const float*)d_in[30];
  float* out = (float*)d_out;

  char* w = (char*)d_ws;
  auto alloc = [&](size_t bytes){ char* p = w; w += (bytes + 255) & ~(size_t)255; return p; };
  unsigned long long* nn64 = (unsigned long long*)alloc((size_t)B_*N_*8);
  float* x    = (float*)alloc((size_t)B_*N_*64*4);
  float* g    = (float*)alloc((size_t)B_*N_*128*4);
  unsigned short* T64  = (unsigned short*)alloc((size_t)B_*4*4*N_*16);   //  8MB
  unsigned short* T128 = (unsigned short*)alloc((size_t)B_*8*4*N_*16);   // 16MB
  float* ccf  = (float*)alloc((size_t)B_*N_*4);
  int*   idx  = (int*)alloc((size_t)B_*N_*16*4);
  float* thrq = (float*)alloc((size_t)B_*N_*2*4);
  unsigned int* qcnt = (unsigned int*)alloc((size_t)B_*N_*4*4);
  ull*   qkeys = (ull*)alloc((size_t)B_*N_*64*8);                        // 16MB
  unsigned int* glob = (unsigned int*)alloc((size_t)B_*1024*4);
  float* base1 = (float*)alloc((size_t)B_*512*4);
  float* base2 = (float*)alloc((size_t)B_*512*4);
  float* mid   = (float*)alloc((size_t)B_*M_*3*4);
  (void)ws_size; (void)in_sizes; (void)n_in; (void)out_size;

  const int SMEM4 = 2*(4*4096) + 512;    // 33,280 B
  const int SMEM8 = 2*(8*4096) + 512;    // 66,048 B
  hipFuncSetAttribute((const void*)k_knnA<4,2>, hipFuncAttributeMaxDynamicSharedMemorySize, SMEM4);
  hipFuncSetAttribute((const void*)k_knnB<4,2>, hipFuncAttributeMaxDynamicSharedMemorySize, SMEM4);
  hipFuncSetAttribute((const void*)k_knnA<8,2>, hipFuncAttributeMaxDynamicSharedMemorySize, SMEM8);
  hipFuncSetAttribute((const void*)k_knnB<8,2>, hipFuncAttributeMaxDynamicSharedMemorySize, SMEM8);

  hipMemsetAsync(nn64, 0xFF, (size_t)B_*N_*8, stream);
  k_init<<<dim3((B_*1024+255)/256), 256, 0, stream>>>(glob);
  k_nn1<<<dim3(N_/256, 4, B_), 256, 0, stream>>>(pts, nn64);
  k_cov_mlp<<<dim3(N_/64, B_), 256, 0, stream>>>(pts, nn64, w1,b1,w2,b2,w3,b3, x);

  k_prep4<4><<<dim3(N_/256, B_), 256, 0, stream>>>(x, T64, ccf);
  k_knnA<4,2><<<dim3(N_/128, 2, B_), 256, SMEM4, stream>>>(T64, ccf, thrq);
  k_knnB<4,2><<<dim3(N_/128, 2, B_), 256, SMEM4, stream>>>(T64, ccf, thrq, qcnt, qkeys);
  k_sel<<<dim3(B_*N_/256), 256, 0, stream>>>(qcnt, qkeys, idx);

  k_gpool_mlp<<<dim3(N_/64, B_), 256, 0, stream>>>(x, idx, g1a,g1ab,g1b,g1bb, g);

  k_prep4<8><<<dim3(N_/256, B_), 256, 0, stream>>>(g, T128, ccf);
  k_knnA<8,2><<<dim3(N_/128, 2, B_), 256, SMEM8, stream>>>(T128, ccf, thrq);
  k_knnB<8,2><<<dim3(N_/128, 2, B_), 256, SMEM8, stream>>>(T128, ccf, thrq, qcnt, qkeys);
  k_sel<<<dim3(B_*N_/256), 256, 0, stream>>>(qcnt, qkeys, idx);

  k_hpool_max<<<dim3(N_/32, B_), 256, 0, stream>>>(g, idx, g2a,g2ab,g2b,g2bb, glob);
  k_code<<<dim3(B_), 512, 0, stream>>>(glob, m1,m1b,m2,m2b, f1a,f1ab, f2a,f2ab, base1, base2);
  k_fold<2><<<dim3((M_+31)/32, B_), 256, 0, stream>>>(base1, f1a, f1b, f1bb, f1c, f1cb, nullptr, mid);
  k_fold<3><<<dim3((M_+31)/32, B_), 256, 0, stream>>>(base2, f2a, f2b, f2bb, f2c, f2cb, mid, out);
}

// Round 8
// 1883.076 us; speedup vs baseline: 3.2740x; 1.0401x over previous
//
#include <hip/hip_runtime.h>
#include <stdint.h>

#define B_ 4
#define N_ 8192
#define K_ 16
#define FEAT_ 512
#define GRID_ 45
#define M_ (GRID_*GRID_)

typedef unsigned long long ull;
typedef __bf16 bf16x8 __attribute__((ext_vector_type(8)));
typedef float f32x16 __attribute__((ext_vector_type(16)));

// ---------- helpers ----------

__device__ __forceinline__ unsigned int fmap(float f){
  unsigned int u = __float_as_uint(f);
  return (u & 0x80000000u) ? ~u : (u | 0x80000000u);
}
__device__ __forceinline__ float funmap(unsigned int u){
  return (u & 0x80000000u) ? __uint_as_float(u ^ 0x80000000u) : __uint_as_float(~u);
}

// sorted top-16 insert on packed (fmap(dist)<<32 | idx) keys: lex order ==
// jax.lax.top_k tie-break (lower index first). Order-independent.
__device__ __forceinline__ void ins16(ull (&d)[16], ull k){
  if (k < d[15]){
    bool c[16];
#pragma unroll
    for (int s = 0; s < 16; ++s) c[s] = k < d[s];
#pragma unroll
    for (int s = 15; s >= 1; --s) d[s] = c[s-1] ? d[s-1] : (c[s] ? k : d[s]);
    if (c[0]) d[0] = k;
  }
}

#define GLDS16(l, g) __builtin_amdgcn_global_load_lds((const __attribute__((address_space(1))) void*)(g), (__attribute__((address_space(3))) void*)(l), 16, 0, 0)
#define GLDS4(l, g)  __builtin_amdgcn_global_load_lds((const __attribute__((address_space(1))) void*)(g), (__attribute__((address_space(3))) void*)(l), 4, 0, 0)

#define KEY_INF 0xFF800000FFFFFFFFull

// ---------- init ----------
__global__ void k_init(unsigned int* glob){
  int i = blockIdx.x*256 + threadIdx.x;
  if (i < B_*1024) glob[i] = 0x007FFFFFu;   // fmap(-inf)
}

// ---------- KNN #1: nearest other point (exact fp32) ----------
__global__ __launch_bounds__(256) void k_nn1(const float* __restrict__ pts,
                                             unsigned long long* __restrict__ nn64){
  __shared__ float sp[2048*3];
  int b = blockIdx.z, s = blockIdx.y;
  int c0 = s*2048;
  const float* P = pts + (size_t)b*N_*3;
  for (int i = threadIdx.x; i < 2048*3; i += 256) sp[i] = P[c0*3 + i];
  __syncthreads();
  int n = blockIdx.x*256 + threadIdx.x;
  float qx = P[n*3], qy = P[n*3+1], qz = P[n*3+2];
  float best = 1e30f; int bi = 0;
  for (int j = 0; j < 2048; ++j){
    float dx = qx - sp[j*3], dy = qy - sp[j*3+1], dz = qz - sp[j*3+2];
    float d2 = fmaf(dx,dx, fmaf(dy,dy, dz*dz));
    int cj = c0 + j;
    if (d2 < best && cj != n){ best = d2; bi = cj; }
  }
  unsigned long long key = ((unsigned long long)__float_as_uint(best) << 32) | (unsigned int)bi;
  atomicMin(&nn64[(size_t)b*N_ + n], key);
}

// ---------- local_cov + 3 convs (12->64->64->64, relu each) ----------
__global__ __launch_bounds__(256) void k_cov_mlp(const float* __restrict__ pts,
    const unsigned long long* __restrict__ nn64,
    const float* __restrict__ w1, const float* __restrict__ b1,
    const float* __restrict__ w2, const float* __restrict__ b2,
    const float* __restrict__ w3, const float* __restrict__ b3,
    float* __restrict__ xout){
  __shared__ __align__(16) float W1t[12*64];
  __shared__ __align__(16) float W2t[64*64];
  __shared__ __align__(16) float W3t[64*64];
  __shared__ float B1[64], B2[64], B3[64];
  __shared__ __align__(16) float x0[64][12];
  __shared__ __align__(16) float h1[64][64];
  __shared__ __align__(16) float h2[64][64];
  int b = blockIdx.y; int n0 = blockIdx.x*64; int tid = threadIdx.x;
  for (int i = tid; i < 12*64; i += 256){ int o = i % 64, ci = i / 64; W1t[i] = w1[o*12 + ci]; }
  for (int i = tid; i < 64*64; i += 256){ int o = i % 64, ci = i / 64; W2t[i] = w2[o*64 + ci]; W3t[i] = w3[o*64 + ci]; }
  if (tid < 64){ B1[tid]=b1[tid]; B2[tid]=b2[tid]; B3[tid]=b3[tid]; }
  {
    int p = tid % 64, cg = tid / 64;
    int n = n0 + p;
    const float* P = pts + ((size_t)b*N_ + n)*3;
    int nb = (int)(nn64[(size_t)b*N_ + n] & 0xFFFFFFFFull);
    const float* Q = pts + ((size_t)b*N_ + nb)*3;
    if (cg == 0){ x0[p][0]=P[0]; x0[p][1]=P[1]; x0[p][2]=P[2]; }
    else { int i = cg-1; float pi = P[i];
      x0[p][3+i*3+0]=pi*Q[0]; x0[p][3+i*3+1]=pi*Q[1]; x0[p][3+i*3+2]=pi*Q[2]; }
  }
  __syncthreads();
  { int o = tid % 64, pg = tid / 64;
    for (int p = pg; p < 64; p += 4){
      float acc = B1[o];
#pragma unroll
      for (int ci = 0; ci < 12; ++ci) acc = fmaf(W1t[ci*64+o], x0[p][ci], acc);
      h1[p][o] = fmaxf(acc, 0.f);
    } }
  __syncthreads();
  { int o = tid % 64, pg = tid / 64;
    for (int p = pg; p < 64; p += 4){
      float acc = B2[o];
#pragma unroll
      for (int ci = 0; ci < 64; ++ci) acc = fmaf(W2t[ci*64+o], h1[p][ci], acc);
      h2[p][o] = fmaxf(acc, 0.f);
    } }
  __syncthreads();
  { int o = tid % 64, pg = tid / 64;
    for (int p = pg; p < 64; p += 4){
      float acc = B3[o];
#pragma unroll
      for (int ci = 0; ci < 64; ++ci) acc = fmaf(W3t[ci*64+o], h2[p][ci], acc);
      xout[((size_t)b*N_ + n0 + p)*64 + o] = fmaxf(acc, 0.f);
    } }
}

// ---------- prep: bf16 hi/lo split into K-major granule layout + norms ----------
// T layout: [b][kf][pl 2][hi8 2][n 8192][16B granule]; granule = 8 bf16 ch.
template<int KF>
__global__ __launch_bounds__(256) void k_prep4(const float* __restrict__ f,
    unsigned short* __restrict__ T, float* __restrict__ cc){
  int b = blockIdx.y; int n = blockIdx.x*256 + threadIdx.x;
  const float* src = f + ((size_t)b*N_ + n)*(KF*16);
  char* Tb = (char*)T;
  float ss = 0.f;
#pragma unroll
  for (int kf = 0; kf < KF; ++kf){
    float v[16];
#pragma unroll
    for (int c4 = 0; c4 < 4; ++c4){
      float4 t4 = *(const float4*)&src[kf*16 + c4*4];
      v[c4*4]=t4.x; v[c4*4+1]=t4.y; v[c4*4+2]=t4.z; v[c4*4+3]=t4.w;
    }
    unsigned short hs[16], ls[16];
#pragma unroll
    for (int c = 0; c < 16; ++c){
      float x = v[c];
      ss = fmaf(x, x, ss);
      __bf16 h = (__bf16)x;
      __bf16 l = (__bf16)(x - (float)h);
      hs[c] = __builtin_bit_cast(unsigned short, h);
      ls[c] = __builtin_bit_cast(unsigned short, l);
    }
    size_t base = ((((size_t)b*KF + kf)*2)*2)*(size_t)(N_*16) + (size_t)n*16;
    const size_t HS = (size_t)N_*16;           // hi8 stride
    const size_t PS = 2*HS;                    // plane stride
    *(uint4*)(Tb + base)            = *(uint4*)&hs[0];
    *(uint4*)(Tb + base + HS)       = *(uint4*)&hs[8];
    *(uint4*)(Tb + base + PS)       = *(uint4*)&ls[0];
    *(uint4*)(Tb + base + PS + HS)  = *(uint4*)&ls[8];
  }
  cc[(size_t)b*N_ + n] = ss;
}

// ---------- fused single-pass KNN: MFMA + gated u64 top-16, region output ----------
// block 256 thr / 4 waves; wave owns 32 queries; lane owns region (q, sp, hi);
// LDS binds occupancy (2 blocks/CU) so launch_bounds MW=1 frees VGPRs (no spill).
template<int KF, int MW>
__global__ __launch_bounds__(256, MW) void k_knnF(const unsigned short* __restrict__ T,
    const float* __restrict__ ccg, ull* __restrict__ qkeys){
  extern __shared__ char smem[];
  constexpr int ABUF = KF*4096;
  constexpr int NT   = (N_/2)/64;      // S=2 candidate split
  char* As = smem;
  char* Cs = smem + 2*ABUF;

  const int tid = threadIdx.x, lane = tid & 63, wid = tid >> 6;
  const int hi = lane >> 5, l31 = lane & 31;
  const int b = blockIdx.z, sp = blockIdx.y, q0 = blockIdx.x*128;
  const int c0 = sp*(N_/2);
  const char* Tb = (const char*)T;
  const size_t HS = (size_t)N_*16, PS = 2*HS, KS = 4*HS;
  const size_t Bb = (size_t)b*KF*KS;
  const float* ccb = ccg + (size_t)b*N_;

  const int q = q0 + wid*32 + l31;
  bf16x8 qh[KF], ql[KF];
#pragma unroll
  for (int kf = 0; kf < KF; ++kf){
    size_t o = Bb + kf*KS + hi*HS + (size_t)q*16;
    qh[kf] = *(const bf16x8*)(Tb + o);
    ql[kf] = *(const bf16x8*)(Tb + o + PS);
  }

  ull keys[16];
#pragma unroll
  for (int t = 0; t < 16; ++t) keys[t] = KEY_INF;
  float kapf = __builtin_inff();

  auto stage = [&](int bf, int t0){
#pragma unroll
    for (int si = 0; si < KF; ++si){
      int s = wid + 4*si;
      int kf = s >> 2, pl = (s >> 1) & 1, h = s & 1;
      GLDS16(As + (bf*KF*4 + s)*1024,
             Tb + Bb + kf*KS + pl*PS + h*HS + (size_t)(c0 + t0)*16);
    }
    if (wid == 0) GLDS4(Cs + bf*256, (const char*)(ccb + c0 + t0));
  };

  stage(0, 0);
  for (int t = 0; t < NT; ++t){
    const int bf = t & 1, t0 = t*64;
    asm volatile("s_waitcnt vmcnt(0)" ::: "memory");
    __syncthreads();
    if (t + 1 < NT) stage(bf ^ 1, (t+1)*64);

    const char* Ab = As + bf*ABUF + hi*1024 + l31*16;
    const float* cct = (const float*)(Cs + bf*256);
#pragma unroll
    for (int i = 0; i < 2; ++i){
      f32x16 acc = (f32x16)(0.f);
#pragma unroll
      for (int kf = 0; kf < KF; ++kf){
        bf16x8 ah = *(const bf16x8*)(Ab + kf*4096 + i*512);
        bf16x8 al = *(const bf16x8*)(Ab + kf*4096 + 2048 + i*512);
        acc = __builtin_amdgcn_mfma_f32_32x32x16_bf16(ah, qh[kf], acc, 0, 0, 0);
        acc = __builtin_amdgcn_mfma_f32_32x32x16_bf16(ah, ql[kf], acc, 0, 0, 0);
        acc = __builtin_amdgcn_mfma_f32_32x32x16_bf16(al, qh[kf], acc, 0, 0, 0);
      }
      // v = cc - 2<q,c> (qq dropped: constant per-query shift, order-preserving)
#pragma unroll
      for (int rq = 0; rq < 4; ++rq){
        float4 c4 = *(const float4*)(cct + i*32 + 4*hi + 8*rq);
        int rowb = c0 + t0 + i*32 + 4*hi + 8*rq;
        float v0 = fmaf(-2.f, acc[rq*4+0], c4.x);
        float v1 = fmaf(-2.f, acc[rq*4+1], c4.y);
        float v2 = fmaf(-2.f, acc[rq*4+2], c4.z);
        float v3 = fmaf(-2.f, acc[rq*4+3], c4.w);
        // group gate: skip insert bodies unless some value can qualify
        if (fminf(fminf(v0, v1), fminf(v2, v3)) <= kapf){
          if (v0 <= kapf) ins16(keys, ((ull)fmap(v0) << 32) | (unsigned)(rowb+0));
          if (v1 <= kapf) ins16(keys, ((ull)fmap(v1) << 32) | (unsigned)(rowb+1));
          if (v2 <= kapf) ins16(keys, ((ull)fmap(v2) << 32) | (unsigned)(rowb+2));
          if (v3 <= kapf) ins16(keys, ((ull)fmap(v3) << 32) | (unsigned)(rowb+3));
          kapf = funmap((unsigned)(keys[15] >> 32));  // sentinel -> +inf
        }
      }
    }
  }
  // write region (q, sp, hi): 16 keys, sentinel-padded
  ull* op = qkeys + (((size_t)b*N_ + q)*2 + sp)*32 + hi*16;
#pragma unroll
  for (int t = 0; t < 16; ++t) op[t] = keys[t];
}

// ---------- final exact top-16 over 4 regions x 16 keys ----------
__global__ void k_sel(const ull* __restrict__ qkeys, int* __restrict__ idxout){
  int i = blockIdx.x*256 + threadIdx.x;
  if (i >= B_*N_) return;
  ull best[16];
#pragma unroll
  for (int t = 0; t < 16; ++t) best[t] = KEY_INF;
  const ull* kp = qkeys + (size_t)i*64;
  for (int t = 0; t < 64; ++t) ins16(best, kp[t]);
  int* op = idxout + (size_t)i*16;
#pragma unroll
  for (int t = 0; t < 16; ++t) op[t] = (int)(best[t] & 0xffffffffu);
}

// ---------- maxpool(x) + conv 64->64 relu + conv 64->128 ----------
__global__ __launch_bounds__(256) void k_gpool_mlp(const float* __restrict__ x,
    const int* __restrict__ idx,
    const float* __restrict__ g1a, const float* __restrict__ g1ab,
    const float* __restrict__ g1b, const float* __restrict__ g1bb,
    float* __restrict__ gout){
  __shared__ __align__(16) float Wt1[64*64];
  __shared__ __align__(16) float Wt2[64*128];
  __shared__ float Ba[64], Bb[128];
  __shared__ __align__(16) float m[64][64];
  __shared__ __align__(16) float r[64][64];
  int b = blockIdx.y; int n0 = blockIdx.x*64; int tid = threadIdx.x;
  for (int i = tid; i < 64*64; i += 256){ int o = i%64, ci = i/64; Wt1[i] = g1a[o*64+ci]; }
  for (int i = tid; i < 64*128; i += 256){ int o = i%128, ci = i/128; Wt2[i] = g1b[o*64+ci]; }
  if (tid < 64) Ba[tid] = g1ab[tid];
  if (tid < 128) Bb[tid] = g1bb[tid];
  { int p = tid/4, cg = tid%4; int n = n0 + p;
    const int* ip = idx + ((size_t)b*N_ + n)*16;
    float mm[16];
#pragma unroll
    for (int u = 0; u < 16; ++u) mm[u] = -1e30f;
    for (int k = 0; k < 16; ++k){
      int nb = ip[k];
      const float4* src = (const float4*)(x + ((size_t)b*N_ + nb)*64 + cg*16);
#pragma unroll
      for (int u = 0; u < 4; ++u){
        float4 v = src[u];
        mm[4*u  ] = fmaxf(mm[4*u  ], v.x); mm[4*u+1] = fmaxf(mm[4*u+1], v.y);
        mm[4*u+2] = fmaxf(mm[4*u+2], v.z); mm[4*u+3] = fmaxf(mm[4*u+3], v.w);
      }
    }
#pragma unroll
    for (int u = 0; u < 16; ++u) m[p][cg*16+u] = mm[u];
  }
  __syncthreads();
  { int o = tid%64, pg = tid/64;
    float acc[16];
#pragma unroll
    for (int u = 0; u < 16; ++u) acc[u] = Ba[o];
    for (int ci = 0; ci < 64; ci += 4){
      float w0 = Wt1[ci*64+o], w1_ = Wt1[(ci+1)*64+o], w2_ = Wt1[(ci+2)*64+o], w3_ = Wt1[(ci+3)*64+o];
#pragma unroll
      for (int u = 0; u < 16; ++u){
        float4 mv = *(const float4*)&m[pg*16+u][ci];
        acc[u] = fmaf(w0, mv.x, acc[u]); acc[u] = fmaf(w1_, mv.y, acc[u]);
        acc[u] = fmaf(w2_, mv.z, acc[u]); acc[u] = fmaf(w3_, mv.w, acc[u]);
      }
    }
#pragma unroll
    for (int u = 0; u < 16; ++u) r[pg*16+u][o] = fmaxf(acc[u], 0.f);
  }
  __syncthreads();
  { int o = tid%128, pg = tid/128;   // no relu on this conv
    float acc[32];
#pragma unroll
    for (int u = 0; u < 32; ++u) acc[u] = Bb[o];
    for (int ci = 0; ci < 64; ci += 4){
      float w0 = Wt2[ci*128+o], w1_ = Wt2[(ci+1)*128+o], w2_ = Wt2[(ci+2)*128+o], w3_ = Wt2[(ci+3)*128+o];
#pragma unroll
      for (int u = 0; u < 32; ++u){
        float4 rv = *(const float4*)&r[pg*32+u][ci];
        acc[u] = fmaf(w0, rv.x, acc[u]); acc[u] = fmaf(w1_, rv.y, acc[u]);
        acc[u] = fmaf(w2_, rv.z, acc[u]); acc[u] = fmaf(w3_, rv.w, acc[u]);
      }
    }
#pragma unroll
    for (int u = 0; u < 32; ++u)
      gout[((size_t)b*N_ + n0 + pg*32 + u)*128 + o] = acc[u];
  }
}

// ---------- maxpool(g) + conv 128->128 relu + conv 128->1024 + global max ----------
__global__ __launch_bounds__(256) void k_hpool_max(const float* __restrict__ g,
    const int* __restrict__ idx,
    const float* __restrict__ g2a, const float* __restrict__ g2ab,
    const float* __restrict__ g2b, const float* __restrict__ g2bb,
    unsigned int* __restrict__ glob){
  __shared__ __align__(16) float m[32][128];
  __shared__ __align__(16) float t[32][128];
  int b = blockIdx.y; int n0 = blockIdx.x*32; int tid = threadIdx.x;
  { int p = tid/8, cg = tid%8; int n = n0+p;
    const int* ip = idx + ((size_t)b*N_+n)*16;
    float mm[16];
#pragma unroll
    for (int u = 0; u < 16; ++u) mm[u] = -1e30f;
    for (int k = 0; k < 16; ++k){
      int nb = ip[k];
      const float4* src = (const float4*)(g + ((size_t)b*N_+nb)*128 + cg*16);
#pragma unroll
      for (int u = 0; u < 4; ++u){
        float4 v = src[u];
        mm[4*u  ] = fmaxf(mm[4*u  ], v.x); mm[4*u+1] = fmaxf(mm[4*u+1], v.y);
        mm[4*u+2] = fmaxf(mm[4*u+2], v.z); mm[4*u+3] = fmaxf(mm[4*u+3], v.w);
      }
    }
#pragma unroll
    for (int u = 0; u < 16; ++u) m[p][cg*16+u] = mm[u];
  }
  __syncthreads();
  { int o = tid%128, pg = tid/128;
    float acc[16];
#pragma unroll
    for (int u = 0; u < 16; ++u) acc[u] = g2ab[o];
    const float4* wrow = (const float4*)(g2a + (size_t)o*128);
    for (int c4 = 0; c4 < 32; ++c4){
      float4 wv = wrow[c4];
#pragma unroll
      for (int u = 0; u < 16; ++u){
        float4 mv = *(const float4*)&m[pg*16+u][c4*4];
        acc[u] = fmaf(wv.x,mv.x,acc[u]); acc[u] = fmaf(wv.y,mv.y,acc[u]);
        acc[u] = fmaf(wv.z,mv.z,acc[u]); acc[u] = fmaf(wv.w,mv.w,acc[u]);
      }
    }
#pragma unroll
    for (int u = 0; u < 16; ++u) t[pg*16+u][o] = fmaxf(acc[u], 0.f);
  }
  __syncthreads();
  for (int oc = 0; oc < 4; ++oc){
    int o = oc*256 + tid;
    const float4* wrow = (const float4*)(g2b + (size_t)o*128);
    float acc[32];
#pragma unroll
    for (int u = 0; u < 32; ++u) acc[u] = 0.f;
    for (int c4 = 0; c4 < 32; ++c4){
      float4 wv = wrow[c4];
#pragma unroll
      for (int u = 0; u < 32; ++u){
        float4 tv = *(const float4*)&t[u][c4*4];
        acc[u] = fmaf(wv.x,tv.x,acc[u]); acc[u] = fmaf(wv.y,tv.y,acc[u]);
        acc[u] = fmaf(wv.z,tv.z,acc[u]); acc[u] = fmaf(wv.w,tv.w,acc[u]);
      }
    }
    float bias = g2bb[o];
    float mx = -1e30f;
#pragma unroll
    for (int u = 0; u < 32; ++u) mx = fmaxf(mx, acc[u] + bias);
    atomicMax(&glob[b*1024 + o], fmap(mx));
  }
}

// ---------- code MLP + decoder base precompute ----------
__global__ __launch_bounds__(512) void k_code(const unsigned int* __restrict__ glob,
    const float* __restrict__ m1, const float* __restrict__ m1b,
    const float* __restrict__ m2, const float* __restrict__ m2b,
    const float* __restrict__ f1a, const float* __restrict__ f1ab,
    const float* __restrict__ f2a, const float* __restrict__ f2ab,
    float* __restrict__ base1, float* __restrict__ base2){
  __shared__ __align__(16) float gl_s[1024];
  __shared__ __align__(16) float hid_s[512];
  __shared__ __align__(16) float code_s[512];
  int b = blockIdx.x; int tid = threadIdx.x;
  for (int i = tid; i < 1024; i += 512) gl_s[i] = funmap(glob[b*1024+i]);
  __syncthreads();
  { float acc = m1b[tid];
    const float4* wr = (const float4*)(m1 + (size_t)tid*1024);
    for (int c4 = 0; c4 < 256; ++c4){ float4 wv = wr[c4]; float4 gv = *(const float4*)&gl_s[c4*4];
      acc = fmaf(wv.x,gv.x,acc); acc = fmaf(wv.y,gv.y,acc);
      acc = fmaf(wv.z,gv.z,acc); acc = fmaf(wv.w,gv.w,acc); }
    hid_s[tid] = fmaxf(acc, 0.f);
  }
  __syncthreads();
  { float acc = m2b[tid];
    const float4* wr = (const float4*)(m2 + (size_t)tid*512);
    for (int c4 = 0; c4 < 128; ++c4){ float4 wv = wr[c4]; float4 hv = *(const float4*)&hid_s[c4*4];
      acc = fmaf(wv.x,hv.x,acc); acc = fmaf(wv.y,hv.y,acc);
      acc = fmaf(wv.z,hv.z,acc); acc = fmaf(wv.w,hv.w,acc); }
    code_s[tid] = acc;
  }
  __syncthreads();
  { float acc = f1ab[tid];
    const float* wr = f1a + (size_t)tid*514;
    for (int c = 0; c < 512; ++c) acc = fmaf(wr[c], code_s[c], acc);
    base1[b*512 + tid] = acc;
  }
  { float acc = f2ab[tid];
    const float* wr = f2a + (size_t)tid*515;
    for (int c = 0; c < 512; ++c) acc = fmaf(wr[c], code_s[c], acc);
    base2[b*512 + tid] = acc;
  }
}

// ---------- folding decoder ----------
template<int NIN>
__global__ __launch_bounds__(256) void k_fold(const float* __restrict__ base,
    const float* __restrict__ fa,
    const float* __restrict__ fb, const float* __restrict__ fbb,
    const float* __restrict__ fc, const float* __restrict__ fcb,
    const float* __restrict__ pin, float* __restrict__ pout){
  __shared__ __align__(16) float y1[32][512];
  __shared__ __align__(16) float y2[32][516];
  __shared__ float pcoord[32][NIN];
  int b = blockIdx.y; int m0 = blockIdx.x*32; int tid = threadIdx.x;
  if (tid < 32*NIN){
    int p = tid / NIN, c = tid % NIN;
    int mm = min(m0 + p, M_-1);
    float v;
    if (NIN == 2){
      const float step = 0.6f/44.f;
      int ii = (c == 0) ? (mm/GRID_) : (mm%GRID_);
      v = -0.3f + step*ii;
    } else {
      v = pin[((size_t)b*M_ + mm)*3 + c];
    }
    pcoord[p][c] = v;
  }
  __syncthreads();
  const int stride_a = 512 + NIN;
  for (int rep = 0; rep < 2; ++rep){
    int o = rep*256 + tid;
    float av[NIN];
#pragma unroll
    for (int c = 0; c < NIN; ++c) av[c] = fa[(size_t)o*stride_a + 512 + c];
    float bv = base[b*512 + o];
    for (int p = 0; p < 32; ++p){
      float acc = bv;
#pragma unroll
      for (int c = 0; c < NIN; ++c) acc = fmaf(av[c], pcoord[p][c], acc);
      y1[p][o] = fmaxf(acc, 0.f);
    }
  }
  __syncthreads();
  for (int rep = 0; rep < 2; ++rep){
    int o2 = rep*256 + tid;
    const float* wr = fb + (size_t)o2*512;
    float acc[32];
#pragma unroll
    for (int u = 0; u < 32; ++u) acc[u] = 0.f;
    for (int c4 = 0; c4 < 128; ++c4){
      float4 wv = *(const float4*)&wr[c4*4];
#pragma unroll
      for (int u = 0; u < 32; ++u){
        float4 yv = *(const float4*)&y1[u][c4*4];
        acc[u] = fmaf(wv.x,yv.x,acc[u]); acc[u] = fmaf(wv.y,yv.y,acc[u]);
        acc[u] = fmaf(wv.z,yv.z,acc[u]); acc[u] = fmaf(wv.w,yv.w,acc[u]);
      }
    }
    float bias = fbb[o2];
#pragma unroll
    for (int u = 0; u < 32; ++u) y2[u][o2] = fmaxf(acc[u] + bias, 0.f);
  }
  __syncthreads();
  if (tid < 96){
    int p = tid / 3, c = tid % 3;
    const float* wr = fc + (size_t)c*512;
    float acc = fcb[c];
    for (int o4 = 0; o4 < 128; ++o4){
      float4 wv = *(const float4*)&wr[o4*4];
      float4 yv = *(const float4*)&y2[p][o4*4];
      acc = fmaf(wv.x,yv.x,acc); acc = fmaf(wv.y,yv.y,acc);
      acc = fmaf(wv.z,yv.z,acc); acc = fmaf(wv.w,yv.w,acc);
    }
    int mm = m0 + p;
    if (mm < M_) pout[((size_t)b*M_ + mm)*3 + c] = acc;
  }
}

// ---------- launcher ----------
extern "C" void kernel_launch(void* const* d_in, const int* in_sizes, int n_in,
                              void* d_out, int out_size, void* d_ws, size_t ws_size,
                              hipStream_t stream){
  const float* pts  = (const float*)d_in[0];
  const float* w1   = (const float*)d_in[1];  const float* b1   = (const float*)d_in[2];
  const float* w2   = (const float*)d_in[3];  const float* b2   = (const float*)d_in[4];
  const float* w3   = (const float*)d_in[5];  const float* b3   = (const float*)d_in[6];
  const float* g1a  = (const float*)d_in[7];  const float* g1ab = (const float*)d_in[8];
  const float* g1b  = (const float*)d_in[9];  const float* g1bb = (const float*)d_in[10];
  const float* g2a  = (const float*)d_in[11]; const float* g2ab = (const float*)d_in[12];
  const float* g2b  = (const float*)d_in[13]; const float* g2bb = (const float*)d_in[14];
  const float* m1   = (const float*)d_in[15]; const float* m1b  = (const float*)d_in[16];
  const float* m2   = (const float*)d_in[17]; const float* m2b  = (const float*)d_in[18];
  const float* f1a  = (const float*)d_in[19]; const float* f1ab = (const float*)d_in[20];
  const float* f1b  = (const float*)d_in[21]; const float* f1bb = (const float*)d_in[22];
  const float* f1c  = (const float*)d_in[23]; const float* f1cb = (const float*)d_in[24];
  const float* f2a  = (const float*)d_in[25]; const float* f2ab = (const float*)d_in[26];
  const float* f2b  = (const float*)d_in[27]; const float* f2bb = (const float*)d_in[28];
  const float* f2c  = (const float*)d_in[29]; const float* f2cb = (const float*)d_in[30];
  float* out = (float*)d_out;

  char* w = (char*)d_ws;
  auto alloc = [&](size_t bytes){ char* p = w; w += (bytes + 255) & ~(size_t)255; return p; };
  unsigned long long* nn64 = (unsigned long long*)alloc((size_t)B_*N_*8);
  float* x    = (float*)alloc((size_t)B_*N_*64*4);
  float* g    = (float*)alloc((size_t)B_*N_*128*4);
  unsigned short* T64  = (unsigned short*)alloc((size_t)B_*4*4*N_*16);   //  8MB
  unsigned short* T128 = (unsigned short*)alloc((size_t)B_*8*4*N_*16);   // 16MB
  float* ccf  = (float*)alloc((size_t)B_*N_*4);
  int*   idx  = (int*)alloc((size_t)B_*N_*16*4);
  ull*   qkeys = (ull*)alloc((size_t)B_*N_*64*8);                        // 16MB
  unsigned int* glob = (unsigned int*)alloc((size_t)B_*1024*4);
  float* base1 = (float*)alloc((size_t)B_*512*4);
  float* base2 = (float*)alloc((size_t)B_*512*4);
  float* mid   = (float*)alloc((size_t)B_*M_*3*4);
  (void)ws_size; (void)in_sizes; (void)n_in; (void)out_size;

  const int SMEM4 = 2*(4*4096) + 512;    // 33,280 B
  const int SMEM8 = 2*(8*4096) + 512;    // 66,048 B
  hipFuncSetAttribute((const void*)k_knnF<4,2>, hipFuncAttributeMaxDynamicSharedMemorySize, SMEM4);
  hipFuncSetAttribute((const void*)k_knnF<8,1>, hipFuncAttributeMaxDynamicSharedMemorySize, SMEM8);

  hipMemsetAsync(nn64, 0xFF, (size_t)B_*N_*8, stream);
  k_init<<<dim3((B_*1024+255)/256), 256, 0, stream>>>(glob);
  k_nn1<<<dim3(N_/256, 4, B_), 256, 0, stream>>>(pts, nn64);
  k_cov_mlp<<<dim3(N_/64, B_), 256, 0, stream>>>(pts, nn64, w1,b1,w2,b2,w3,b3, x);

  k_prep4<4><<<dim3(N_/256, B_), 256, 0, stream>>>(x, T64, ccf);
  k_knnF<4,2><<<dim3(N_/128, 2, B_), 256, SMEM4, stream>>>(T64, ccf, qkeys);
  k_sel<<<dim3(B_*N_/256), 256, 0, stream>>>(qkeys, idx);

  k_gpool_mlp<<<dim3(N_/64, B_), 256, 0, stream>>>(x, idx, g1a,g1ab,g1b,g1bb, g);

  k_prep4<8><<<dim3(N_/256, B_), 256, 0, stream>>>(g, T128, ccf);
  k_knnF<8,1><<<dim3(N_/128, 2, B_), 256, SMEM8, stream>>>(T128, ccf, qkeys);
  k_sel<<<dim3(B_*N_/256), 256, 0, stream>>>(qkeys, idx);

  k_hpool_max<<<dim3(N_/32, B_), 256, 0, stream>>>(g, idx, g2a,g2ab,g2b,g2bb, glob);
  k_code<<<dim3(B_), 512, 0, stream>>>(glob, m1,m1b,m2,m2b, f1a,f1ab, f2a,f2ab, base1, base2);
  k_fold<2><<<dim3((M_+31)/32, B_), 256, 0, stream>>>(base1, f1a, f1b, f1bb, f1c, f1cb, nullptr, mid);
  k_fold<3><<<dim3((M_+31)/32, B_), 256, 0, stream>>>(base2, f2a, f2b, f2bb, f2c, f2cb, mid, out);
}

// Round 9
// 1831.700 us; speedup vs baseline: 3.3659x; 1.0280x over previous
//
#include <hip/hip_runtime.h>
#include <stdint.h>

#define B_ 4
#define N_ 8192
#define K_ 16
#define FEAT_ 512
#define GRID_ 45
#define M_ (GRID_*GRID_)

typedef unsigned long long ull;
typedef __bf16 bf16x8 __attribute__((ext_vector_type(8)));
typedef float f32x16 __attribute__((ext_vector_type(16)));

// ---------- helpers ----------

__device__ __forceinline__ unsigned int fmap(float f){
  unsigned int u = __float_as_uint(f);
  return (u & 0x80000000u) ? ~u : (u | 0x80000000u);
}
__device__ __forceinline__ float funmap(unsigned int u){
  return (u & 0x80000000u) ? __uint_as_float(u ^ 0x80000000u) : __uint_as_float(~u);
}

// sorted top-16 insert on packed (fmap(dist)<<32 | idx) keys: lex order ==
// jax.lax.top_k tie-break (lower index first). Order-independent.
__device__ __forceinline__ void ins16(ull (&d)[16], ull k){
  if (k < d[15]){
    bool c[16];
#pragma unroll
    for (int s = 0; s < 16; ++s) c[s] = k < d[s];
#pragma unroll
    for (int s = 15; s >= 1; --s) d[s] = c[s-1] ? d[s-1] : (c[s] ? k : d[s]);
    if (c[0]) d[0] = k;
  }
}

#define GLDS16(l, g) __builtin_amdgcn_global_load_lds((const __attribute__((address_space(1))) void*)(g), (__attribute__((address_space(3))) void*)(l), 16, 0, 0)
#define GLDS4(l, g)  __builtin_amdgcn_global_load_lds((const __attribute__((address_space(1))) void*)(g), (__attribute__((address_space(3))) void*)(l), 4, 0, 0)

#define KEY_INF 0xFF800000FFFFFFFFull

// ---------- init ----------
__global__ void k_init(unsigned int* glob){
  int i = blockIdx.x*256 + threadIdx.x;
  if (i < B_*1024) glob[i] = 0x007FFFFFu;   // fmap(-inf)
}

// ---------- KNN #1: nearest other point (exact fp32) ----------
__global__ __launch_bounds__(256) void k_nn1(const float* __restrict__ pts,
                                             unsigned long long* __restrict__ nn64){
  __shared__ float sp[2048*3];
  int b = blockIdx.z, s = blockIdx.y;
  int c0 = s*2048;
  const float* P = pts + (size_t)b*N_*3;
  for (int i = threadIdx.x; i < 2048*3; i += 256) sp[i] = P[c0*3 + i];
  __syncthreads();
  int n = blockIdx.x*256 + threadIdx.x;
  float qx = P[n*3], qy = P[n*3+1], qz = P[n*3+2];
  float best = 1e30f; int bi = 0;
  for (int j = 0; j < 2048; ++j){
    float dx = qx - sp[j*3], dy = qy - sp[j*3+1], dz = qz - sp[j*3+2];
    float d2 = fmaf(dx,dx, fmaf(dy,dy, dz*dz));
    int cj = c0 + j;
    if (d2 < best && cj != n){ best = d2; bi = cj; }
  }
  unsigned long long key = ((unsigned long long)__float_as_uint(best) << 32) | (unsigned int)bi;
  atomicMin(&nn64[(size_t)b*N_ + n], key);
}

// ---------- local_cov + 3 convs (12->64->64->64, relu each) ----------
__global__ __launch_bounds__(256) void k_cov_mlp(const float* __restrict__ pts,
    const unsigned long long* __restrict__ nn64,
    const float* __restrict__ w1, const float* __restrict__ b1,
    const float* __restrict__ w2, const float* __restrict__ b2,
    const float* __restrict__ w3, const float* __restrict__ b3,
    float* __restrict__ xout){
  __shared__ __align__(16) float W1t[12*64];
  __shared__ __align__(16) float W2t[64*64];
  __shared__ __align__(16) float W3t[64*64];
  __shared__ float B1[64], B2[64], B3[64];
  __shared__ __align__(16) float x0[64][12];
  __shared__ __align__(16) float h1[64][64];
  __shared__ __align__(16) float h2[64][64];
  int b = blockIdx.y; int n0 = blockIdx.x*64; int tid = threadIdx.x;
  for (int i = tid; i < 12*64; i += 256){ int o = i % 64, ci = i / 64; W1t[i] = w1[o*12 + ci]; }
  for (int i = tid; i < 64*64; i += 256){ int o = i % 64, ci = i / 64; W2t[i] = w2[o*64 + ci]; W3t[i] = w3[o*64 + ci]; }
  if (tid < 64){ B1[tid]=b1[tid]; B2[tid]=b2[tid]; B3[tid]=b3[tid]; }
  {
    int p = tid % 64, cg = tid / 64;
    int n = n0 + p;
    const float* P = pts + ((size_t)b*N_ + n)*3;
    int nb = (int)(nn64[(size_t)b*N_ + n] & 0xFFFFFFFFull);
    const float* Q = pts + ((size_t)b*N_ + nb)*3;
    if (cg == 0){ x0[p][0]=P[0]; x0[p][1]=P[1]; x0[p][2]=P[2]; }
    else { int i = cg-1; float pi = P[i];
      x0[p][3+i*3+0]=pi*Q[0]; x0[p][3+i*3+1]=pi*Q[1]; x0[p][3+i*3+2]=pi*Q[2]; }
  }
  __syncthreads();
  { int o = tid % 64, pg = tid / 64;
    for (int p = pg; p < 64; p += 4){
      float acc = B1[o];
#pragma unroll
      for (int ci = 0; ci < 12; ++ci) acc = fmaf(W1t[ci*64+o], x0[p][ci], acc);
      h1[p][o] = fmaxf(acc, 0.f);
    } }
  __syncthreads();
  { int o = tid % 64, pg = tid / 64;
    for (int p = pg; p < 64; p += 4){
      float acc = B2[o];
#pragma unroll
      for (int ci = 0; ci < 64; ++ci) acc = fmaf(W2t[ci*64+o], h1[p][ci], acc);
      h2[p][o] = fmaxf(acc, 0.f);
    } }
  __syncthreads();
  { int o = tid % 64, pg = tid / 64;
    for (int p = pg; p < 64; p += 4){
      float acc = B3[o];
#pragma unroll
      for (int ci = 0; ci < 64; ++ci) acc = fmaf(W3t[ci*64+o], h2[p][ci], acc);
      xout[((size_t)b*N_ + n0 + p)*64 + o] = fmaxf(acc, 0.f);
    } }
}

// ---------- prep: bf16 hi/lo split into K-major granule layout + norms ----------
// T layout: [b][kf][pl 2][hi8 2][n 8192][16B granule]; granule = 8 bf16 ch.
template<int KF>
__global__ __launch_bounds__(256) void k_prep4(const float* __restrict__ f,
    unsigned short* __restrict__ T, float* __restrict__ cc){
  int b = blockIdx.y; int n = blockIdx.x*256 + threadIdx.x;
  const float* src = f + ((size_t)b*N_ + n)*(KF*16);
  char* Tb = (char*)T;
  float ss = 0.f;
#pragma unroll
  for (int kf = 0; kf < KF; ++kf){
    float v[16];
#pragma unroll
    for (int c4 = 0; c4 < 4; ++c4){
      float4 t4 = *(const float4*)&src[kf*16 + c4*4];
      v[c4*4]=t4.x; v[c4*4+1]=t4.y; v[c4*4+2]=t4.z; v[c4*4+3]=t4.w;
    }
    unsigned short hs[16], ls[16];
#pragma unroll
    for (int c = 0; c < 16; ++c){
      float x = v[c];
      ss = fmaf(x, x, ss);
      __bf16 h = (__bf16)x;
      __bf16 l = (__bf16)(x - (float)h);
      hs[c] = __builtin_bit_cast(unsigned short, h);
      ls[c] = __builtin_bit_cast(unsigned short, l);
    }
    size_t base = ((((size_t)b*KF + kf)*2)*2)*(size_t)(N_*16) + (size_t)n*16;
    const size_t HS = (size_t)N_*16;           // hi8 stride
    const size_t PS = 2*HS;                    // plane stride
    *(uint4*)(Tb + base)            = *(uint4*)&hs[0];
    *(uint4*)(Tb + base + HS)       = *(uint4*)&hs[8];
    *(uint4*)(Tb + base + PS)       = *(uint4*)&ls[0];
    *(uint4*)(Tb + base + PS + HS)  = *(uint4*)&ls[8];
  }
  cc[(size_t)b*N_ + n] = ss;
}

// ---------- fused single-pass KNN: MFMA + gated u64 top-16, region output ----------
// Single LDS buffer (occupancy > intra-block pipelining; cross-block TLP hides
// staging). S-way candidate split; lane owns region (q, sp, hi).
template<int KF, int MW, int S>
__global__ __launch_bounds__(256, MW) void k_knnF(const unsigned short* __restrict__ T,
    const float* __restrict__ ccg, ull* __restrict__ qkeys){
  extern __shared__ char smem[];
  constexpr int NT = (N_/S)/64;
  char* As = smem;                    // KF*4096
  char* Cs = smem + KF*4096;          // 256

  const int tid = threadIdx.x, lane = tid & 63, wid = tid >> 6;
  const int hi = lane >> 5, l31 = lane & 31;
  const int b = blockIdx.z, sp = blockIdx.y, q0 = blockIdx.x*128;
  const int c0 = sp*(N_/S);
  const char* Tb = (const char*)T;
  const size_t HS = (size_t)N_*16, PS = 2*HS, KS = 4*HS;
  const size_t Bb = (size_t)b*KF*KS;
  const float* ccb = ccg + (size_t)b*N_;

  const int q = q0 + wid*32 + l31;
  bf16x8 qh[KF], ql[KF];
#pragma unroll
  for (int kf = 0; kf < KF; ++kf){
    size_t o = Bb + kf*KS + hi*HS + (size_t)q*16;
    qh[kf] = *(const bf16x8*)(Tb + o);
    ql[kf] = *(const bf16x8*)(Tb + o + PS);
  }

  ull keys[16];
#pragma unroll
  for (int t = 0; t < 16; ++t) keys[t] = KEY_INF;
  float kapf = __builtin_inff();

  auto stage = [&](int t0){
#pragma unroll
    for (int si = 0; si < KF; ++si){
      int s = wid + 4*si;
      int kf = s >> 2, pl = (s >> 1) & 1, h = s & 1;
      GLDS16(As + s*1024,
             Tb + Bb + kf*KS + pl*PS + h*HS + (size_t)(c0 + t0)*16);
    }
    if (wid == 0) GLDS4(Cs, (const char*)(ccb + c0 + t0));
  };

  for (int t = 0; t < NT; ++t){
    const int t0 = t*64;
    __syncthreads();                   // all waves done reading previous tile
    stage(t0);
    asm volatile("s_waitcnt vmcnt(0)" ::: "memory");
    __syncthreads();                   // tile visible to all waves

    const char* Ab = As + hi*1024 + l31*16;
    const float* cct = (const float*)Cs;
#pragma unroll
    for (int i = 0; i < 2; ++i){
      f32x16 acc = (f32x16)(0.f);
#pragma unroll
      for (int kf = 0; kf < KF; ++kf){
        bf16x8 ah = *(const bf16x8*)(Ab + kf*4096 + i*512);
        bf16x8 al = *(const bf16x8*)(Ab + kf*4096 + 2048 + i*512);
        acc = __builtin_amdgcn_mfma_f32_32x32x16_bf16(ah, qh[kf], acc, 0, 0, 0);
        acc = __builtin_amdgcn_mfma_f32_32x32x16_bf16(ah, ql[kf], acc, 0, 0, 0);
        acc = __builtin_amdgcn_mfma_f32_32x32x16_bf16(al, qh[kf], acc, 0, 0, 0);
      }
      // v = cc - 2<q,c> (qq dropped: constant per-query shift, order-preserving)
#pragma unroll
      for (int rq = 0; rq < 4; ++rq){
        float4 c4 = *(const float4*)(cct + i*32 + 4*hi + 8*rq);
        int rowb = c0 + t0 + i*32 + 4*hi + 8*rq;
        float v0 = fmaf(-2.f, acc[rq*4+0], c4.x);
        float v1 = fmaf(-2.f, acc[rq*4+1], c4.y);
        float v2 = fmaf(-2.f, acc[rq*4+2], c4.z);
        float v3 = fmaf(-2.f, acc[rq*4+3], c4.w);
        if (fminf(fminf(v0, v1), fminf(v2, v3)) <= kapf){
          if (v0 <= kapf) ins16(keys, ((ull)fmap(v0) << 32) | (unsigned)(rowb+0));
          if (v1 <= kapf) ins16(keys, ((ull)fmap(v1) << 32) | (unsigned)(rowb+1));
          if (v2 <= kapf) ins16(keys, ((ull)fmap(v2) << 32) | (unsigned)(rowb+2));
          if (v3 <= kapf) ins16(keys, ((ull)fmap(v3) << 32) | (unsigned)(rowb+3));
          kapf = funmap((unsigned)(keys[15] >> 32));  // sentinel -> +inf
        }
      }
    }
  }
  // write region (q, sp, hi): 16 keys, sentinel-padded
  ull* op = qkeys + (((size_t)((size_t)b*N_ + q)*S + sp)*2 + hi)*16;
#pragma unroll
  for (int t = 0; t < 16; ++t) op[t] = keys[t];
}

// ---------- final exact top-16 over S*2 regions x 16 keys ----------
template<int S>
__global__ void k_sel(const ull* __restrict__ qkeys, int* __restrict__ idxout){
  int i = blockIdx.x*256 + threadIdx.x;
  if (i >= B_*N_) return;
  ull best[16];
#pragma unroll
  for (int t = 0; t < 16; ++t) best[t] = KEY_INF;
  const ull* kp = qkeys + (size_t)i*(S*32);
  for (int t = 0; t < S*32; ++t) ins16(best, kp[t]);
  int* op = idxout + (size_t)i*16;
#pragma unroll
  for (int t = 0; t < 16; ++t) op[t] = (int)(best[t] & 0xffffffffu);
}

// ---------- maxpool(x) + conv 64->64 relu + conv 64->128 ----------
__global__ __launch_bounds__(256) void k_gpool_mlp(const float* __restrict__ x,
    const int* __restrict__ idx,
    const float* __restrict__ g1a, const float* __restrict__ g1ab,
    const float* __restrict__ g1b, const float* __restrict__ g1bb,
    float* __restrict__ gout){
  __shared__ __align__(16) float Wt1[64*64];
  __shared__ __align__(16) float Wt2[64*128];
  __shared__ float Ba[64], Bb[128];
  __shared__ __align__(16) float m[64][64];
  __shared__ __align__(16) float r[64][64];
  int b = blockIdx.y; int n0 = blockIdx.x*64; int tid = threadIdx.x;
  for (int i = tid; i < 64*64; i += 256){ int o = i%64, ci = i/64; Wt1[i] = g1a[o*64+ci]; }
  for (int i = tid; i < 64*128; i += 256){ int o = i%128, ci = i/128; Wt2[i] = g1b[o*64+ci]; }
  if (tid < 64) Ba[tid] = g1ab[tid];
  if (tid < 128) Bb[tid] = g1bb[tid];
  { int p = tid/4, cg = tid%4; int n = n0 + p;
    const int* ip = idx + ((size_t)b*N_ + n)*16;
    float mm[16];
#pragma unroll
    for (int u = 0; u < 16; ++u) mm[u] = -1e30f;
    for (int k = 0; k < 16; ++k){
      int nb = ip[k];
      const float4* src = (const float4*)(x + ((size_t)b*N_ + nb)*64 + cg*16);
#pragma unroll
      for (int u = 0; u < 4; ++u){
        float4 v = src[u];
        mm[4*u  ] = fmaxf(mm[4*u  ], v.x); mm[4*u+1] = fmaxf(mm[4*u+1], v.y);
        mm[4*u+2] = fmaxf(mm[4*u+2], v.z); mm[4*u+3] = fmaxf(mm[4*u+3], v.w);
      }
    }
#pragma unroll
    for (int u = 0; u < 16; ++u) m[p][cg*16+u] = mm[u];
  }
  __syncthreads();
  { int o = tid%64, pg = tid/64;
    float acc[16];
#pragma unroll
    for (int u = 0; u < 16; ++u) acc[u] = Ba[o];
    for (int ci = 0; ci < 64; ci += 4){
      float w0 = Wt1[ci*64+o], w1_ = Wt1[(ci+1)*64+o], w2_ = Wt1[(ci+2)*64+o], w3_ = Wt1[(ci+3)*64+o];
#pragma unroll
      for (int u = 0; u < 16; ++u){
        float4 mv = *(const float4*)&m[pg*16+u][ci];
        acc[u] = fmaf(w0, mv.x, acc[u]); acc[u] = fmaf(w1_, mv.y, acc[u]);
        acc[u] = fmaf(w2_, mv.z, acc[u]); acc[u] = fmaf(w3_, mv.w, acc[u]);
      }
    }
#pragma unroll
    for (int u = 0; u < 16; ++u) r[pg*16+u][o] = fmaxf(acc[u], 0.f);
  }
  __syncthreads();
  { int o = tid%128, pg = tid/128;   // no relu on this conv
    float acc[32];
#pragma unroll
    for (int u = 0; u < 32; ++u) acc[u] = Bb[o];
    for (int ci = 0; ci < 64; ci += 4){
      float w0 = Wt2[ci*128+o], w1_ = Wt2[(ci+1)*128+o], w2_ = Wt2[(ci+2)*128+o], w3_ = Wt2[(ci+3)*128+o];
#pragma unroll
      for (int u = 0; u < 32; ++u){
        float4 rv = *(const float4*)&r[pg*32+u][ci];
        acc[u] = fmaf(w0, rv.x, acc[u]); acc[u] = fmaf(w1_, rv.y, acc[u]);
        acc[u] = fmaf(w2_, rv.z, acc[u]); acc[u] = fmaf(w3_, rv.w, acc[u]);
      }
    }
#pragma unroll
    for (int u = 0; u < 32; ++u)
      gout[((size_t)b*N_ + n0 + pg*32 + u)*128 + o] = acc[u];
  }
}

// ---------- maxpool(g) + conv 128->128 relu + conv 128->1024 + global max ----------
__global__ __launch_bounds__(256) void k_hpool_max(const float* __restrict__ g,
    const int* __restrict__ idx,
    const float* __restrict__ g2a, const float* __restrict__ g2ab,
    const float* __restrict__ g2b, const float* __restrict__ g2bb,
    unsigned int* __restrict__ glob){
  __shared__ __align__(16) float m[32][128];
  __shared__ __align__(16) float t[32][128];
  int b = blockIdx.y; int n0 = blockIdx.x*32; int tid = threadIdx.x;
  { int p = tid/8, cg = tid%8; int n = n0+p;
    const int* ip = idx + ((size_t)b*N_+n)*16;
    float mm[16];
#pragma unroll
    for (int u = 0; u < 16; ++u) mm[u] = -1e30f;
    for (int k = 0; k < 16; ++k){
      int nb = ip[k];
      const float4* src = (const float4*)(g + ((size_t)b*N_+nb)*128 + cg*16);
#pragma unroll
      for (int u = 0; u < 4; ++u){
        float4 v = src[u];
        mm[4*u  ] = fmaxf(mm[4*u  ], v.x); mm[4*u+1] = fmaxf(mm[4*u+1], v.y);
        mm[4*u+2] = fmaxf(mm[4*u+2], v.z); mm[4*u+3] = fmaxf(mm[4*u+3], v.w);
      }
    }
#pragma unroll
    for (int u = 0; u < 16; ++u) m[p][cg*16+u] = mm[u];
  }
  __syncthreads();
  { int o = tid%128, pg = tid/128;
    float acc[16];
#pragma unroll
    for (int u = 0; u < 16; ++u) acc[u] = g2ab[o];
    const float4* wrow = (const float4*)(g2a + (size_t)o*128);
    for (int c4 = 0; c4 < 32; ++c4){
      float4 wv = wrow[c4];
#pragma unroll
      for (int u = 0; u < 16; ++u){
        float4 mv = *(const float4*)&m[pg*16+u][c4*4];
        acc[u] = fmaf(wv.x,mv.x,acc[u]); acc[u] = fmaf(wv.y,mv.y,acc[u]);
        acc[u] = fmaf(wv.z,mv.z,acc[u]); acc[u] = fmaf(wv.w,mv.w,acc[u]);
      }
    }
#pragma unroll
    for (int u = 0; u < 16; ++u) t[pg*16+u][o] = fmaxf(acc[u], 0.f);
  }
  __syncthreads();
  for (int oc = 0; oc < 4; ++oc){
    int o = oc*256 + tid;
    const float4* wrow = (const float4*)(g2b + (size_t)o*128);
    float acc[32];
#pragma unroll
    for (int u = 0; u < 32; ++u) acc[u] = 0.f;
    for (int c4 = 0; c4 < 32; ++c4){
      float4 wv = wrow[c4];
#pragma unroll
      for (int u = 0; u < 32; ++u){
        float4 tv = *(const float4*)&t[u][c4*4];
        acc[u] = fmaf(wv.x,tv.x,acc[u]); acc[u] = fmaf(wv.y,tv.y,acc[u]);
        acc[u] = fmaf(wv.z,tv.z,acc[u]); acc[u] = fmaf(wv.w,tv.w,acc[u]);
      }
    }
    float bias = g2bb[o];
    float mx = -1e30f;
#pragma unroll
    for (int u = 0; u < 32; ++u) mx = fmaxf(mx, acc[u] + bias);
    atomicMax(&glob[b*1024 + o], fmap(mx));
  }
}

// ---------- code MLP + decoder base precompute ----------
__global__ __launch_bounds__(512) void k_code(const unsigned int* __restrict__ glob,
    const float* __restrict__ m1, const float* __restrict__ m1b,
    const float* __restrict__ m2, const float* __restrict__ m2b,
    const float* __restrict__ f1a, const float* __restrict__ f1ab,
    const float* __restrict__ f2a, const float* __restrict__ f2ab,
    float* __restrict__ base1, float* __restrict__ base2){
  __shared__ __align__(16) float gl_s[1024];
  __shared__ __align__(16) float hid_s[512];
  __shared__ __align__(16) float code_s[512];
  int b = blockIdx.x; int tid = threadIdx.x;
  for (int i = tid; i < 1024; i += 512) gl_s[i] = funmap(glob[b*1024+i]);
  __syncthreads();
  { float acc = m1b[tid];
    const float4* wr = (const float4*)(m1 + (size_t)tid*1024);
    for (int c4 = 0; c4 < 256; ++c4){ float4 wv = wr[c4]; float4 gv = *(const float4*)&gl_s[c4*4];
      acc = fmaf(wv.x,gv.x,acc); acc = fmaf(wv.y,gv.y,acc);
      acc = fmaf(wv.z,gv.z,acc); acc = fmaf(wv.w,gv.w,acc); }
    hid_s[tid] = fmaxf(acc, 0.f);
  }
  __syncthreads();
  { float acc = m2b[tid];
    const float4* wr = (const float4*)(m2 + (size_t)tid*512);
    for (int c4 = 0; c4 < 128; ++c4){ float4 wv = wr[c4]; float4 hv = *(const float4*)&hid_s[c4*4];
      acc = fmaf(wv.x,hv.x,acc); acc = fmaf(wv.y,hv.y,acc);
      acc = fmaf(wv.z,hv.z,acc); acc = fmaf(wv.w,hv.w,acc); }
    code_s[tid] = acc;
  }
  __syncthreads();
  { float acc = f1ab[tid];
    const float* wr = f1a + (size_t)tid*514;
    for (int c = 0; c < 512; ++c) acc = fmaf(wr[c], code_s[c], acc);
    base1[b*512 + tid] = acc;
  }
  { float acc = f2ab[tid];
    const float* wr = f2a + (size_t)tid*515;
    for (int c = 0; c < 512; ++c) acc = fmaf(wr[c], code_s[c], acc);
    base2[b*512 + tid] = acc;
  }
}

// ---------- folding decoder ----------
template<int NIN>
__global__ __launch_bounds__(256) void k_fold(const float* __restrict__ base,
    const float* __restrict__ fa,
    const float* __restrict__ fb, const float* __restrict__ fbb,
    const float* __restrict__ fc, const float* __restrict__ fcb,
    const float* __restrict__ pin, float* __restrict__ pout){
  __shared__ __align__(16) float y1[32][512];
  __shared__ __align__(16) float y2[32][516];
  __shared__ float pcoord[32][NIN];
  int b = blockIdx.y; int m0 = blockIdx.x*32; int tid = threadIdx.x;
  if (tid < 32*NIN){
    int p = tid / NIN, c = tid % NIN;
    int mm = min(m0 + p, M_-1);
    float v;
    if (NIN == 2){
      const float step = 0.6f/44.f;
      int ii = (c == 0) ? (mm/GRID_) : (mm%GRID_);
      v = -0.3f + step*ii;
    } else {
      v = pin[((size_t)b*M_ + mm)*3 + c];
    }
    pcoord[p][c] = v;
  }
  __syncthreads();
  const int stride_a = 512 + NIN;
  for (int rep = 0; rep < 2; ++rep){
    int o = rep*256 + tid;
    float av[NIN];
#pragma unroll
    for (int c = 0; c < NIN; ++c) av[c] = fa[(size_t)o*stride_a + 512 + c];
    float bv = base[b*512 + o];
    for (int p = 0; p < 32; ++p){
      float acc = bv;
#pragma unroll
      for (int c = 0; c < NIN; ++c) acc = fmaf(av[c], pcoord[p][c], acc);
      y1[p][o] = fmaxf(acc, 0.f);
    }
  }
  __syncthreads();
  for (int rep = 0; rep < 2; ++rep){
    int o2 = rep*256 + tid;
    const float* wr = fb + (size_t)o2*512;
    float acc[32];
#pragma unroll
    for (int u = 0; u < 32; ++u) acc[u] = 0.f;
    for (int c4 = 0; c4 < 128; ++c4){
      float4 wv = *(const float4*)&wr[c4*4];
#pragma unroll
      for (int u = 0; u < 32; ++u){
        float4 yv = *(const float4*)&y1[u][c4*4];
        acc[u] = fmaf(wv.x,yv.x,acc[u]); acc[u] = fmaf(wv.y,yv.y,acc[u]);
        acc[u] = fmaf(wv.z,yv.z,acc[u]); acc[u] = fmaf(wv.w,yv.w,acc[u]);
      }
    }
    float bias = fbb[o2];
#pragma unroll
    for (int u = 0; u < 32; ++u) y2[u][o2] = fmaxf(acc[u] + bias, 0.f);
  }
  __syncthreads();
  if (tid < 96){
    int p = tid / 3, c = tid % 3;
    const float* wr = fc + (size_t)c*512;
    float acc = fcb[c];
    for (int o4 = 0; o4 < 128; ++o4){
      float4 wv = *(const float4*)&wr[o4*4];
      float4 yv = *(const float4*)&y2[p][o4*4];
      acc = fmaf(wv.x,yv.x,acc); acc = fmaf(wv.y,yv.y,acc);
      acc = fmaf(wv.z,yv.z,acc); acc = fmaf(wv.w,yv.w,acc);
    }
    int mm = m0 + p;
    if (mm < M_) pout[((size_t)b*M_ + mm)*3 + c] = acc;
  }
}

// ---------- launcher ----------
extern "C" void kernel_launch(void* const* d_in, const int* in_sizes, int n_in,
                              void* d_out, int out_size, void* d_ws, size_t ws_size,
                              hipStream_t stream){
  const float* pts  = (const float*)d_in[0];
  const float* w1   = (const float*)d_in[1];  const float* b1   = (const float*)d_in[2];
  const float* w2   = (const float*)d_in[3];  const float* b2   = (const float*)d_in[4];
  const float* w3   = (const float*)d_in[5];  const float* b3   = (const float*)d_in[6];
  const float* g1a  = (const float*)d_in[7];  const float* g1ab = (const float*)d_in[8];
  const float* g1b  = (const float*)d_in[9];  const float* g1bb = (const float*)d_in[10];
  const float* g2a  = (const float*)d_in[11]; const float* g2ab = (const float*)d_in[12];
  const float* g2b  = (const float*)d_in[13]; const float* g2bb = (const float*)d_in[14];
  const float* m1   = (const float*)d_in[15]; const float* m1b  = (const float*)d_in[16];
  const float* m2   = (const float*)d_in[17]; const float* m2b  = (const float*)d_in[18];
  const float* f1a  = (const float*)d_in[19]; const float* f1ab = (const float*)d_in[20];
  const float* f1b  = (const float*)d_in[21]; const float* f1bb = (const float*)d_in[22];
  const float* f1c  = (const float*)d_in[23]; const float* f1cb = (const float*)d_in[24];
  const float* f2a  = (const float*)d_in[25]; const float* f2ab = (const float*)d_in[26];
  const float* f2b  = (const float*)d_in[27]; const float* f2bb = (const float*)d_in[28];
  const float* f2c  = (const float*)d_in[29]; const float* f2cb = (const float*)d_in[30];
  float* out = (float*)d_out;

  char* w = (char*)d_ws;
  auto alloc = [&](size_t bytes){ char* p = w; w += (bytes + 255) & ~(size_t)255; return p; };
  unsigned long long* nn64 = (unsigned long long*)alloc((size_t)B_*N_*8);
  float* x    = (float*)alloc((size_t)B_*N_*64*4);
  float* g    = (float*)alloc((size_t)B_*N_*128*4);
  unsigned short* T64  = (unsigned short*)alloc((size_t)B_*4*4*N_*16);   //  8MB
  unsigned short* T128 = (unsigned short*)alloc((size_t)B_*8*4*N_*16);   // 16MB
  float* ccf  = (float*)alloc((size_t)B_*N_*4);
  int*   idx  = (int*)alloc((size_t)B_*N_*16*4);
  ull*   qkeys = (ull*)alloc((size_t)B_*N_*4*2*16*8);                    // 32MB
  unsigned int* glob = (unsigned int*)alloc((size_t)B_*1024*4);
  float* base1 = (float*)alloc((size_t)B_*512*4);
  float* base2 = (float*)alloc((size_t)B_*512*4);
  float* mid   = (float*)alloc((size_t)B_*M_*3*4);
  (void)ws_size; (void)in_sizes; (void)n_in; (void)out_size;

  const int SMEM4 = 4*4096 + 256;    // 16,640 B
  const int SMEM8 = 8*4096 + 256;    // 33,024 B
  hipFuncSetAttribute((const void*)k_knnF<4,4,4>, hipFuncAttributeMaxDynamicSharedMemorySize, SMEM4);
  hipFuncSetAttribute((const void*)k_knnF<8,3,4>, hipFuncAttributeMaxDynamicSharedMemorySize, SMEM8);

  hipMemsetAsync(nn64, 0xFF, (size_t)B_*N_*8, stream);
  k_init<<<dim3((B_*1024+255)/256), 256, 0, stream>>>(glob);
  k_nn1<<<dim3(N_/256, 4, B_), 256, 0, stream>>>(pts, nn64);
  k_cov_mlp<<<dim3(N_/64, B_), 256, 0, stream>>>(pts, nn64, w1,b1,w2,b2,w3,b3, x);

  k_prep4<4><<<dim3(N_/256, B_), 256, 0, stream>>>(x, T64, ccf);
  k_knnF<4,4,4><<<dim3(N_/128, 4, B_), 256, SMEM4, stream>>>(T64, ccf, qkeys);
  k_sel<4><<<dim3(B_*N_/256), 256, 0, stream>>>(qkeys, idx);

  k_gpool_mlp<<<dim3(N_/64, B_), 256, 0, stream>>>(x, idx, g1a,g1ab,g1b,g1bb, g);

  k_prep4<8><<<dim3(N_/256, B_), 256, 0, stream>>>(g, T128, ccf);
  k_knnF<8,3,4><<<dim3(N_/128, 4, B_), 256, SMEM8, stream>>>(T128, ccf, qkeys);
  k_sel<4><<<dim3(B_*N_/256), 256, 0, stream>>>(qkeys, idx);

  k_hpool_max<<<dim3(N_/32, B_), 256, 0, stream>>>(g, idx, g2a,g2ab,g2b,g2bb, glob);
  k_code<<<dim3(B_), 512, 0, stream>>>(glob, m1,m1b,m2,m2b, f1a,f1ab, f2a,f2ab, base1, base2);
  k_fold<2><<<dim3((M_+31)/32, B_), 256, 0, stream>>>(base1, f1a, f1b, f1bb, f1c, f1cb, nullptr, mid);
  k_fold<3><<<dim3((M_+31)/32, B_), 256, 0, stream>>>(base2, f2a, f2b, f2bb, f2c, f2cb, mid, out);
}